// Round 1
// baseline (10448.575 us; speedup 1.0000x reference)
//
#include <hip/hip_runtime.h>
#include <hip/hip_bf16.h>
#include <math.h>

// Problem constants (from reference)
#define V_SZ 32000
#define D_SZ 1024
#define H_SZ 16
#define L_SZ 4
#define F_SZ 4096
#define S_SZ 1024
#define B_SZ 2
#define DK 64              // D/H
#define NTOK (B_SZ * S_SZ) // 2048

// ---------------------------------------------------------------------------
// Embedding gather: x[n,:] = tok_emb[ids[n],:]   (one block per token row)
// ---------------------------------------------------------------------------
__global__ __launch_bounds__(256) void embed_kernel(const int* __restrict__ ids,
                                                    const float* __restrict__ emb,
                                                    float* __restrict__ x) {
    const int row = blockIdx.x;
    const int id = ids[row];
    const float4* src = (const float4*)(emb + (size_t)id * D_SZ);
    float4* dst = (float4*)(x + (size_t)row * D_SZ);
    dst[threadIdx.x] = src[threadIdx.x];  // D=1024 floats = 256 float4
}

// ---------------------------------------------------------------------------
// RMSNorm: out = x / (sqrt(mean(x^2)) + eps) * w    (one block per row)
// ---------------------------------------------------------------------------
__global__ __launch_bounds__(256) void rmsnorm_kernel(const float* __restrict__ x,
                                                      const float* __restrict__ w,
                                                      float* __restrict__ out) {
    const int row = blockIdx.x;
    const int tid = threadIdx.x;
    const float4* xr = (const float4*)(x + (size_t)row * D_SZ);
    float4 v = xr[tid];
    float ss = v.x * v.x + v.y * v.y + v.z * v.z + v.w * v.w;
#pragma unroll
    for (int off = 32; off > 0; off >>= 1) ss += __shfl_down(ss, off, 64);
    __shared__ float red[4];
    if ((tid & 63) == 0) red[tid >> 6] = ss;
    __syncthreads();
    float tot = red[0] + red[1] + red[2] + red[3];
    float rms = sqrtf(tot * (1.0f / (float)D_SZ)) + 1e-5f;
    float inv = 1.0f / rms;
    const float4* wr = (const float4*)w;
    float4 wv = wr[tid];
    float4 o;
    o.x = v.x * inv * wv.x;
    o.y = v.y * inv * wv.y;
    o.z = v.z * inv * wv.z;
    o.w = v.w * inv * wv.w;
    ((float4*)(out + (size_t)row * D_SZ))[tid] = o;
}

// ---------------------------------------------------------------------------
// GEMM (NT): C[M,N] = A[M,K] * B[N,K]^T      (both row-major, K contiguous)
// BM=128, BN=64, BK=16, 256 threads, 8x4 micro-tile per thread.
// EPI: 0 = store, 1 = C += val (residual add), 2 = store swish(val),
//      3 = C *= val (swiglu combine)
// All dims must divide evenly (they do: M=2048, N in {1024,4096,32000},
// K in {1024,4096}).
// ---------------------------------------------------------------------------
#define BM 128
#define BN 64
#define BKK 16

template <int EPI>
__global__ __launch_bounds__(256) void gemm_nt(const float* __restrict__ A,
                                               const float* __restrict__ B,
                                               float* __restrict__ C,
                                               int M, int N, int K) {
    __shared__ float As[BKK][BM + 4];
    __shared__ float Bs[BKK][BN + 4];
    const int tid = threadIdx.x;
    const int tx = tid & 15;        // 0..15 -> 4 cols each
    const int ty = tid >> 4;        // 0..15 -> 8 rows each
    const int m0 = blockIdx.y * BM;
    const int n0 = blockIdx.x * BN;
    const int lr = tid >> 2;        // 0..63
    const int lk = (tid & 3) << 2;  // 0,4,8,12

    const float* Ap0 = A + (size_t)(m0 + lr) * K + lk;
    const float* Ap1 = A + (size_t)(m0 + lr + 64) * K + lk;
    const float* Bp  = B + (size_t)(n0 + lr) * K + lk;

    float acc[8][4];
#pragma unroll
    for (int i = 0; i < 8; i++)
#pragma unroll
        for (int j = 0; j < 4; j++) acc[i][j] = 0.0f;

    for (int k0 = 0; k0 < K; k0 += BKK) {
        float4 a0 = *(const float4*)(Ap0 + k0);
        float4 a1 = *(const float4*)(Ap1 + k0);
        float4 b0 = *(const float4*)(Bp + k0);
        __syncthreads();
        As[lk + 0][lr] = a0.x; As[lk + 1][lr] = a0.y;
        As[lk + 2][lr] = a0.z; As[lk + 3][lr] = a0.w;
        As[lk + 0][lr + 64] = a1.x; As[lk + 1][lr + 64] = a1.y;
        As[lk + 2][lr + 64] = a1.z; As[lk + 3][lr + 64] = a1.w;
        Bs[lk + 0][lr] = b0.x; Bs[lk + 1][lr] = b0.y;
        Bs[lk + 2][lr] = b0.z; Bs[lk + 3][lr] = b0.w;
        __syncthreads();
#pragma unroll
        for (int k = 0; k < BKK; k++) {
            float4 t0 = *(const float4*)&As[k][ty * 8];
            float4 t1 = *(const float4*)&As[k][ty * 8 + 4];
            float4 t2 = *(const float4*)&Bs[k][tx * 4];
            float av[8], bv[4];
            av[0] = t0.x; av[1] = t0.y; av[2] = t0.z; av[3] = t0.w;
            av[4] = t1.x; av[5] = t1.y; av[6] = t1.z; av[7] = t1.w;
            bv[0] = t2.x; bv[1] = t2.y; bv[2] = t2.z; bv[3] = t2.w;
#pragma unroll
            for (int i = 0; i < 8; i++)
#pragma unroll
                for (int j = 0; j < 4; j++) acc[i][j] += av[i] * bv[j];
        }
    }

#pragma unroll
    for (int i = 0; i < 8; i++) {
        const int row = m0 + ty * 8 + i;
        float* cp = C + (size_t)row * N + n0 + tx * 4;
        float4 r;
        r.x = acc[i][0]; r.y = acc[i][1]; r.z = acc[i][2]; r.w = acc[i][3];
        if (EPI == 1) {
            float4 c = *(const float4*)cp;
            r.x += c.x; r.y += c.y; r.z += c.z; r.w += c.w;
        } else if (EPI == 2) {
            r.x = r.x / (1.0f + __expf(-r.x));
            r.y = r.y / (1.0f + __expf(-r.y));
            r.z = r.z / (1.0f + __expf(-r.z));
            r.w = r.w / (1.0f + __expf(-r.w));
        } else if (EPI == 3) {
            float4 c = *(const float4*)cp;
            r.x *= c.x; r.y *= c.y; r.z *= c.z; r.w *= c.w;
        }
        *(float4*)cp = r;
    }
}

// ---------------------------------------------------------------------------
// RoPE in-place on q and k. One thread per (row, pair).
// Within-row element offset of pair pp is exactly 2*pp (head-major layout).
// ---------------------------------------------------------------------------
__global__ __launch_bounds__(256) void rope_kernel(float* __restrict__ q,
                                                   float* __restrict__ k,
                                                   int total) {
    const int idx = blockIdx.x * 256 + threadIdx.x;
    if (idx >= total) return;
    const int n = idx >> 9;       // row (D/2 = 512 pairs per row)
    const int pp = idx & 511;     // pair index within row
    const int i = pp & 31;        // pair index within head (dk/2 = 32)
    const int pos = n & (S_SZ - 1);
    const float inv_freq = powf(10000.0f, -(float)(2 * i) * (1.0f / (float)DK));
    const float ang = (float)pos * inv_freq;
    float sn, cs;
    sincosf(ang, &sn, &cs);
    const size_t base = (size_t)n * D_SZ + (size_t)pp * 2;
    float q1 = q[base], q2 = q[base + 1];
    q[base]     = q1 * cs - q2 * sn;
    q[base + 1] = q1 * sn + q2 * cs;
    float k1 = k[base], k2 = k[base + 1];
    k[base]     = k1 * cs - k2 * sn;
    k[base + 1] = k1 * sn + k2 * cs;
}

// ---------------------------------------------------------------------------
// Causal flash attention, fp32. Grid: (S/128, B*H). 128 threads; thread t
// owns query row bx*128+t. K/V tiles of 128 rows staged in LDS (64 KB).
// Online softmax with rescale-only-on-new-max.
// ---------------------------------------------------------------------------
__global__ __launch_bounds__(128) void attn_kernel(const float* __restrict__ q,
                                                   const float* __restrict__ kk,
                                                   const float* __restrict__ vv,
                                                   float* __restrict__ o) {
    __shared__ float Ks[128][DK];
    __shared__ float Vs[128][DK];
    const int t = threadIdx.x;
    const int bx = blockIdx.x;
    const int qi = bx * 128 + t;
    const int b = blockIdx.y >> 4;   // H=16
    const int h = blockIdx.y & 15;
    const size_t rowbase = ((size_t)b * S_SZ + qi) * D_SZ + h * DK;

    float qreg[DK];
#pragma unroll
    for (int c = 0; c < 16; c++) {
        float4 v4 = *(const float4*)(q + rowbase + c * 4);
        qreg[4 * c] = v4.x; qreg[4 * c + 1] = v4.y;
        qreg[4 * c + 2] = v4.z; qreg[4 * c + 3] = v4.w;
    }
    float oacc[DK];
#pragma unroll
    for (int d = 0; d < DK; d++) oacc[d] = 0.0f;
    float m = -3.0e38f, l = 0.0f;

    for (int kt = 0; kt <= bx; ++kt) {
        __syncthreads();
        const size_t kbase = ((size_t)b * S_SZ + kt * 128) * D_SZ + h * DK;
#pragma unroll
        for (int it = 0; it < 16; ++it) {
            const int r = it * 8 + (t >> 4);
            const int c4 = t & 15;
            *(float4*)&Ks[r][c4 * 4] = *(const float4*)(kk + kbase + (size_t)r * D_SZ + c4 * 4);
            *(float4*)&Vs[r][c4 * 4] = *(const float4*)(vv + kbase + (size_t)r * D_SZ + c4 * 4);
        }
        __syncthreads();
        const int jmax = (kt == bx) ? t : 127;
        for (int j = 0; j <= jmax; ++j) {
            const float4* kr = (const float4*)&Ks[j][0];
            float s = 0.0f;
#pragma unroll
            for (int c = 0; c < 16; c++) {
                float4 kv = kr[c];
                s += qreg[4 * c] * kv.x + qreg[4 * c + 1] * kv.y +
                     qreg[4 * c + 2] * kv.z + qreg[4 * c + 3] * kv.w;
            }
            s *= 0.125f;  // 1/sqrt(64)
            float p;
            if (s > m) {
                const float sf = __expf(m - s);
                m = s;
                l = l * sf + 1.0f;
#pragma unroll
                for (int d = 0; d < DK; d++) oacc[d] *= sf;
                p = 1.0f;
            } else {
                p = __expf(s - m);
                l += p;
            }
            const float4* vr = (const float4*)&Vs[j][0];
#pragma unroll
            for (int c = 0; c < 16; c++) {
                float4 v4 = vr[c];
                oacc[4 * c] += p * v4.x; oacc[4 * c + 1] += p * v4.y;
                oacc[4 * c + 2] += p * v4.z; oacc[4 * c + 3] += p * v4.w;
            }
        }
    }
    const float inv = 1.0f / l;
#pragma unroll
    for (int c = 0; c < 16; c++) {
        float4 ov;
        ov.x = oacc[4 * c] * inv; ov.y = oacc[4 * c + 1] * inv;
        ov.z = oacc[4 * c + 2] * inv; ov.w = oacc[4 * c + 3] * inv;
        *(float4*)(o + rowbase + c * 4) = ov;
    }
}

// ---------------------------------------------------------------------------
// Host-side launch
// ---------------------------------------------------------------------------
extern "C" void kernel_launch(void* const* d_in, const int* in_sizes, int n_in,
                              void* d_out, int out_size, void* d_ws, size_t ws_size,
                              hipStream_t stream) {
    const int*   token_ids  = (const int*)d_in[0];
    const float* tok_emb    = (const float*)d_in[1];
    const float* lm_head_w  = (const float*)d_in[2];
    const float* ln_final_w = (const float*)d_in[3];
    const float* q_w        = (const float*)d_in[4];
    const float* k_w        = (const float*)d_in[5];
    const float* v_w        = (const float*)d_in[6];
    const float* o_w        = (const float*)d_in[7];
    const float* ln1_w      = (const float*)d_in[8];
    const float* ln2_w      = (const float*)d_in[9];
    const float* w1         = (const float*)d_in[10];
    const float* w2         = (const float*)d_in[11];
    const float* w3         = (const float*)d_in[12];
    float* out = (float*)d_out;

    float* ws = (float*)d_ws;
    const size_t ND = (size_t)NTOK * D_SZ;   // 2M floats
    float* x   = ws;
    float* h   = x  + ND;
    float* qb  = h  + ND;
    float* kb  = qb + ND;
    float* vb  = kb + ND;
    float* ob  = vb + ND;
    float* ff1 = ob + ND;                    // NTOK * F floats (8M)

    embed_kernel<<<NTOK, 256, 0, stream>>>(token_ids, tok_emb, x);

    const dim3 gQKV(D_SZ / BN, NTOK / BM);   // (16,16)
    const dim3 gFFN(F_SZ / BN, NTOK / BM);   // (64,16)
    const dim3 gATT(S_SZ / 128, B_SZ * H_SZ);
    const int rope_total = NTOK * D_SZ / 2;

    for (int l = 0; l < L_SZ; l++) {
        rmsnorm_kernel<<<NTOK, 256, 0, stream>>>(x, ln1_w + (size_t)l * D_SZ, h);
        gemm_nt<0><<<gQKV, 256, 0, stream>>>(h, q_w + (size_t)l * D_SZ * D_SZ, qb, NTOK, D_SZ, D_SZ);
        gemm_nt<0><<<gQKV, 256, 0, stream>>>(h, k_w + (size_t)l * D_SZ * D_SZ, kb, NTOK, D_SZ, D_SZ);
        gemm_nt<0><<<gQKV, 256, 0, stream>>>(h, v_w + (size_t)l * D_SZ * D_SZ, vb, NTOK, D_SZ, D_SZ);
        rope_kernel<<<(rope_total + 255) / 256, 256, 0, stream>>>(qb, kb, rope_total);
        attn_kernel<<<gATT, 128, 0, stream>>>(qb, kb, vb, ob);
        gemm_nt<1><<<gQKV, 256, 0, stream>>>(ob, o_w + (size_t)l * D_SZ * D_SZ, x, NTOK, D_SZ, D_SZ);
        rmsnorm_kernel<<<NTOK, 256, 0, stream>>>(x, ln2_w + (size_t)l * D_SZ, h);
        gemm_nt<2><<<gFFN, 256, 0, stream>>>(h, w1 + (size_t)l * F_SZ * D_SZ, ff1, NTOK, F_SZ, D_SZ);
        gemm_nt<3><<<gFFN, 256, 0, stream>>>(h, w3 + (size_t)l * F_SZ * D_SZ, ff1, NTOK, F_SZ, D_SZ);
        gemm_nt<1><<<gQKV, 256, 0, stream>>>(ff1, w2 + (size_t)l * D_SZ * F_SZ, x, NTOK, D_SZ, F_SZ);
    }
    rmsnorm_kernel<<<NTOK, 256, 0, stream>>>(x, ln_final_w, h);
    const dim3 gOUT(V_SZ / BN, NTOK / BM);   // (500,16)
    gemm_nt<0><<<gOUT, 256, 0, stream>>>(h, lm_head_w, out, NTOK, V_SZ, D_SZ);
}

// Round 2
// 4285.741 us; speedup vs baseline: 2.4380x; 2.4380x over previous
//
#include <hip/hip_runtime.h>
#include <math.h>

// Problem constants (from reference)
#define V_SZ 32000
#define D_SZ 1024
#define H_SZ 16
#define L_SZ 4
#define F_SZ 4096
#define S_SZ 1024
#define B_SZ 2
#define DK 64              // D/H
#define NTOK (B_SZ * S_SZ) // 2048

typedef _Float16 half8 __attribute__((ext_vector_type(8)));
typedef _Float16 half4 __attribute__((ext_vector_type(4)));
typedef float floatx4 __attribute__((ext_vector_type(4)));

// async global->LDS, 16B per lane; lds ptr must be wave-uniform (HW writes
// base + lane*16), global ptr is per-lane.
__device__ __forceinline__ void gload16(const void* g, void* l) {
    __builtin_amdgcn_global_load_lds(
        (const __attribute__((address_space(1))) unsigned int*)g,
        (__attribute__((address_space(3))) unsigned int*)l, 16, 0, 0);
}

// ---------------------------------------------------------------------------
// fp32 -> fp16 conversion, 8 elems/thread
// ---------------------------------------------------------------------------
__global__ __launch_bounds__(256) void f2h(const float* __restrict__ in,
                                           _Float16* __restrict__ out, int n8) {
    const int i = blockIdx.x * 256 + threadIdx.x;
    if (i >= n8) return;
    const float4 a = ((const float4*)in)[2 * i];
    const float4 b = ((const float4*)in)[2 * i + 1];
    half8 h = {(_Float16)a.x, (_Float16)a.y, (_Float16)a.z, (_Float16)a.w,
               (_Float16)b.x, (_Float16)b.y, (_Float16)b.z, (_Float16)b.w};
    ((half8*)out)[i] = h;
}

// ---------------------------------------------------------------------------
// Embedding gather (fp32)
// ---------------------------------------------------------------------------
__global__ __launch_bounds__(256) void embed_kernel(const int* __restrict__ ids,
                                                    const float* __restrict__ emb,
                                                    float* __restrict__ x) {
    const int row = blockIdx.x;
    const int id = ids[row];
    const float4* src = (const float4*)(emb + (size_t)id * D_SZ);
    float4* dst = (float4*)(x + (size_t)row * D_SZ);
    dst[threadIdx.x] = src[threadIdx.x];
}

// ---------------------------------------------------------------------------
// RMSNorm: fp32 in, fp16 out (GEMM A-operand)
// ---------------------------------------------------------------------------
__global__ __launch_bounds__(256) void rmsnorm_kernel(const float* __restrict__ x,
                                                      const float* __restrict__ w,
                                                      _Float16* __restrict__ out) {
    const int row = blockIdx.x;
    const int tid = threadIdx.x;
    const float4 v = ((const float4*)(x + (size_t)row * D_SZ))[tid];
    float ss = v.x * v.x + v.y * v.y + v.z * v.z + v.w * v.w;
#pragma unroll
    for (int off = 32; off > 0; off >>= 1) ss += __shfl_down(ss, off, 64);
    __shared__ float red[4];
    if ((tid & 63) == 0) red[tid >> 6] = ss;
    __syncthreads();
    const float tot = red[0] + red[1] + red[2] + red[3];
    const float inv = 1.0f / (sqrtf(tot * (1.0f / (float)D_SZ)) + 1e-5f);
    const float4 wv = ((const float4*)w)[tid];
    half4 o = {(_Float16)(v.x * inv * wv.x), (_Float16)(v.y * inv * wv.y),
               (_Float16)(v.z * inv * wv.z), (_Float16)(v.w * inv * wv.w)};
    ((half4*)(out + (size_t)row * D_SZ))[tid] = o;
}

// ---------------------------------------------------------------------------
// MFMA fp16 GEMM (NT): C[M,N] = A[M,K] * B[N,K]^T, fp32 accumulate.
// 128x128 tile, BK=32, 4 waves (2x2), each wave 64x64 = 4x4 frags of 16x16x32.
// global_load_lds(16B) staging, linear LDS [128][32] f16, 2 barriers/K-step.
// EPI: 0 = Cf(f32) store; 1 = Cf += ; 2 = Ch(f16) = swish(v);
//      3 = Ch(f16) = AUXh * v (in-place swiglu; AUXh may alias Ch);
//      4 = qkv split store into Cq/Ck/Cv (each N'=1024)
// ---------------------------------------------------------------------------
template <int EPI>
__global__ __launch_bounds__(256) void hgemm(const _Float16* __restrict__ A,
                                             const _Float16* __restrict__ B,
                                             float* __restrict__ Cf,
                                             _Float16* Ch,
                                             const _Float16* AUXh,
                                             float* __restrict__ Cq,
                                             float* __restrict__ Ck,
                                             float* __restrict__ Cv,
                                             int M, int N, int K) {
    __shared__ __align__(16) _Float16 As[128 * 32];
    __shared__ __align__(16) _Float16 Bs[128 * 32];
    const int tid = threadIdx.x;
    const int lane = tid & 63;
    const int wave = tid >> 6;
    const int wr = wave >> 1, wc = wave & 1;
    const int l15 = lane & 15, g = lane >> 4;
    const int m0 = blockIdx.y * 128, n0 = blockIdx.x * 128;

    // staging slots: each wave covers 2KB of A-tile and 2KB of B-tile
    const int offA0 = wave * 2048 + lane * 16;
    const int offA1 = offA0 + 1024;
    const int rA0 = offA0 >> 6, kA0 = offA0 & 63;
    const int rA1 = offA1 >> 6, kA1 = offA1 & 63;
    const char* gA0 = (const char*)(A + (size_t)(m0 + rA0) * K) + kA0;
    const char* gA1 = (const char*)(A + (size_t)(m0 + rA1) * K) + kA1;
    const char* gB0 = (const char*)(B + (size_t)(n0 + rA0) * K) + kA0;
    const char* gB1 = (const char*)(B + (size_t)(n0 + rA1) * K) + kA1;
    char* lA0 = (char*)As + wave * 2048;
    char* lA1 = lA0 + 1024;
    char* lB0 = (char*)Bs + wave * 2048;
    char* lB1 = lB0 + 1024;

    floatx4 acc[4][4];
#pragma unroll
    for (int i = 0; i < 4; i++)
#pragma unroll
        for (int j = 0; j < 4; j++) acc[i][j] = 0;

    for (int kk = 0; kk < K; kk += 32) {
        __syncthreads();   // all waves done reading previous tile
        gload16(gA0, lA0);
        gload16(gA1, lA1);
        gload16(gB0, lB0);
        gload16(gB1, lB1);
        gA0 += 64; gA1 += 64; gB0 += 64; gB1 += 64;
        __syncthreads();   // loads drained (vmcnt(0) before barrier)
        half8 aF[4], bF[4];
#pragma unroll
        for (int i = 0; i < 4; i++)
            aF[i] = *(const half8*)&As[(wr * 64 + i * 16 + l15) * 32 + g * 8];
#pragma unroll
        for (int j = 0; j < 4; j++)
            bF[j] = *(const half8*)&Bs[(wc * 64 + j * 16 + l15) * 32 + g * 8];
#pragma unroll
        for (int i = 0; i < 4; i++)
#pragma unroll
            for (int j = 0; j < 4; j++)
                acc[i][j] = __builtin_amdgcn_mfma_f32_16x16x32_f16(aF[i], bF[j], acc[i][j], 0, 0, 0);
    }

    // epilogue: D frag mapping col = lane&15, row = (lane>>4)*4 + e  (m89)
    const int rb = m0 + wr * 64 + g * 4;
    const int cb = n0 + wc * 64 + l15;
    float* Cx = Cf;
    int cbq = cb;
    if (EPI == 4) {
        const int sel = n0 >> 10;   // tile never crosses a 1024 boundary
        Cx = sel == 0 ? Cq : (sel == 1 ? Ck : Cv);
        cbq = cb - sel * 1024;
    }
#pragma unroll
    for (int i = 0; i < 4; i++) {
#pragma unroll
        for (int e = 0; e < 4; e++) {
            const int row = rb + i * 16 + e;
#pragma unroll
            for (int j = 0; j < 4; j++) {
                const float v = acc[i][j][e];
                if (EPI == 0) {
                    Cf[(size_t)row * N + cb + j * 16] = v;
                } else if (EPI == 1) {
                    Cf[(size_t)row * N + cb + j * 16] += v;
                } else if (EPI == 2) {
                    Ch[(size_t)row * N + cb + j * 16] =
                        (_Float16)(v / (1.0f + __expf(-v)));
                } else if (EPI == 3) {
                    const size_t idx = (size_t)row * N + cb + j * 16;
                    Ch[idx] = (_Float16)((float)AUXh[idx] * v);
                } else {
                    Cx[(size_t)row * 1024 + cbq + j * 16] = v;
                }
            }
        }
    }
}

// ---------------------------------------------------------------------------
// RoPE in-place on q and k (fp32)
// ---------------------------------------------------------------------------
__global__ __launch_bounds__(256) void rope_kernel(float* __restrict__ q,
                                                   float* __restrict__ k,
                                                   int total) {
    const int idx = blockIdx.x * 256 + threadIdx.x;
    if (idx >= total) return;
    const int n = idx >> 9;
    const int pp = idx & 511;
    const int i = pp & 31;
    const int pos = n & (S_SZ - 1);
    const float inv_freq = powf(10000.0f, -(float)(2 * i) * (1.0f / (float)DK));
    const float ang = (float)pos * inv_freq;
    float sn, cs;
    sincosf(ang, &sn, &cs);
    const size_t base = (size_t)n * D_SZ + (size_t)pp * 2;
    float q1 = q[base], q2 = q[base + 1];
    q[base]     = q1 * cs - q2 * sn;
    q[base + 1] = q1 * sn + q2 * cs;
    float k1 = k[base], k2 = k[base + 1];
    k[base]     = k1 * cs - k2 * sn;
    k[base + 1] = k1 * sn + k2 * cs;
}

// ---------------------------------------------------------------------------
// Causal flash attention, fp32 math, fp16 output (feeds o-proj MFMA GEMM)
// ---------------------------------------------------------------------------
__global__ __launch_bounds__(128) void attn_kernel(const float* __restrict__ q,
                                                   const float* __restrict__ kk,
                                                   const float* __restrict__ vv,
                                                   _Float16* __restrict__ o) {
    __shared__ float Ks[128][DK];
    __shared__ float Vs[128][DK];
    const int t = threadIdx.x;
    const int bx = blockIdx.x;
    const int qi = bx * 128 + t;
    const int b = blockIdx.y >> 4;
    const int h = blockIdx.y & 15;
    const size_t rowbase = ((size_t)b * S_SZ + qi) * D_SZ + h * DK;

    float qreg[DK];
#pragma unroll
    for (int c = 0; c < 16; c++) {
        float4 v4 = *(const float4*)(q + rowbase + c * 4);
        qreg[4 * c] = v4.x; qreg[4 * c + 1] = v4.y;
        qreg[4 * c + 2] = v4.z; qreg[4 * c + 3] = v4.w;
    }
    float oacc[DK];
#pragma unroll
    for (int d = 0; d < DK; d++) oacc[d] = 0.0f;
    float m = -3.0e38f, l = 0.0f;

    for (int kt = 0; kt <= bx; ++kt) {
        __syncthreads();
        const size_t kbase = ((size_t)b * S_SZ + kt * 128) * D_SZ + h * DK;
#pragma unroll
        for (int it = 0; it < 16; ++it) {
            const int r = it * 8 + (t >> 4);
            const int c4 = t & 15;
            *(float4*)&Ks[r][c4 * 4] = *(const float4*)(kk + kbase + (size_t)r * D_SZ + c4 * 4);
            *(float4*)&Vs[r][c4 * 4] = *(const float4*)(vv + kbase + (size_t)r * D_SZ + c4 * 4);
        }
        __syncthreads();
        const int jmax = (kt == bx) ? t : 127;
        for (int j = 0; j <= jmax; ++j) {
            const float4* kr = (const float4*)&Ks[j][0];
            float s = 0.0f;
#pragma unroll
            for (int c = 0; c < 16; c++) {
                float4 kv = kr[c];
                s += qreg[4 * c] * kv.x + qreg[4 * c + 1] * kv.y +
                     qreg[4 * c + 2] * kv.z + qreg[4 * c + 3] * kv.w;
            }
            s *= 0.125f;
            float p;
            if (s > m) {
                const float sf = __expf(m - s);
                m = s;
                l = l * sf + 1.0f;
#pragma unroll
                for (int d = 0; d < DK; d++) oacc[d] *= sf;
                p = 1.0f;
            } else {
                p = __expf(s - m);
                l += p;
            }
            const float4* vr = (const float4*)&Vs[j][0];
#pragma unroll
            for (int c = 0; c < 16; c++) {
                float4 v4 = vr[c];
                oacc[4 * c] += p * v4.x; oacc[4 * c + 1] += p * v4.y;
                oacc[4 * c + 2] += p * v4.z; oacc[4 * c + 3] += p * v4.w;
            }
        }
    }
    const float inv = 1.0f / l;
#pragma unroll
    for (int c = 0; c < 16; c++) {
        half4 hv = {(_Float16)(oacc[4 * c] * inv), (_Float16)(oacc[4 * c + 1] * inv),
                    (_Float16)(oacc[4 * c + 2] * inv), (_Float16)(oacc[4 * c + 3] * inv)};
        *(half4*)(o + rowbase + c * 4) = hv;
    }
}

// ---------------------------------------------------------------------------
// Host-side launch
// ---------------------------------------------------------------------------
extern "C" void kernel_launch(void* const* d_in, const int* in_sizes, int n_in,
                              void* d_out, int out_size, void* d_ws, size_t ws_size,
                              hipStream_t stream) {
    const int*   token_ids  = (const int*)d_in[0];
    const float* tok_emb    = (const float*)d_in[1];
    const float* lm_head_w  = (const float*)d_in[2];
    const float* ln_final_w = (const float*)d_in[3];
    const float* q_w        = (const float*)d_in[4];
    const float* k_w        = (const float*)d_in[5];
    const float* v_w        = (const float*)d_in[6];
    const float* o_w        = (const float*)d_in[7];
    const float* ln1_w      = (const float*)d_in[8];
    const float* ln2_w      = (const float*)d_in[9];
    const float* w1         = (const float*)d_in[10];
    const float* w2         = (const float*)d_in[11];
    const float* w3         = (const float*)d_in[12];
    float* out = (float*)d_out;

    char* W = (char*)d_ws;
    const size_t MB = 1u << 20;
    float*    x    = (float*)(W + 0);          // 8 MB
    _Float16* h    = (_Float16*)(W + 8 * MB);  // 4 MB
    _Float16* ao   = (_Float16*)(W + 12 * MB); // 4 MB
    _Float16* wq   = (_Float16*)(W + 16 * MB); // 2 MB each, wq/wk/wv contiguous
    _Float16* wk   = wq + (1u << 20);
    _Float16* wv   = wk + (1u << 20);
    _Float16* wo   = wv + (1u << 20);          // ends 24 MB
    _Float16* ww1  = (_Float16*)(W + 24 * MB); // 8 MB
    _Float16* ww3  = (_Float16*)(W + 32 * MB); // 8 MB
    _Float16* ww2  = (_Float16*)(W + 40 * MB); // 8 MB
    float*    qb   = (float*)(W + 48 * MB);    // 8 MB
    float*    kb   = (float*)(W + 56 * MB);    // 8 MB
    float*    vb   = (float*)(W + 64 * MB);    // 8 MB
    _Float16* ff1h = (_Float16*)(W + 72 * MB); // 16 MB -> 88 MB
    _Float16* whead = (_Float16*)(W + 24 * MB); // 64 MB region [24,89.5), dead bufs

    embed_kernel<<<NTOK, 256, 0, stream>>>(token_ids, tok_emb, x);

    const int nDD8 = D_SZ * D_SZ / 8;     // 131072
    const int nFD8 = F_SZ * D_SZ / 8;     // 524288
    const dim3 gQKV(3 * D_SZ / 128, NTOK / 128);  // (24,16)
    const dim3 gD(D_SZ / 128, NTOK / 128);        // (8,16)
    const dim3 gF(F_SZ / 128, NTOK / 128);        // (32,16)
    const dim3 gATT(S_SZ / 128, B_SZ * H_SZ);
    const int rope_total = NTOK * D_SZ / 2;

    for (int l = 0; l < L_SZ; l++) {
        const size_t oDD = (size_t)l * D_SZ * D_SZ;
        const size_t oFD = (size_t)l * F_SZ * D_SZ;
        rmsnorm_kernel<<<NTOK, 256, 0, stream>>>(x, ln1_w + (size_t)l * D_SZ, h);
        f2h<<<(nDD8 + 255) / 256, 256, 0, stream>>>(q_w + oDD, wq, nDD8);
        f2h<<<(nDD8 + 255) / 256, 256, 0, stream>>>(k_w + oDD, wk, nDD8);
        f2h<<<(nDD8 + 255) / 256, 256, 0, stream>>>(v_w + oDD, wv, nDD8);
        f2h<<<(nDD8 + 255) / 256, 256, 0, stream>>>(o_w + oDD, wo, nDD8);
        hgemm<4><<<gQKV, 256, 0, stream>>>(h, wq, nullptr, nullptr, nullptr,
                                           qb, kb, vb, NTOK, 3 * D_SZ, D_SZ);
        rope_kernel<<<(rope_total + 255) / 256, 256, 0, stream>>>(qb, kb, rope_total);
        attn_kernel<<<gATT, 128, 0, stream>>>(qb, kb, vb, ao);
        hgemm<1><<<gD, 256, 0, stream>>>(ao, wo, x, nullptr, nullptr,
                                         nullptr, nullptr, nullptr, NTOK, D_SZ, D_SZ);
        rmsnorm_kernel<<<NTOK, 256, 0, stream>>>(x, ln2_w + (size_t)l * D_SZ, h);
        f2h<<<(nFD8 + 255) / 256, 256, 0, stream>>>(w1 + oFD, ww1, nFD8);
        f2h<<<(nFD8 + 255) / 256, 256, 0, stream>>>(w3 + oFD, ww3, nFD8);
        f2h<<<(nFD8 + 255) / 256, 256, 0, stream>>>(w2 + oFD, ww2, nFD8);
        hgemm<2><<<gF, 256, 0, stream>>>(h, ww1, nullptr, ff1h, nullptr,
                                         nullptr, nullptr, nullptr, NTOK, F_SZ, D_SZ);
        hgemm<3><<<gF, 256, 0, stream>>>(h, ww3, nullptr, ff1h, ff1h,
                                         nullptr, nullptr, nullptr, NTOK, F_SZ, D_SZ);
        hgemm<1><<<gD, 256, 0, stream>>>(ff1h, ww2, x, nullptr, nullptr,
                                         nullptr, nullptr, nullptr, NTOK, D_SZ, F_SZ);
    }
    rmsnorm_kernel<<<NTOK, 256, 0, stream>>>(x, ln_final_w, h);
    const int nVD8 = V_SZ * D_SZ / 8;   // 4096000
    f2h<<<(nVD8 + 255) / 256, 256, 0, stream>>>(lm_head_w, whead, nVD8);
    const dim3 gOUT(V_SZ / 128, NTOK / 128);   // (250,16)
    hgemm<0><<<gOUT, 256, 0, stream>>>(h, whead, out, nullptr, nullptr,
                                       nullptr, nullptr, nullptr, NTOK, V_SZ, D_SZ);
}

// Round 3
// 1565.849 us; speedup vs baseline: 6.6728x; 2.7370x over previous
//
#include <hip/hip_runtime.h>
#include <math.h>

// Problem constants (from reference)
#define V_SZ 32000
#define D_SZ 1024
#define H_SZ 16
#define L_SZ 4
#define F_SZ 4096
#define S_SZ 1024
#define B_SZ 2
#define DK 64              // D/H
#define NTOK (B_SZ * S_SZ) // 2048
#define NEG_INF -3.0e38f

typedef _Float16 half8 __attribute__((ext_vector_type(8)));
typedef _Float16 half4 __attribute__((ext_vector_type(4)));
typedef float floatx4 __attribute__((ext_vector_type(4)));

// async global->LDS, 16B per lane; lds ptr must be wave-uniform (HW writes
// base + lane*16), global ptr is per-lane.
__device__ __forceinline__ void gload16(const void* g, void* l) {
    __builtin_amdgcn_global_load_lds(
        (const __attribute__((address_space(1))) unsigned int*)g,
        (__attribute__((address_space(3))) unsigned int*)l, 16, 0, 0);
}

// ---------------------------------------------------------------------------
// fp32 -> fp16 conversion, 8 elems/thread
// ---------------------------------------------------------------------------
__global__ __launch_bounds__(256) void f2h(const float* __restrict__ in,
                                           _Float16* __restrict__ out, int n8) {
    const int i = blockIdx.x * 256 + threadIdx.x;
    if (i >= n8) return;
    const float4 a = ((const float4*)in)[2 * i];
    const float4 b = ((const float4*)in)[2 * i + 1];
    half8 h = {(_Float16)a.x, (_Float16)a.y, (_Float16)a.z, (_Float16)a.w,
               (_Float16)b.x, (_Float16)b.y, (_Float16)b.z, (_Float16)b.w};
    ((half8*)out)[i] = h;
}

// ---------------------------------------------------------------------------
// Embedding gather (fp32)
// ---------------------------------------------------------------------------
__global__ __launch_bounds__(256) void embed_kernel(const int* __restrict__ ids,
                                                    const float* __restrict__ emb,
                                                    float* __restrict__ x) {
    const int row = blockIdx.x;
    const int id = ids[row];
    const float4* src = (const float4*)(emb + (size_t)id * D_SZ);
    float4* dst = (float4*)(x + (size_t)row * D_SZ);
    dst[threadIdx.x] = src[threadIdx.x];
}

// ---------------------------------------------------------------------------
// RMSNorm: fp32 in, fp16 out (GEMM A-operand)
// ---------------------------------------------------------------------------
__global__ __launch_bounds__(256) void rmsnorm_kernel(const float* __restrict__ x,
                                                      const float* __restrict__ w,
                                                      _Float16* __restrict__ out) {
    const int row = blockIdx.x;
    const int tid = threadIdx.x;
    const float4 v = ((const float4*)(x + (size_t)row * D_SZ))[tid];
    float ss = v.x * v.x + v.y * v.y + v.z * v.z + v.w * v.w;
#pragma unroll
    for (int off = 32; off > 0; off >>= 1) ss += __shfl_down(ss, off, 64);
    __shared__ float red[4];
    if ((tid & 63) == 0) red[tid >> 6] = ss;
    __syncthreads();
    const float tot = red[0] + red[1] + red[2] + red[3];
    const float inv = 1.0f / (sqrtf(tot * (1.0f / (float)D_SZ)) + 1e-5f);
    const float4 wv = ((const float4*)w)[tid];
    half4 o = {(_Float16)(v.x * inv * wv.x), (_Float16)(v.y * inv * wv.y),
               (_Float16)(v.z * inv * wv.z), (_Float16)(v.w * inv * wv.w)};
    ((half4*)(out + (size_t)row * D_SZ))[tid] = o;
}

// ---------------------------------------------------------------------------
// MFMA fp16 GEMM (NT): C[M,N] = A[M,K] * B[N,K]^T, fp32 accumulate.
// 128x128 tile, BK=32, 4 waves (2x2), each wave 64x64 = 4x4 frags of 16x16x32.
// EPI: 0 = Cf(f32) store; 1 = Cf += ; 2 = Ch(f16) = swish(v);
//      3 = Ch(f16) = AUXh * v (in-place swiglu); 4 = qkv split store (fp16)
// ---------------------------------------------------------------------------
template <int EPI>
__global__ __launch_bounds__(256) void hgemm(const _Float16* __restrict__ A,
                                             const _Float16* __restrict__ B,
                                             float* __restrict__ Cf,
                                             _Float16* Ch,
                                             const _Float16* AUXh,
                                             _Float16* Cq,
                                             _Float16* Ck,
                                             _Float16* Cv,
                                             int M, int N, int K) {
    __shared__ __align__(16) _Float16 As[128 * 32];
    __shared__ __align__(16) _Float16 Bs[128 * 32];
    const int tid = threadIdx.x;
    const int lane = tid & 63;
    const int wave = tid >> 6;
    const int wr = wave >> 1, wc = wave & 1;
    const int l15 = lane & 15, g = lane >> 4;
    const int m0 = blockIdx.y * 128, n0 = blockIdx.x * 128;

    const int offA0 = wave * 2048 + lane * 16;
    const int offA1 = offA0 + 1024;
    const int rA0 = offA0 >> 6, kA0 = offA0 & 63;
    const int rA1 = offA1 >> 6, kA1 = offA1 & 63;
    const char* gA0 = (const char*)(A + (size_t)(m0 + rA0) * K) + kA0;
    const char* gA1 = (const char*)(A + (size_t)(m0 + rA1) * K) + kA1;
    const char* gB0 = (const char*)(B + (size_t)(n0 + rA0) * K) + kA0;
    const char* gB1 = (const char*)(B + (size_t)(n0 + rA1) * K) + kA1;
    char* lA0 = (char*)As + wave * 2048;
    char* lA1 = lA0 + 1024;
    char* lB0 = (char*)Bs + wave * 2048;
    char* lB1 = lB0 + 1024;

    floatx4 acc[4][4];
#pragma unroll
    for (int i = 0; i < 4; i++)
#pragma unroll
        for (int j = 0; j < 4; j++) acc[i][j] = 0;

    for (int kk = 0; kk < K; kk += 32) {
        __syncthreads();
        gload16(gA0, lA0);
        gload16(gA1, lA1);
        gload16(gB0, lB0);
        gload16(gB1, lB1);
        gA0 += 64; gA1 += 64; gB0 += 64; gB1 += 64;
        __syncthreads();
        half8 aF[4], bF[4];
#pragma unroll
        for (int i = 0; i < 4; i++)
            aF[i] = *(const half8*)&As[(wr * 64 + i * 16 + l15) * 32 + g * 8];
#pragma unroll
        for (int j = 0; j < 4; j++)
            bF[j] = *(const half8*)&Bs[(wc * 64 + j * 16 + l15) * 32 + g * 8];
#pragma unroll
        for (int i = 0; i < 4; i++)
#pragma unroll
            for (int j = 0; j < 4; j++)
                acc[i][j] = __builtin_amdgcn_mfma_f32_16x16x32_f16(aF[i], bF[j], acc[i][j], 0, 0, 0);
    }

    const int rb = m0 + wr * 64 + g * 4;
    const int cb = n0 + wc * 64 + l15;
    _Float16* Cx = nullptr;
    int cbq = cb;
    if (EPI == 4) {
        const int sel = n0 >> 10;
        Cx = sel == 0 ? Cq : (sel == 1 ? Ck : Cv);
        cbq = cb - sel * 1024;
    }
#pragma unroll
    for (int i = 0; i < 4; i++) {
#pragma unroll
        for (int e = 0; e < 4; e++) {
            const int row = rb + i * 16 + e;
#pragma unroll
            for (int j = 0; j < 4; j++) {
                const float v = acc[i][j][e];
                if (EPI == 0) {
                    Cf[(size_t)row * N + cb + j * 16] = v;
                } else if (EPI == 1) {
                    Cf[(size_t)row * N + cb + j * 16] += v;
                } else if (EPI == 2) {
                    Ch[(size_t)row * N + cb + j * 16] =
                        (_Float16)(v / (1.0f + __expf(-v)));
                } else if (EPI == 3) {
                    const size_t idx = (size_t)row * N + cb + j * 16;
                    Ch[idx] = (_Float16)((float)AUXh[idx] * v);
                } else {
                    Cx[(size_t)row * 1024 + cbq + j * 16] = (_Float16)v;
                }
            }
        }
    }
}

// ---------------------------------------------------------------------------
// RoPE in-place on fp16 q and k, 4 pairs (8 elems) per thread
// ---------------------------------------------------------------------------
__global__ __launch_bounds__(256) void rope_h(_Float16* __restrict__ q,
                                              _Float16* __restrict__ k, int total8) {
    const int idx = blockIdx.x * 256 + threadIdx.x;
    if (idx >= total8) return;
    const int n = idx >> 7;       // row (D/8 = 128 chunks per row)
    const int c = idx & 127;
    const int pos = n & (S_SZ - 1);
    const size_t base = (size_t)n * D_SZ + c * 8;
    half8 qv = *(half8*)(q + base);
    half8 kv = *(half8*)(k + base);
#pragma unroll
    for (int cc = 0; cc < 4; ++cc) {
        const int i = (c * 4 + cc) & 31;   // pair index within head
        const float inv_freq = powf(10000.0f, -(float)(2 * i) * (1.0f / 64.0f));
        float sn, cs;
        sincosf((float)pos * inv_freq, &sn, &cs);
        const float q1 = (float)qv[2 * cc], q2 = (float)qv[2 * cc + 1];
        qv[2 * cc]     = (_Float16)(q1 * cs - q2 * sn);
        qv[2 * cc + 1] = (_Float16)(q1 * sn + q2 * cs);
        const float k1 = (float)kv[2 * cc], k2 = (float)kv[2 * cc + 1];
        kv[2 * cc]     = (_Float16)(k1 * cs - k2 * sn);
        kv[2 * cc + 1] = (_Float16)(k1 * sn + k2 * cs);
    }
    *(half8*)(q + base) = qv;
    *(half8*)(k + base) = kv;
}

// ---------------------------------------------------------------------------
// Per-head V transpose: vh[b,s,h*64+d] -> vt[(b*16+h)*64+d][s]
// ---------------------------------------------------------------------------
__global__ __launch_bounds__(256) void vtrans(const _Float16* __restrict__ vh,
                                              _Float16* __restrict__ vt) {
    __shared__ __align__(16) _Float16 Ls[64][80];
    const int t = threadIdx.x;
    const int s0 = blockIdx.x * 64;
    const int bh = blockIdx.y;
    const int b = bh >> 4, h = bh & 15;
#pragma unroll
    for (int p = 0; p < 2; ++p) {
        const int sl = p * 32 + (t >> 3);
        const int d = (t & 7) * 8;
        *(half8*)&Ls[sl][d] =
            *(const half8*)&vh[((size_t)b * S_SZ + s0 + sl) * D_SZ + h * 64 + d];
    }
    __syncthreads();
#pragma unroll
    for (int p = 0; p < 2; ++p) {
        const int d = p * 32 + (t >> 3);
        const int sc = (t & 7) * 8;
        half8 v;
#pragma unroll
        for (int j = 0; j < 8; ++j) v[j] = Ls[sc + j][d];
        *(half8*)&vt[((size_t)bh * 64 + d) * S_SZ + s0 + sc] = v;
    }
}

// ---------------------------------------------------------------------------
// MFMA flash attention (causal), fp16 in/out, fp32 softmax state.
// Grid (S/64, B*H), 256 threads = 4 waves. Wave rows interleaved:
// q = qbase + r*4 + wave (r = fragment row 0..15). K/V fetched per-fragment
// directly from global (L2-resident). P via per-wave LDS round-trip.
// ---------------------------------------------------------------------------
__global__ __launch_bounds__(256) void attn_mfma(const _Float16* __restrict__ qh,
                                                 const _Float16* __restrict__ kh,
                                                 const _Float16* __restrict__ vt,
                                                 _Float16* __restrict__ o) {
    __shared__ __align__(16) _Float16 Ps[4][16][88];
    const int tid = threadIdx.x;
    const int lane = tid & 63, wave = tid >> 6;
    const int l15 = lane & 15, g = lane >> 4;
    const int bx = blockIdx.x;
    const int b = blockIdx.y >> 4, h = blockIdx.y & 15;
    const int qbase = bx * 64;
    const size_t tokb = (size_t)b * S_SZ;
    const int qrow = qbase + l15 * 4 + wave;

    half8 qA[2];
    qA[0] = *(const half8*)&qh[(tokb + qrow) * D_SZ + h * 64 + g * 8];
    qA[1] = *(const half8*)&qh[(tokb + qrow) * D_SZ + h * 64 + 32 + g * 8];

    floatx4 accO[4];
#pragma unroll
    for (int s = 0; s < 4; s++) accO[s] = 0;
    float m_[4] = {NEG_INF, NEG_INF, NEG_INF, NEG_INF};
    float l_[4] = {0.0f, 0.0f, 0.0f, 0.0f};

    const _Float16* Kb = kh + tokb * D_SZ + h * 64;
    const _Float16* Vb = vt + (size_t)blockIdx.y * 64 * S_SZ;

    for (int kt = 0; kt <= bx; ++kt) {
        const int kv0 = kt * 64;
        // ---- S = Q K^T (scaled) ----
        floatx4 accS[4];
#pragma unroll
        for (int sub = 0; sub < 4; ++sub) {
            accS[sub] = 0;
#pragma unroll
            for (int kk = 0; kk < 2; ++kk) {
                half8 kB = *(const half8*)&Kb[(size_t)(kv0 + sub * 16 + l15) * D_SZ + kk * 32 + g * 8];
                accS[sub] = __builtin_amdgcn_mfma_f32_16x16x32_f16(qA[kk], kB, accS[sub], 0, 0, 0);
            }
        }
        const bool diag = (kt == bx);
        float sv[4][4];
        float mx[4] = {NEG_INF, NEG_INF, NEG_INF, NEG_INF};
#pragma unroll
        for (int sub = 0; sub < 4; ++sub)
#pragma unroll
            for (int e = 0; e < 4; ++e) {
                float s = accS[sub][e] * 0.125f;
                if (diag && (kv0 + sub * 16 + l15 > qbase + (g * 4 + e) * 4 + wave))
                    s = NEG_INF;
                sv[sub][e] = s;
                mx[e] = fmaxf(mx[e], s);
            }
#pragma unroll
        for (int msk = 1; msk <= 8; msk <<= 1)
#pragma unroll
            for (int e = 0; e < 4; ++e)
                mx[e] = fmaxf(mx[e], __shfl_xor(mx[e], msk, 64));
        float sf[4];
#pragma unroll
        for (int e = 0; e < 4; ++e) {
            const float mn = fmaxf(m_[e], mx[e]);
            sf[e] = __expf(m_[e] - mn);
            m_[e] = mn;
        }
        float rs[4] = {0.0f, 0.0f, 0.0f, 0.0f};
#pragma unroll
        for (int sub = 0; sub < 4; ++sub)
#pragma unroll
            for (int e = 0; e < 4; ++e) {
                const float p = __expf(sv[sub][e] - m_[e]);
                sv[sub][e] = p;
                rs[e] += p;
            }
#pragma unroll
        for (int msk = 1; msk <= 8; msk <<= 1)
#pragma unroll
            for (int e = 0; e < 4; ++e)
                rs[e] += __shfl_xor(rs[e], msk, 64);
#pragma unroll
        for (int e = 0; e < 4; ++e) l_[e] = l_[e] * sf[e] + rs[e];
#pragma unroll
        for (int sub = 0; sub < 4; ++sub)
#pragma unroll
            for (int e = 0; e < 4; ++e) accO[sub][e] *= sf[e];
        // ---- P -> LDS -> A-frag ----
#pragma unroll
        for (int sub = 0; sub < 4; ++sub)
#pragma unroll
            for (int e = 0; e < 4; ++e)
                Ps[wave][g * 4 + e][sub * 16 + l15] = (_Float16)sv[sub][e];
        half8 aP[2];
        aP[0] = *(const half8*)&Ps[wave][l15][g * 8];
        aP[1] = *(const half8*)&Ps[wave][l15][32 + g * 8];
        // ---- O += P V ----
#pragma unroll
        for (int sub = 0; sub < 4; ++sub)
#pragma unroll
            for (int kk = 0; kk < 2; ++kk) {
                half8 vB = *(const half8*)&Vb[(size_t)(sub * 16 + l15) * S_SZ + kv0 + kk * 32 + g * 8];
                accO[sub] = __builtin_amdgcn_mfma_f32_16x16x32_f16(aP[kk], vB, accO[sub], 0, 0, 0);
            }
    }
    // ---- store O / l ----
#pragma unroll
    for (int sub = 0; sub < 4; ++sub)
#pragma unroll
        for (int e = 0; e < 4; ++e) {
            const float ov = accO[sub][e] / l_[e];
            o[(tokb + qbase + (g * 4 + e) * 4 + wave) * D_SZ + h * 64 + sub * 16 + l15] =
                (_Float16)ov;
        }
}

// ---------------------------------------------------------------------------
// Host-side launch
// ---------------------------------------------------------------------------
extern "C" void kernel_launch(void* const* d_in, const int* in_sizes, int n_in,
                              void* d_out, int out_size, void* d_ws, size_t ws_size,
                              hipStream_t stream) {
    const int*   token_ids  = (const int*)d_in[0];
    const float* tok_emb    = (const float*)d_in[1];
    const float* lm_head_w  = (const float*)d_in[2];
    const float* ln_final_w = (const float*)d_in[3];
    const float* q_w        = (const float*)d_in[4];
    const float* k_w        = (const float*)d_in[5];
    const float* v_w        = (const float*)d_in[6];
    const float* o_w        = (const float*)d_in[7];
    const float* ln1_w      = (const float*)d_in[8];
    const float* ln2_w      = (const float*)d_in[9];
    const float* w1         = (const float*)d_in[10];
    const float* w2         = (const float*)d_in[11];
    const float* w3         = (const float*)d_in[12];
    float* out = (float*)d_out;

    char* W = (char*)d_ws;
    const size_t MB = 1u << 20;
    float*    x    = (float*)(W + 0);           // 8 MB
    _Float16* h    = (_Float16*)(W + 8 * MB);   // 4 MB
    _Float16* ao   = (_Float16*)(W + 12 * MB);  // 4 MB
    _Float16* wq   = (_Float16*)(W + 16 * MB);  // 2 MB each, q/k/v contiguous
    _Float16* wo   = (_Float16*)(W + 22 * MB);  // 2 MB
    _Float16* ww1  = (_Float16*)(W + 24 * MB);  // 8 MB
    _Float16* ww3  = (_Float16*)(W + 32 * MB);  // 8 MB
    _Float16* ww2  = (_Float16*)(W + 40 * MB);  // 8 MB
    _Float16* qh   = (_Float16*)(W + 48 * MB);  // 4 MB
    _Float16* kh   = (_Float16*)(W + 52 * MB);  // 4 MB
    _Float16* vh   = (_Float16*)(W + 56 * MB);  // 4 MB
    _Float16* vt   = (_Float16*)(W + 60 * MB);  // 4 MB
    _Float16* ff1h = (_Float16*)(W + 64 * MB);  // 16 MB -> 80 MB
    _Float16* whead = (_Float16*)(W + 24 * MB); // 62.5 MB, overlaps dead bufs

    embed_kernel<<<NTOK, 256, 0, stream>>>(token_ids, tok_emb, x);

    const int nDD8 = D_SZ * D_SZ / 8;
    const int nFD8 = F_SZ * D_SZ / 8;
    const dim3 gQKV(3 * D_SZ / 128, NTOK / 128);
    const dim3 gD(D_SZ / 128, NTOK / 128);
    const dim3 gF(F_SZ / 128, NTOK / 128);
    const dim3 gATT(S_SZ / 64, B_SZ * H_SZ);    // (16,32)
    const dim3 gVT(S_SZ / 64, B_SZ * H_SZ);
    const int rope8 = NTOK * D_SZ / 8;          // 262144

    for (int l = 0; l < L_SZ; l++) {
        const size_t oDD = (size_t)l * D_SZ * D_SZ;
        const size_t oFD = (size_t)l * F_SZ * D_SZ;
        rmsnorm_kernel<<<NTOK, 256, 0, stream>>>(x, ln1_w + (size_t)l * D_SZ, h);
        f2h<<<(nDD8 + 255) / 256, 256, 0, stream>>>(q_w + oDD, wq, nDD8);
        f2h<<<(nDD8 + 255) / 256, 256, 0, stream>>>(k_w + oDD, wq + (1u << 20), nDD8);
        f2h<<<(nDD8 + 255) / 256, 256, 0, stream>>>(v_w + oDD, wq + (2u << 20), nDD8);
        f2h<<<(nDD8 + 255) / 256, 256, 0, stream>>>(o_w + oDD, wo, nDD8);
        hgemm<4><<<gQKV, 256, 0, stream>>>(h, wq, nullptr, nullptr, nullptr,
                                           qh, kh, vh, NTOK, 3 * D_SZ, D_SZ);
        rope_h<<<rope8 / 256, 256, 0, stream>>>(qh, kh, rope8);
        vtrans<<<gVT, 256, 0, stream>>>(vh, vt);
        attn_mfma<<<gATT, 256, 0, stream>>>(qh, kh, vt, ao);
        hgemm<1><<<gD, 256, 0, stream>>>(ao, wo, x, nullptr, nullptr,
                                         nullptr, nullptr, nullptr, NTOK, D_SZ, D_SZ);
        rmsnorm_kernel<<<NTOK, 256, 0, stream>>>(x, ln2_w + (size_t)l * D_SZ, h);
        f2h<<<(nFD8 + 255) / 256, 256, 0, stream>>>(w1 + oFD, ww1, nFD8);
        f2h<<<(nFD8 + 255) / 256, 256, 0, stream>>>(w3 + oFD, ww3, nFD8);
        f2h<<<(nFD8 + 255) / 256, 256, 0, stream>>>(w2 + oFD, ww2, nFD8);
        hgemm<2><<<gF, 256, 0, stream>>>(h, ww1, nullptr, ff1h, nullptr,
                                         nullptr, nullptr, nullptr, NTOK, F_SZ, D_SZ);
        hgemm<3><<<gF, 256, 0, stream>>>(h, ww3, nullptr, ff1h, ff1h,
                                         nullptr, nullptr, nullptr, NTOK, F_SZ, D_SZ);
        hgemm<1><<<gD, 256, 0, stream>>>(ff1h, ww2, x, nullptr, nullptr,
                                         nullptr, nullptr, nullptr, NTOK, D_SZ, F_SZ);
    }
    rmsnorm_kernel<<<NTOK, 256, 0, stream>>>(x, ln_final_w, h);
    const int nVD8 = V_SZ * D_SZ / 8;
    f2h<<<(nVD8 + 255) / 256, 256, 0, stream>>>(lm_head_w, whead, nVD8);
    const dim3 gOUT(V_SZ / 128, NTOK / 128);
    hgemm<0><<<gOUT, 256, 0, stream>>>(h, whead, out, nullptr, nullptr,
                                       nullptr, nullptr, nullptr, NTOK, V_SZ, D_SZ);
}

// Round 4
// 1454.888 us; speedup vs baseline: 7.1817x; 1.0763x over previous
//
#include <hip/hip_runtime.h>
#include <math.h>

// Problem constants (from reference)
#define V_SZ 32000
#define D_SZ 1024
#define H_SZ 16
#define L_SZ 4
#define F_SZ 4096
#define S_SZ 1024
#define B_SZ 2
#define DK 64              // D/H
#define NTOK (B_SZ * S_SZ) // 2048
#define NEG_INF -3.0e38f

typedef _Float16 half8 __attribute__((ext_vector_type(8)));
typedef _Float16 half4 __attribute__((ext_vector_type(4)));
typedef float floatx4 __attribute__((ext_vector_type(4)));

// async global->LDS, 16B per lane; lds dest is wave-uniform base + lane*16.
__device__ __forceinline__ void gload16(const void* g, void* l) {
    __builtin_amdgcn_global_load_lds(
        (const __attribute__((address_space(1))) unsigned int*)g,
        (__attribute__((address_space(3))) unsigned int*)l, 16, 0, 0);
}

// ---------------------------------------------------------------------------
// fp32 -> fp16 weight conversion, batched 4 sources (attn weights, 1M elems ea)
// ---------------------------------------------------------------------------
__global__ __launch_bounds__(256) void f2h4(const float* __restrict__ s0,
                                            const float* __restrict__ s1,
                                            const float* __restrict__ s2,
                                            const float* __restrict__ s3,
                                            _Float16* __restrict__ d, int n8each) {
    const int i = blockIdx.x * 256 + threadIdx.x;
    const int sel = i / n8each;
    const int off = i - sel * n8each;
    const float* s = sel == 0 ? s0 : (sel == 1 ? s1 : (sel == 2 ? s2 : s3));
    const float4 a = ((const float4*)s)[2 * off];
    const float4 b = ((const float4*)s)[2 * off + 1];
    half8 h = {(_Float16)a.x, (_Float16)a.y, (_Float16)a.z, (_Float16)a.w,
               (_Float16)b.x, (_Float16)b.y, (_Float16)b.z, (_Float16)b.w};
    ((half8*)d)[i] = h;
}

// batched 3 sources (ffn weights, 4M elems each)
__global__ __launch_bounds__(256) void f2h3(const float* __restrict__ s0,
                                            const float* __restrict__ s1,
                                            const float* __restrict__ s2,
                                            _Float16* __restrict__ d, int n8each) {
    const int i = blockIdx.x * 256 + threadIdx.x;
    const int sel = i / n8each;
    const int off = i - sel * n8each;
    const float* s = sel == 0 ? s0 : (sel == 1 ? s1 : s2);
    const float4 a = ((const float4*)s)[2 * off];
    const float4 b = ((const float4*)s)[2 * off + 1];
    half8 h = {(_Float16)a.x, (_Float16)a.y, (_Float16)a.z, (_Float16)a.w,
               (_Float16)b.x, (_Float16)b.y, (_Float16)b.z, (_Float16)b.w};
    ((half8*)d)[i] = h;
}

__global__ __launch_bounds__(256) void f2h(const float* __restrict__ in,
                                           _Float16* __restrict__ out, int n8) {
    const int i = blockIdx.x * 256 + threadIdx.x;
    if (i >= n8) return;
    const float4 a = ((const float4*)in)[2 * i];
    const float4 b = ((const float4*)in)[2 * i + 1];
    half8 h = {(_Float16)a.x, (_Float16)a.y, (_Float16)a.z, (_Float16)a.w,
               (_Float16)b.x, (_Float16)b.y, (_Float16)b.z, (_Float16)b.w};
    ((half8*)out)[i] = h;
}

// ---------------------------------------------------------------------------
// Embedding gather (fp32)
// ---------------------------------------------------------------------------
__global__ __launch_bounds__(256) void embed_kernel(const int* __restrict__ ids,
                                                    const float* __restrict__ emb,
                                                    float* __restrict__ x) {
    const int row = blockIdx.x;
    const int id = ids[row];
    const float4* src = (const float4*)(emb + (size_t)id * D_SZ);
    float4* dst = (float4*)(x + (size_t)row * D_SZ);
    dst[threadIdx.x] = src[threadIdx.x];
}

// ---------------------------------------------------------------------------
// RMSNorm: fp32 in, fp16 out
// ---------------------------------------------------------------------------
__global__ __launch_bounds__(256) void rmsnorm_kernel(const float* __restrict__ x,
                                                      const float* __restrict__ w,
                                                      _Float16* __restrict__ out) {
    const int row = blockIdx.x;
    const int tid = threadIdx.x;
    const float4 v = ((const float4*)(x + (size_t)row * D_SZ))[tid];
    float ss = v.x * v.x + v.y * v.y + v.z * v.z + v.w * v.w;
#pragma unroll
    for (int off = 32; off > 0; off >>= 1) ss += __shfl_down(ss, off, 64);
    __shared__ float red[4];
    if ((tid & 63) == 0) red[tid >> 6] = ss;
    __syncthreads();
    const float tot = red[0] + red[1] + red[2] + red[3];
    const float inv = 1.0f / (sqrtf(tot * (1.0f / (float)D_SZ)) + 1e-5f);
    const float4 wv = ((const float4*)w)[tid];
    half4 o = {(_Float16)(v.x * inv * wv.x), (_Float16)(v.y * inv * wv.y),
               (_Float16)(v.z * inv * wv.z), (_Float16)(v.w * inv * wv.w)};
    ((half4*)(out + (size_t)row * D_SZ))[tid] = o;
}

// ---------------------------------------------------------------------------
// MFMA fp16 GEMM (NT): C[M,N] = A[M,K] * B[N,K]^T, fp32 accumulate.
// 128x128 tile, BK=32, 4 waves (2x2). 2-phase prefetch: double-buffered LDS,
// next tile's global_load_lds issued BEFORE current tile's ds_read+MFMA,
// single __syncthreads per K-step (drain happens after MFMA -> overlap).
// Block order: bijective XCD chunk swizzle (m204); within chunk MFAST picks
// which grid dim runs fastest (share the larger operand's panel in L2).
// EPI: 0 = Cf store; 1 = Cf += ; 2 = Ch = swish(v); 3 = Ch = AUXh * v;
//      4 = qkv split store (fp16) with fused RoPE on q,k
// ---------------------------------------------------------------------------
template <int EPI, bool MFAST>
__global__ __launch_bounds__(256) void hgemm(const _Float16* __restrict__ A,
                                             const _Float16* __restrict__ B,
                                             float* __restrict__ Cf,
                                             _Float16* Ch,
                                             const _Float16* AUXh,
                                             _Float16* Cq,
                                             _Float16* Ck,
                                             _Float16* Cv,
                                             int M, int N, int K) {
    __shared__ __align__(16) _Float16 As[2][128 * 32];
    __shared__ __align__(16) _Float16 Bs[2][128 * 32];
    const int tid = threadIdx.x;
    const int lane = tid & 63;
    const int wave = tid >> 6;
    const int wr = wave >> 1, wc = wave & 1;
    const int l15 = lane & 15, g = lane >> 4;

    // block swizzle: contiguous logical chunk per XCD (bijective, m204)
    const int gm = M >> 7, gn = N >> 7, nwg = gm * gn;
    const int orig = blockIdx.x;
    const int q8 = nwg >> 3, r8 = nwg & 7, xcd = orig & 7, j8 = orig >> 3;
    const int wgid = (xcd < r8 ? xcd * (q8 + 1) : r8 * (q8 + 1) + (xcd - r8) * q8) + j8;
    const int bm = MFAST ? (wgid % gm) : (wgid / gn);
    const int bn = MFAST ? (wgid / gm) : (wgid % gn);
    const int m0 = bm * 128, n0 = bn * 128;

    // staging slots: each wave covers 2KB of A-tile and 2KB of B-tile
    const int offA0 = wave * 2048 + lane * 16;
    const int offA1 = offA0 + 1024;
    const int rA0 = offA0 >> 6, kA0 = offA0 & 63;
    const int rA1 = offA1 >> 6, kA1 = offA1 & 63;
    const char* gA0 = (const char*)(A + (size_t)(m0 + rA0) * K) + kA0;
    const char* gA1 = (const char*)(A + (size_t)(m0 + rA1) * K) + kA1;
    const char* gB0 = (const char*)(B + (size_t)(n0 + rA0) * K) + kA0;
    const char* gB1 = (const char*)(B + (size_t)(n0 + rA1) * K) + kA1;

#define STAGE(buf)                                     \
    do {                                               \
        gload16(gA0, (char*)As[buf] + offA0);          \
        gload16(gA1, (char*)As[buf] + offA1);          \
        gload16(gB0, (char*)Bs[buf] + offA0);          \
        gload16(gB1, (char*)Bs[buf] + offA1);          \
        gA0 += 64; gA1 += 64; gB0 += 64; gB1 += 64;    \
    } while (0)

    floatx4 acc[4][4];
#pragma unroll
    for (int i = 0; i < 4; i++)
#pragma unroll
        for (int j = 0; j < 4; j++) acc[i][j] = 0;

    STAGE(0);
    __syncthreads();   // drain prologue stage
    int cur = 0;
    for (int kk = 0; kk < K; kk += 32) {
        if (kk + 32 < K) STAGE(cur ^ 1);   // prefetch overlaps MFMA below
        half8 aF[4], bF[4];
#pragma unroll
        for (int i = 0; i < 4; i++)
            aF[i] = *(const half8*)&As[cur][(wr * 64 + i * 16 + l15) * 32 + g * 8];
#pragma unroll
        for (int j = 0; j < 4; j++)
            bF[j] = *(const half8*)&Bs[cur][(wc * 64 + j * 16 + l15) * 32 + g * 8];
#pragma unroll
        for (int i = 0; i < 4; i++)
#pragma unroll
            for (int j = 0; j < 4; j++)
                acc[i][j] = __builtin_amdgcn_mfma_f32_16x16x32_f16(aF[i], bF[j], acc[i][j], 0, 0, 0);
        __syncthreads();   // drains prefetch (vmcnt) + LDS reads (lgkm)
        cur ^= 1;
    }
#undef STAGE

    // epilogue: D frag mapping col = lane&15, row = (lane>>4)*4 + e
    const int rb = m0 + wr * 64 + g * 4;
    const int cb = n0 + wc * 64 + l15;
    if (EPI == 4) {
        const int sel = n0 >> 10;   // tile never crosses a 1024 boundary
        _Float16* Cx = sel == 0 ? Cq : (sel == 1 ? Ck : Cv);
        const int cb0 = cb - sel * 1024;
#pragma unroll
        for (int i = 0; i < 4; i++) {
#pragma unroll
            for (int e = 0; e < 4; e++) {
                const int row = rb + i * 16 + e;
                const int pos = row & (S_SZ - 1);
#pragma unroll
                for (int j = 0; j < 4; j++) {
                    float v = acc[i][j][e];
                    const int col = cb0 + j * 16;
                    if (sel < 2) {
                        // fused RoPE: pair partner value lives in lane^1
                        const float p = __shfl_xor(v, 1, 64);
                        const int pi = (col & 63) >> 1;   // pair idx in head
                        // inv_freq = 10000^(-2*pi/64) = exp2(-pi*log2(1e4)/32)
                        const float invf = exp2f((float)pi * -0.41524101186f);
                        float sn, cs;
                        sincosf((float)pos * invf, &sn, &cs);
                        v = (col & 1) ? (p * sn + v * cs) : (v * cs - p * sn);
                    }
                    Cx[(size_t)row * 1024 + col] = (_Float16)v;
                }
            }
        }
        return;
    }
#pragma unroll
    for (int i = 0; i < 4; i++) {
#pragma unroll
        for (int e = 0; e < 4; e++) {
            const int row = rb + i * 16 + e;
#pragma unroll
            for (int j = 0; j < 4; j++) {
                const float v = acc[i][j][e];
                if (EPI == 0) {
                    Cf[(size_t)row * N + cb + j * 16] = v;
                } else if (EPI == 1) {
                    Cf[(size_t)row * N + cb + j * 16] += v;
                } else if (EPI == 2) {
                    Ch[(size_t)row * N + cb + j * 16] =
                        (_Float16)(v / (1.0f + __expf(-v)));
                } else if (EPI == 3) {
                    const size_t idx = (size_t)row * N + cb + j * 16;
                    Ch[idx] = (_Float16)((float)AUXh[idx] * v);
                }
            }
        }
    }
}

// ---------------------------------------------------------------------------
// Per-head V transpose: vh[b,s,h*64+d] -> vt[(b*16+h)*64+d][s]
// ---------------------------------------------------------------------------
__global__ __launch_bounds__(256) void vtrans(const _Float16* __restrict__ vh,
                                              _Float16* __restrict__ vt) {
    __shared__ __align__(16) _Float16 Ls[64][80];
    const int t = threadIdx.x;
    const int s0 = blockIdx.x * 64;
    const int bh = blockIdx.y;
    const int b = bh >> 4, h = bh & 15;
#pragma unroll
    for (int p = 0; p < 2; ++p) {
        const int sl = p * 32 + (t >> 3);
        const int d = (t & 7) * 8;
        *(half8*)&Ls[sl][d] =
            *(const half8*)&vh[((size_t)b * S_SZ + s0 + sl) * D_SZ + h * 64 + d];
    }
    __syncthreads();
#pragma unroll
    for (int p = 0; p < 2; ++p) {
        const int d = p * 32 + (t >> 3);
        const int sc = (t & 7) * 8;
        half8 v;
#pragma unroll
        for (int j = 0; j < 8; ++j) v[j] = Ls[sc + j][d];
        *(half8*)&vt[((size_t)bh * 64 + d) * S_SZ + s0 + sc] = v;
    }
}

// ---------------------------------------------------------------------------
// MFMA flash attention (causal), fp16 in/out, fp32 softmax state.
// ---------------------------------------------------------------------------
__global__ __launch_bounds__(256) void attn_mfma(const _Float16* __restrict__ qh,
                                                 const _Float16* __restrict__ kh,
                                                 const _Float16* __restrict__ vt,
                                                 _Float16* __restrict__ o) {
    __shared__ __align__(16) _Float16 Ps[4][16][88];
    const int tid = threadIdx.x;
    const int lane = tid & 63, wave = tid >> 6;
    const int l15 = lane & 15, g = lane >> 4;
    const int bx = blockIdx.x;
    const int b = blockIdx.y >> 4, h = blockIdx.y & 15;
    const int qbase = bx * 64;
    const size_t tokb = (size_t)b * S_SZ;
    const int qrow = qbase + l15 * 4 + wave;

    half8 qA[2];
    qA[0] = *(const half8*)&qh[(tokb + qrow) * D_SZ + h * 64 + g * 8];
    qA[1] = *(const half8*)&qh[(tokb + qrow) * D_SZ + h * 64 + 32 + g * 8];

    floatx4 accO[4];
#pragma unroll
    for (int s = 0; s < 4; s++) accO[s] = 0;
    float m_[4] = {NEG_INF, NEG_INF, NEG_INF, NEG_INF};
    float l_[4] = {0.0f, 0.0f, 0.0f, 0.0f};

    const _Float16* Kb = kh + tokb * D_SZ + h * 64;
    const _Float16* Vb = vt + (size_t)blockIdx.y * 64 * S_SZ;

    for (int kt = 0; kt <= bx; ++kt) {
        const int kv0 = kt * 64;
        floatx4 accS[4];
#pragma unroll
        for (int sub = 0; sub < 4; ++sub) {
            accS[sub] = 0;
#pragma unroll
            for (int kk = 0; kk < 2; ++kk) {
                half8 kB = *(const half8*)&Kb[(size_t)(kv0 + sub * 16 + l15) * D_SZ + kk * 32 + g * 8];
                accS[sub] = __builtin_amdgcn_mfma_f32_16x16x32_f16(qA[kk], kB, accS[sub], 0, 0, 0);
            }
        }
        const bool diag = (kt == bx);
        float sv[4][4];
        float mx[4] = {NEG_INF, NEG_INF, NEG_INF, NEG_INF};
#pragma unroll
        for (int sub = 0; sub < 4; ++sub)
#pragma unroll
            for (int e = 0; e < 4; ++e) {
                float s = accS[sub][e] * 0.125f;
                if (diag && (kv0 + sub * 16 + l15 > qbase + (g * 4 + e) * 4 + wave))
                    s = NEG_INF;
                sv[sub][e] = s;
                mx[e] = fmaxf(mx[e], s);
            }
#pragma unroll
        for (int msk = 1; msk <= 8; msk <<= 1)
#pragma unroll
            for (int e = 0; e < 4; ++e)
                mx[e] = fmaxf(mx[e], __shfl_xor(mx[e], msk, 64));
        float sf[4];
#pragma unroll
        for (int e = 0; e < 4; ++e) {
            const float mn = fmaxf(m_[e], mx[e]);
            sf[e] = __expf(m_[e] - mn);
            m_[e] = mn;
        }
        float rs[4] = {0.0f, 0.0f, 0.0f, 0.0f};
#pragma unroll
        for (int sub = 0; sub < 4; ++sub)
#pragma unroll
            for (int e = 0; e < 4; ++e) {
                const float p = __expf(sv[sub][e] - m_[e]);
                sv[sub][e] = p;
                rs[e] += p;
            }
#pragma unroll
        for (int msk = 1; msk <= 8; msk <<= 1)
#pragma unroll
            for (int e = 0; e < 4; ++e)
                rs[e] += __shfl_xor(rs[e], msk, 64);
#pragma unroll
        for (int e = 0; e < 4; ++e) l_[e] = l_[e] * sf[e] + rs[e];
#pragma unroll
        for (int sub = 0; sub < 4; ++sub)
#pragma unroll
            for (int e = 0; e < 4; ++e) accO[sub][e] *= sf[e];
#pragma unroll
        for (int sub = 0; sub < 4; ++sub)
#pragma unroll
            for (int e = 0; e < 4; ++e)
                Ps[wave][g * 4 + e][sub * 16 + l15] = (_Float16)sv[sub][e];
        half8 aP[2];
        aP[0] = *(const half8*)&Ps[wave][l15][g * 8];
        aP[1] = *(const half8*)&Ps[wave][l15][32 + g * 8];
#pragma unroll
        for (int sub = 0; sub < 4; ++sub)
#pragma unroll
            for (int kk = 0; kk < 2; ++kk) {
                half8 vB = *(const half8*)&Vb[(size_t)(sub * 16 + l15) * S_SZ + kv0 + kk * 32 + g * 8];
                accO[sub] = __builtin_amdgcn_mfma_f32_16x16x32_f16(aP[kk], vB, accO[sub], 0, 0, 0);
            }
    }
#pragma unroll
    for (int sub = 0; sub < 4; ++sub)
#pragma unroll
        for (int e = 0; e < 4; ++e) {
            const float ov = accO[sub][e] / l_[e];
            o[(tokb + qbase + (g * 4 + e) * 4 + wave) * D_SZ + h * 64 + sub * 16 + l15] =
                (_Float16)ov;
        }
}

// ---------------------------------------------------------------------------
// Host-side launch
// ---------------------------------------------------------------------------
extern "C" void kernel_launch(void* const* d_in, const int* in_sizes, int n_in,
                              void* d_out, int out_size, void* d_ws, size_t ws_size,
                              hipStream_t stream) {
    const int*   token_ids  = (const int*)d_in[0];
    const float* tok_emb    = (const float*)d_in[1];
    const float* lm_head_w  = (const float*)d_in[2];
    const float* ln_final_w = (const float*)d_in[3];
    const float* q_w        = (const float*)d_in[4];
    const float* k_w        = (const float*)d_in[5];
    const float* v_w        = (const float*)d_in[6];
    const float* o_w        = (const float*)d_in[7];
    const float* ln1_w      = (const float*)d_in[8];
    const float* ln2_w      = (const float*)d_in[9];
    const float* w1         = (const float*)d_in[10];
    const float* w2         = (const float*)d_in[11];
    const float* w3         = (const float*)d_in[12];
    float* out = (float*)d_out;

    char* W = (char*)d_ws;
    const size_t MB = 1u << 20;
    float*    x    = (float*)(W + 0);           // 8 MB
    _Float16* h    = (_Float16*)(W + 8 * MB);   // 4 MB
    _Float16* ao   = (_Float16*)(W + 12 * MB);  // 4 MB
    _Float16* wq   = (_Float16*)(W + 16 * MB);  // 8 MB: q/k/v/o contiguous
    _Float16* wo   = wq + 3 * (1u << 20);
    _Float16* ww1  = (_Float16*)(W + 24 * MB);  // 24 MB: w1/w3/w2 contiguous
    _Float16* ww3  = ww1 + (F_SZ * D_SZ);
    _Float16* ww2  = ww3 + (F_SZ * D_SZ);
    _Float16* qh   = (_Float16*)(W + 48 * MB);  // 4 MB
    _Float16* kh   = (_Float16*)(W + 52 * MB);  // 4 MB
    _Float16* vh   = (_Float16*)(W + 56 * MB);  // 4 MB
    _Float16* vt   = (_Float16*)(W + 60 * MB);  // 4 MB
    _Float16* ff1h = (_Float16*)(W + 64 * MB);  // 16 MB -> 80 MB
    _Float16* whead = (_Float16*)(W + 24 * MB); // 62.5 MB, overlaps dead ww*

    embed_kernel<<<NTOK, 256, 0, stream>>>(token_ids, tok_emb, x);

    const int nDD8 = D_SZ * D_SZ / 8;     // 131072
    const int nFD8 = F_SZ * D_SZ / 8;     // 524288
    const dim3 gQKV(3 * D_SZ / 128 * (NTOK / 128));   // 384
    const dim3 gD(D_SZ / 128 * (NTOK / 128));         // 128
    const dim3 gF(F_SZ / 128 * (NTOK / 128));         // 512
    const dim3 gATT(S_SZ / 64, B_SZ * H_SZ);
    const dim3 gVT(S_SZ / 64, B_SZ * H_SZ);

    for (int l = 0; l < L_SZ; l++) {
        const size_t oDD = (size_t)l * D_SZ * D_SZ;
        const size_t oFD = (size_t)l * F_SZ * D_SZ;
        rmsnorm_kernel<<<NTOK, 256, 0, stream>>>(x, ln1_w + (size_t)l * D_SZ, h);
        f2h4<<<4 * nDD8 / 256, 256, 0, stream>>>(q_w + oDD, k_w + oDD, v_w + oDD,
                                                 o_w + oDD, wq, nDD8);
        f2h3<<<3 * nFD8 / 256, 256, 0, stream>>>(w1 + oFD, w3 + oFD, w2 + oFD,
                                                 ww1, nFD8);
        hgemm<4, true><<<gQKV, 256, 0, stream>>>(h, wq, nullptr, nullptr, nullptr,
                                                 qh, kh, vh, NTOK, 3 * D_SZ, D_SZ);
        vtrans<<<gVT, 256, 0, stream>>>(vh, vt);
        attn_mfma<<<gATT, 256, 0, stream>>>(qh, kh, vt, ao);
        hgemm<1, false><<<gD, 256, 0, stream>>>(ao, wo, x, nullptr, nullptr,
                                                nullptr, nullptr, nullptr, NTOK, D_SZ, D_SZ);
        rmsnorm_kernel<<<NTOK, 256, 0, stream>>>(x, ln2_w + (size_t)l * D_SZ, h);
        hgemm<2, true><<<gF, 256, 0, stream>>>(h, ww1, nullptr, ff1h, nullptr,
                                               nullptr, nullptr, nullptr, NTOK, F_SZ, D_SZ);
        hgemm<3, true><<<gF, 256, 0, stream>>>(h, ww3, nullptr, ff1h, ff1h,
                                               nullptr, nullptr, nullptr, NTOK, F_SZ, D_SZ);
        hgemm<1, false><<<gD, 256, 0, stream>>>(ff1h, ww2, x, nullptr, nullptr,
                                                nullptr, nullptr, nullptr, NTOK, D_SZ, F_SZ);
    }
    rmsnorm_kernel<<<NTOK, 256, 0, stream>>>(x, ln_final_w, h);
    const int nVD8 = V_SZ * D_SZ / 8;
    f2h<<<(nVD8 + 255) / 256, 256, 0, stream>>>(lm_head_w, whead, nVD8);
    const dim3 gOUT(V_SZ / 128 * (NTOK / 128));       // 4000
    hgemm<0, true><<<gOUT, 256, 0, stream>>>(h, whead, out, nullptr, nullptr,
                                             nullptr, nullptr, nullptr, NTOK, V_SZ, D_SZ);
}

// Round 5
// 1286.047 us; speedup vs baseline: 8.1246x; 1.1313x over previous
//
#include <hip/hip_runtime.h>
#include <math.h>

// Problem constants (from reference)
#define V_SZ 32000
#define D_SZ 1024
#define H_SZ 16
#define L_SZ 4
#define F_SZ 4096
#define S_SZ 1024
#define B_SZ 2
#define DK 64              // D/H
#define NTOK (B_SZ * S_SZ) // 2048
#define NEG_INF -3.0e38f

typedef _Float16 half8 __attribute__((ext_vector_type(8)));
typedef _Float16 half4 __attribute__((ext_vector_type(4)));
typedef float floatx4 __attribute__((ext_vector_type(4)));

// async global->LDS, 16B per lane; lds dest is wave-uniform base + lane*16.
__device__ __forceinline__ void gload16(const void* g, void* l) {
    __builtin_amdgcn_global_load_lds(
        (const __attribute__((address_space(1))) unsigned int*)g,
        (__attribute__((address_space(3))) unsigned int*)l, 16, 0, 0);
}

// ---------------------------------------------------------------------------
// fp32 -> fp16 weight conversion, batched
// ---------------------------------------------------------------------------
__global__ __launch_bounds__(256) void f2h4(const float* __restrict__ s0,
                                            const float* __restrict__ s1,
                                            const float* __restrict__ s2,
                                            const float* __restrict__ s3,
                                            _Float16* __restrict__ d, int n8each) {
    const int i = blockIdx.x * 256 + threadIdx.x;
    const int sel = i / n8each;
    const int off = i - sel * n8each;
    const float* s = sel == 0 ? s0 : (sel == 1 ? s1 : (sel == 2 ? s2 : s3));
    const float4 a = ((const float4*)s)[2 * off];
    const float4 b = ((const float4*)s)[2 * off + 1];
    half8 h = {(_Float16)a.x, (_Float16)a.y, (_Float16)a.z, (_Float16)a.w,
               (_Float16)b.x, (_Float16)b.y, (_Float16)b.z, (_Float16)b.w};
    ((half8*)d)[i] = h;
}

__global__ __launch_bounds__(256) void f2h3(const float* __restrict__ s0,
                                            const float* __restrict__ s1,
                                            const float* __restrict__ s2,
                                            _Float16* __restrict__ d, int n8each) {
    const int i = blockIdx.x * 256 + threadIdx.x;
    const int sel = i / n8each;
    const int off = i - sel * n8each;
    const float* s = sel == 0 ? s0 : (sel == 1 ? s1 : s2);
    const float4 a = ((const float4*)s)[2 * off];
    const float4 b = ((const float4*)s)[2 * off + 1];
    half8 h = {(_Float16)a.x, (_Float16)a.y, (_Float16)a.z, (_Float16)a.w,
               (_Float16)b.x, (_Float16)b.y, (_Float16)b.z, (_Float16)b.w};
    ((half8*)d)[i] = h;
}

__global__ __launch_bounds__(256) void f2h(const float* __restrict__ in,
                                           _Float16* __restrict__ out, int n8) {
    const int i = blockIdx.x * 256 + threadIdx.x;
    if (i >= n8) return;
    const float4 a = ((const float4*)in)[2 * i];
    const float4 b = ((const float4*)in)[2 * i + 1];
    half8 h = {(_Float16)a.x, (_Float16)a.y, (_Float16)a.z, (_Float16)a.w,
               (_Float16)b.x, (_Float16)b.y, (_Float16)b.z, (_Float16)b.w};
    ((half8*)out)[i] = h;
}

// ---------------------------------------------------------------------------
// Embedding gather (fp32)
// ---------------------------------------------------------------------------
__global__ __launch_bounds__(256) void embed_kernel(const int* __restrict__ ids,
                                                    const float* __restrict__ emb,
                                                    float* __restrict__ x) {
    const int row = blockIdx.x;
    const int id = ids[row];
    const float4* src = (const float4*)(emb + (size_t)id * D_SZ);
    float4* dst = (float4*)(x + (size_t)row * D_SZ);
    dst[threadIdx.x] = src[threadIdx.x];
}

// ---------------------------------------------------------------------------
// RMSNorm: fp32 in, fp16 out
// ---------------------------------------------------------------------------
__global__ __launch_bounds__(256) void rmsnorm_kernel(const float* __restrict__ x,
                                                      const float* __restrict__ w,
                                                      _Float16* __restrict__ out) {
    const int row = blockIdx.x;
    const int tid = threadIdx.x;
    const float4 v = ((const float4*)(x + (size_t)row * D_SZ))[tid];
    float ss = v.x * v.x + v.y * v.y + v.z * v.z + v.w * v.w;
#pragma unroll
    for (int off = 32; off > 0; off >>= 1) ss += __shfl_down(ss, off, 64);
    __shared__ float red[4];
    if ((tid & 63) == 0) red[tid >> 6] = ss;
    __syncthreads();
    const float tot = red[0] + red[1] + red[2] + red[3];
    const float inv = 1.0f / (sqrtf(tot * (1.0f / (float)D_SZ)) + 1e-5f);
    const float4 wv = ((const float4*)w)[tid];
    half4 o = {(_Float16)(v.x * inv * wv.x), (_Float16)(v.y * inv * wv.y),
               (_Float16)(v.z * inv * wv.z), (_Float16)(v.w * inv * wv.w)};
    ((half4*)(out + (size_t)row * D_SZ))[tid] = o;
}

// ---------------------------------------------------------------------------
// MFMA fp16 GEMM (NT): C[M,N] = A[M,K] * B[N,K]^T, fp32 accumulate.
// Tile TM x 128, BK=32, 4 waves. TM=128: 2x2 waves, 64x64/wave (4x4 frags).
// TM=64: 1x4 waves, 64x32/wave (4x2 frags) -> 2x the blocks for small-N GEMMs.
// 2-phase prefetch: double-buffered LDS, next tile's global_load_lds issued
// before current tile's ds_read+MFMA, single __syncthreads per K-step.
// Bijective XCD chunk swizzle (m204); MFAST picks fastest-varying grid dim.
// EPI: 0 = Cf store; 1 = Cf += ; 2 = Ch = swish(v); 3 = Ch = AUXh * v;
//      4 = qkv split store (fp16) with fused RoPE on q,k
// ---------------------------------------------------------------------------
template <int EPI, bool MFAST, int TM>
__global__ __launch_bounds__(256) void hgemm(const _Float16* __restrict__ A,
                                             const _Float16* __restrict__ B,
                                             float* __restrict__ Cf,
                                             _Float16* Ch,
                                             const _Float16* AUXh,
                                             _Float16* Cq,
                                             _Float16* Ck,
                                             _Float16* Cv,
                                             int M, int N, int K) {
    constexpr int WN = (TM == 128) ? 2 : 4;   // waves along N
    constexpr int CW = 128 / WN;              // wave col width (64 / 32)
    constexpr int FN = CW / 16;               // col frags per wave (4 / 2)
    __shared__ __align__(16) _Float16 As[2][TM * 32];
    __shared__ __align__(16) _Float16 Bs[2][128 * 32];
    const int tid = threadIdx.x;
    const int lane = tid & 63;
    const int wave = tid >> 6;
    const int wr = (TM == 128) ? (wave >> 1) : 0;
    const int wc = (TM == 128) ? (wave & 1) : wave;
    const int l15 = lane & 15, g = lane >> 4;

    // block swizzle: contiguous logical chunk per XCD (bijective, m204)
    const int gm = M / TM, gn = N >> 7, nwg = gm * gn;
    const int orig = blockIdx.x;
    const int q8 = nwg >> 3, r8 = nwg & 7, xcd = orig & 7, j8 = orig >> 3;
    const int wgid = (xcd < r8 ? xcd * (q8 + 1) : r8 * (q8 + 1) + (xcd - r8) * q8) + j8;
    const int bm = MFAST ? (wgid % gm) : (wgid / gn);
    const int bn = MFAST ? (wgid / gm) : (wgid % gn);
    const int m0 = bm * TM, n0 = bn * 128;

    // staging: A tile = TM*64 B (TM*16 B/wave), B tile = 8 KB (2 KB/wave)
    const int offA0 = wave * (TM * 16) + lane * 16;
    const int offA1 = offA0 + 1024;
    const int rA0 = offA0 >> 6, kA0 = offA0 & 63;
    const int rA1 = offA1 >> 6, kA1 = offA1 & 63;
    const int offB0 = wave * 2048 + lane * 16;
    const int offB1 = offB0 + 1024;
    const int rB0 = offB0 >> 6, kB0 = offB0 & 63;
    const int rB1 = offB1 >> 6, kB1 = offB1 & 63;
    const char* gA0 = (const char*)(A + (size_t)(m0 + rA0) * K) + kA0;
    const char* gA1 = (const char*)(A + (size_t)(m0 + rA1) * K) + kA1;
    const char* gB0 = (const char*)(B + (size_t)(n0 + rB0) * K) + kB0;
    const char* gB1 = (const char*)(B + (size_t)(n0 + rB1) * K) + kB1;

#define STAGE(buf)                                                     \
    do {                                                               \
        gload16(gA0, (char*)As[buf] + offA0);                          \
        if constexpr (TM == 128) gload16(gA1, (char*)As[buf] + offA1); \
        gload16(gB0, (char*)Bs[buf] + offB0);                          \
        gload16(gB1, (char*)Bs[buf] + offB1);                          \
        gA0 += 64; gA1 += 64; gB0 += 64; gB1 += 64;                    \
    } while (0)

    floatx4 acc[4][FN];
#pragma unroll
    for (int i = 0; i < 4; i++)
#pragma unroll
        for (int j = 0; j < FN; j++) acc[i][j] = 0;

    STAGE(0);
    __syncthreads();   // drain prologue stage
    int cur = 0;
    for (int kk = 0; kk < K; kk += 32) {
        if (kk + 32 < K) STAGE(cur ^ 1);   // prefetch overlaps MFMA below
        half8 aF[4], bF[FN];
#pragma unroll
        for (int i = 0; i < 4; i++)
            aF[i] = *(const half8*)&As[cur][(wr * 64 + i * 16 + l15) * 32 + g * 8];
#pragma unroll
        for (int j = 0; j < FN; j++)
            bF[j] = *(const half8*)&Bs[cur][(wc * CW + j * 16 + l15) * 32 + g * 8];
#pragma unroll
        for (int i = 0; i < 4; i++)
#pragma unroll
            for (int j = 0; j < FN; j++)
                acc[i][j] = __builtin_amdgcn_mfma_f32_16x16x32_f16(aF[i], bF[j], acc[i][j], 0, 0, 0);
        __syncthreads();   // drains prefetch (vmcnt) + LDS reads (lgkm)
        cur ^= 1;
    }
#undef STAGE

    // epilogue: D frag mapping col = lane&15, row = (lane>>4)*4 + e
    const int rb = m0 + wr * 64 + g * 4;
    const int cb = n0 + wc * CW + l15;
    if (EPI == 4) {
        const int sel = n0 >> 10;   // tile never crosses a 1024 boundary
        _Float16* Cx = sel == 0 ? Cq : (sel == 1 ? Ck : Cv);
        const int cb0 = cb - sel * 1024;
#pragma unroll
        for (int i = 0; i < 4; i++) {
#pragma unroll
            for (int e = 0; e < 4; e++) {
                const int row = rb + i * 16 + e;
                const int pos = row & (S_SZ - 1);
#pragma unroll
                for (int j = 0; j < FN; j++) {
                    float v = acc[i][j][e];
                    const int col = cb0 + j * 16;
                    if (sel < 2) {
                        // fused RoPE: pair partner value lives in lane^1
                        const float p = __shfl_xor(v, 1, 64);
                        const int pi = (col & 63) >> 1;   // pair idx in head
                        const float invf = exp2f((float)pi * -0.41524101186f);
                        float sn, cs;
                        sincosf((float)pos * invf, &sn, &cs);
                        v = (col & 1) ? (p * sn + v * cs) : (v * cs - p * sn);
                    }
                    Cx[(size_t)row * 1024 + col] = (_Float16)v;
                }
            }
        }
        return;
    }
#pragma unroll
    for (int i = 0; i < 4; i++) {
#pragma unroll
        for (int e = 0; e < 4; e++) {
            const int row = rb + i * 16 + e;
#pragma unroll
            for (int j = 0; j < FN; j++) {
                const float v = acc[i][j][e];
                if (EPI == 0) {
                    Cf[(size_t)row * N + cb + j * 16] = v;
                } else if (EPI == 1) {
                    Cf[(size_t)row * N + cb + j * 16] += v;
                } else if (EPI == 2) {
                    Ch[(size_t)row * N + cb + j * 16] =
                        (_Float16)(v / (1.0f + __expf(-v)));
                } else if (EPI == 3) {
                    const size_t idx = (size_t)row * N + cb + j * 16;
                    Ch[idx] = (_Float16)((float)AUXh[idx] * v);
                }
            }
        }
    }
}

// ---------------------------------------------------------------------------
// Per-head V transpose: vh[b,s,h*64+d] -> vt[(b*16+h)*64+d][s]
// ---------------------------------------------------------------------------
__global__ __launch_bounds__(256) void vtrans(const _Float16* __restrict__ vh,
                                              _Float16* __restrict__ vt) {
    __shared__ __align__(16) _Float16 Ls[64][80];
    const int t = threadIdx.x;
    const int s0 = blockIdx.x * 64;
    const int bh = blockIdx.y;
    const int b = bh >> 4, h = bh & 15;
#pragma unroll
    for (int p = 0; p < 2; ++p) {
        const int sl = p * 32 + (t >> 3);
        const int d = (t & 7) * 8;
        *(half8*)&Ls[sl][d] =
            *(const half8*)&vh[((size_t)b * S_SZ + s0 + sl) * D_SZ + h * 64 + d];
    }
    __syncthreads();
#pragma unroll
    for (int p = 0; p < 2; ++p) {
        const int d = p * 32 + (t >> 3);
        const int sc = (t & 7) * 8;
        half8 v;
#pragma unroll
        for (int j = 0; j < 8; ++j) v[j] = Ls[sc + j][d];
        *(half8*)&vt[((size_t)bh * 64 + d) * S_SZ + s0 + sc] = v;
    }
}

// ---------------------------------------------------------------------------
// MFMA flash attention (causal), fp16 in/out, fp32 softmax state.
// Grid (8, B*H), 256 thr. Block handles q-tiles bx and 15-bx (balanced: 17
// tile-computes each). K/V 64x64 tiles staged in LDS via global_load_lds,
// double-buffered 2-phase prefetch; XOR chunk swizzle (c ^= row&7) applied
// both-sides (pre-swizzled global source + swizzled ds_read).
// ---------------------------------------------------------------------------
__global__ __launch_bounds__(256) void attn_mfma(const _Float16* __restrict__ qh,
                                                 const _Float16* __restrict__ kh,
                                                 const _Float16* __restrict__ vt,
                                                 _Float16* __restrict__ o) {
    __shared__ __align__(16) _Float16 Ks[2][64 * 64];
    __shared__ __align__(16) _Float16 Vs[2][64 * 64];
    __shared__ __align__(16) _Float16 Ps[4][16][88];
    const int tid = threadIdx.x;
    const int lane = tid & 63, wave = tid >> 6;
    const int l15 = lane & 15, g = lane >> 4;
    const int bx = blockIdx.x;            // 0..7
    const int bh = blockIdx.y;
    const int h = bh & 15;
    const size_t tokb = (size_t)(bh >> 4) * S_SZ;

    const int qt0 = bx, qt1 = 15 - bx;    // paired q-tiles
    const int qb0 = qt0 * 64, qb1 = qt1 * 64;
    const int ktmax = qt1;                // qt1 > qt0 always

    const int qrow = l15 * 4 + wave;      // q row within tile (interleaved)
    half8 qA0[2], qA1[2];
#pragma unroll
    for (int kk = 0; kk < 2; ++kk) {
        qA0[kk] = *(const half8*)&qh[(tokb + qb0 + qrow) * D_SZ + h * 64 + kk * 32 + g * 8];
        qA1[kk] = *(const half8*)&qh[(tokb + qb1 + qrow) * D_SZ + h * 64 + kk * 32 + g * 8];
    }

    floatx4 accO0[4], accO1[4];
#pragma unroll
    for (int s = 0; s < 4; s++) { accO0[s] = 0; accO1[s] = 0; }
    float m0_[4] = {NEG_INF, NEG_INF, NEG_INF, NEG_INF};
    float l0_[4] = {0.0f, 0.0f, 0.0f, 0.0f};
    float m1_[4] = {NEG_INF, NEG_INF, NEG_INF, NEG_INF};
    float l1_[4] = {0.0f, 0.0f, 0.0f, 0.0f};

    // staging geometry: tile = 64 rows x 128 B; per wave 2 x 1 KB instrs
    const char* KbB = (const char*)(kh + tokb * D_SZ + h * 64);
    const char* VbB = (const char*)(vt + (size_t)bh * 64 * S_SZ);
    const int so0 = wave * 2048 + lane * 16;
    const int so1 = so0 + 1024;
    const int r0 = so0 >> 7, c0 = (so0 >> 4) & 7;
    const int r1 = so1 >> 7, c1 = (so1 >> 4) & 7;
    const int gc0 = ((c0 ^ (r0 & 7)) << 4);   // inverse-swizzled source chunk
    const int gc1 = ((c1 ^ (r1 & 7)) << 4);

#define STAGEKV(buf, kt)                                                   \
    do {                                                                   \
        const size_t kvr = (size_t)(kt) * 64;                              \
        gload16(KbB + (kvr + r0) * 2048 + gc0, (char*)Ks[buf] + so0);      \
        gload16(KbB + (kvr + r1) * 2048 + gc1, (char*)Ks[buf] + so1);      \
        gload16(VbB + r0 * 2048 + kvr * 2 + gc0, (char*)Vs[buf] + so0);    \
        gload16(VbB + r1 * 2048 + kvr * 2 + gc1, (char*)Vs[buf] + so1);    \
    } while (0)

    // swizzled LDS fragment read: row rr, 16B-chunk cc
#define LDSW(arr, rr, cc) \
    (*(const half8*)&(arr)[(rr) * 64 + ((((cc) ^ ((rr) & 7))) << 3)])

    auto computeTile = [&](const half8* qA, floatx4* accO, float* m_, float* l_,
                           int qbase, int kt, bool diag, int buf) {
        const int kv0 = kt * 64;
        floatx4 accS[4];
#pragma unroll
        for (int sub = 0; sub < 4; ++sub) {
            accS[sub] = 0;
#pragma unroll
            for (int kk = 0; kk < 2; ++kk) {
                half8 kB = LDSW(Ks[buf], sub * 16 + l15, kk * 4 + g);
                accS[sub] = __builtin_amdgcn_mfma_f32_16x16x32_f16(qA[kk], kB, accS[sub], 0, 0, 0);
            }
        }
        float sv[4][4];
        float mx[4] = {NEG_INF, NEG_INF, NEG_INF, NEG_INF};
#pragma unroll
        for (int sub = 0; sub < 4; ++sub)
#pragma unroll
            for (int e = 0; e < 4; ++e) {
                float s = accS[sub][e] * 0.125f;
                if (diag && (kv0 + sub * 16 + l15 > qbase + (g * 4 + e) * 4 + wave))
                    s = NEG_INF;
                sv[sub][e] = s;
                mx[e] = fmaxf(mx[e], s);
            }
#pragma unroll
        for (int msk = 1; msk <= 8; msk <<= 1)
#pragma unroll
            for (int e = 0; e < 4; ++e)
                mx[e] = fmaxf(mx[e], __shfl_xor(mx[e], msk, 64));
        float sf[4];
#pragma unroll
        for (int e = 0; e < 4; ++e) {
            const float mn = fmaxf(m_[e], mx[e]);
            sf[e] = __expf(m_[e] - mn);
            m_[e] = mn;
        }
        float rs[4] = {0.0f, 0.0f, 0.0f, 0.0f};
#pragma unroll
        for (int sub = 0; sub < 4; ++sub)
#pragma unroll
            for (int e = 0; e < 4; ++e) {
                const float p = __expf(sv[sub][e] - m_[e]);
                sv[sub][e] = p;
                rs[e] += p;
            }
#pragma unroll
        for (int msk = 1; msk <= 8; msk <<= 1)
#pragma unroll
            for (int e = 0; e < 4; ++e)
                rs[e] += __shfl_xor(rs[e], msk, 64);
#pragma unroll
        for (int e = 0; e < 4; ++e) l_[e] = l_[e] * sf[e] + rs[e];
#pragma unroll
        for (int sub = 0; sub < 4; ++sub)
#pragma unroll
            for (int e = 0; e < 4; ++e) accO[sub][e] *= sf[e];
        // P -> LDS -> A-frag re-layout
#pragma unroll
        for (int sub = 0; sub < 4; ++sub)
#pragma unroll
            for (int e = 0; e < 4; ++e)
                Ps[wave][g * 4 + e][sub * 16 + l15] = (_Float16)sv[sub][e];
        half8 aP[2];
        aP[0] = *(const half8*)&Ps[wave][l15][g * 8];
        aP[1] = *(const half8*)&Ps[wave][l15][32 + g * 8];
#pragma unroll
        for (int sub = 0; sub < 4; ++sub)
#pragma unroll
            for (int kk = 0; kk < 2; ++kk) {
                half8 vB = LDSW(Vs[buf], sub * 16 + l15, kk * 4 + g);
                accO[sub] = __builtin_amdgcn_mfma_f32_16x16x32_f16(aP[kk], vB, accO[sub], 0, 0, 0);
            }
    };

    STAGEKV(0, 0);
    __syncthreads();
    int cur = 0;
    for (int kt = 0; kt <= ktmax; ++kt) {
        if (kt < ktmax) STAGEKV(cur ^ 1, kt + 1);   // prefetch next tile
        computeTile(qA1, accO1, m1_, l1_, qb1, kt, kt == qt1, cur);
        if (kt <= qt0)
            computeTile(qA0, accO0, m0_, l0_, qb0, kt, kt == qt0, cur);
        __syncthreads();   // drains prefetch + all waves done reading cur
        cur ^= 1;
    }
#undef STAGEKV
#undef LDSW

#pragma unroll
    for (int sub = 0; sub < 4; ++sub)
#pragma unroll
        for (int e = 0; e < 4; ++e) {
            const int rr = (g * 4 + e) * 4 + wave;
            o[(tokb + qb1 + rr) * D_SZ + h * 64 + sub * 16 + l15] =
                (_Float16)(accO1[sub][e] / l1_[e]);
            o[(tokb + qb0 + rr) * D_SZ + h * 64 + sub * 16 + l15] =
                (_Float16)(accO0[sub][e] / l0_[e]);
        }
}

// ---------------------------------------------------------------------------
// Host-side launch
// ---------------------------------------------------------------------------
extern "C" void kernel_launch(void* const* d_in, const int* in_sizes, int n_in,
                              void* d_out, int out_size, void* d_ws, size_t ws_size,
                              hipStream_t stream) {
    const int*   token_ids  = (const int*)d_in[0];
    const float* tok_emb    = (const float*)d_in[1];
    const float* lm_head_w  = (const float*)d_in[2];
    const float* ln_final_w = (const float*)d_in[3];
    const float* q_w        = (const float*)d_in[4];
    const float* k_w        = (const float*)d_in[5];
    const float* v_w        = (const float*)d_in[6];
    const float* o_w        = (const float*)d_in[7];
    const float* ln1_w      = (const float*)d_in[8];
    const float* ln2_w      = (const float*)d_in[9];
    const float* w1         = (const float*)d_in[10];
    const float* w2         = (const float*)d_in[11];
    const float* w3         = (const float*)d_in[12];
    float* out = (float*)d_out;

    char* W = (char*)d_ws;
    const size_t MB = 1u << 20;
    float*    x    = (float*)(W + 0);           // 8 MB
    _Float16* h    = (_Float16*)(W + 8 * MB);   // 4 MB
    _Float16* ao   = (_Float16*)(W + 12 * MB);  // 4 MB
    _Float16* wq   = (_Float16*)(W + 16 * MB);  // 8 MB: q/k/v/o contiguous
    _Float16* wo   = wq + 3 * (1u << 20);
    _Float16* ww1  = (_Float16*)(W + 24 * MB);  // 24 MB: w1/w3/w2 contiguous
    _Float16* ww3  = ww1 + (F_SZ * D_SZ);
    _Float16* ww2  = ww3 + (F_SZ * D_SZ);
    _Float16* qh   = (_Float16*)(W + 48 * MB);  // 4 MB
    _Float16* kh   = (_Float16*)(W + 52 * MB);  // 4 MB
    _Float16* vh   = (_Float16*)(W + 56 * MB);  // 4 MB
    _Float16* vt   = (_Float16*)(W + 60 * MB);  // 4 MB
    _Float16* ff1h = (_Float16*)(W + 64 * MB);  // 16 MB -> 80 MB
    _Float16* whead = (_Float16*)(W + 24 * MB); // 62.5 MB, overlaps dead ww*

    embed_kernel<<<NTOK, 256, 0, stream>>>(token_ids, tok_emb, x);

    const int nDD8 = D_SZ * D_SZ / 8;     // 131072
    const int nFD8 = F_SZ * D_SZ / 8;     // 524288
    const dim3 gQKV(3 * D_SZ / 128 * (NTOK / 128));   // 384
    const dim3 gD64(D_SZ / 128 * (NTOK / 64));        // 256 (TM=64)
    const dim3 gF(F_SZ / 128 * (NTOK / 128));         // 512
    const dim3 gATT(S_SZ / 128, B_SZ * H_SZ);         // (8,32), paired tiles
    const dim3 gVT(S_SZ / 64, B_SZ * H_SZ);

    for (int l = 0; l < L_SZ; l++) {
        const size_t oDD = (size_t)l * D_SZ * D_SZ;
        const size_t oFD = (size_t)l * F_SZ * D_SZ;
        rmsnorm_kernel<<<NTOK, 256, 0, stream>>>(x, ln1_w + (size_t)l * D_SZ, h);
        f2h4<<<4 * nDD8 / 256, 256, 0, stream>>>(q_w + oDD, k_w + oDD, v_w + oDD,
                                                 o_w + oDD, wq, nDD8);
        f2h3<<<3 * nFD8 / 256, 256, 0, stream>>>(w1 + oFD, w3 + oFD, w2 + oFD,
                                                 ww1, nFD8);
        hgemm<4, true, 128><<<gQKV, 256, 0, stream>>>(h, wq, nullptr, nullptr, nullptr,
                                                      qh, kh, vh, NTOK, 3 * D_SZ, D_SZ);
        vtrans<<<gVT, 256, 0, stream>>>(vh, vt);
        attn_mfma<<<gATT, 256, 0, stream>>>(qh, kh, vt, ao);
        hgemm<1, false, 64><<<gD64, 256, 0, stream>>>(ao, wo, x, nullptr, nullptr,
                                                      nullptr, nullptr, nullptr, NTOK, D_SZ, D_SZ);
        rmsnorm_kernel<<<NTOK, 256, 0, stream>>>(x, ln2_w + (size_t)l * D_SZ, h);
        hgemm<2, true, 128><<<gF, 256, 0, stream>>>(h, ww1, nullptr, ff1h, nullptr,
                                                    nullptr, nullptr, nullptr, NTOK, F_SZ, D_SZ);
        hgemm<3, true, 128><<<gF, 256, 0, stream>>>(h, ww3, nullptr, ff1h, ff1h,
                                                    nullptr, nullptr, nullptr, NTOK, F_SZ, D_SZ);
        hgemm<1, false, 64><<<gD64, 256, 0, stream>>>(ff1h, ww2, x, nullptr, nullptr,
                                                      nullptr, nullptr, nullptr, NTOK, D_SZ, F_SZ);
    }
    rmsnorm_kernel<<<NTOK, 256, 0, stream>>>(x, ln_final_w, h);
    const int nVD8 = V_SZ * D_SZ / 8;
    f2h<<<(nVD8 + 255) / 256, 256, 0, stream>>>(lm_head_w, whead, nVD8);
    const dim3 gOUT(V_SZ / 128 * (NTOK / 128));       // 4000
    hgemm<0, true, 128><<<gOUT, 256, 0, stream>>>(h, whead, out, nullptr, nullptr,
                                                  nullptr, nullptr, nullptr, NTOK, V_SZ, D_SZ);
}

// Round 6
// 1260.648 us; speedup vs baseline: 8.2883x; 1.0201x over previous
//
#include <hip/hip_runtime.h>
#include <math.h>

// Problem constants (from reference)
#define V_SZ 32000
#define D_SZ 1024
#define H_SZ 16
#define L_SZ 4
#define F_SZ 4096
#define S_SZ 1024
#define B_SZ 2
#define DK 64              // D/H
#define NTOK (B_SZ * S_SZ) // 2048
#define NEG_INF -3.0e38f

typedef _Float16 half8 __attribute__((ext_vector_type(8)));
typedef _Float16 half4 __attribute__((ext_vector_type(4)));
typedef float floatx4 __attribute__((ext_vector_type(4)));

// async global->LDS, 16B per lane; lds dest is wave-uniform base + lane*16.
__device__ __forceinline__ void gload16(const void* g, void* l) {
    __builtin_amdgcn_global_load_lds(
        (const __attribute__((address_space(1))) unsigned int*)g,
        (__attribute__((address_space(3))) unsigned int*)l, 16, 0, 0);
}

// ---------------------------------------------------------------------------
// fp32 -> fp16 weight conversion, batched
// ---------------------------------------------------------------------------
__global__ __launch_bounds__(256) void f2h4(const float* __restrict__ s0,
                                            const float* __restrict__ s1,
                                            const float* __restrict__ s2,
                                            const float* __restrict__ s3,
                                            _Float16* __restrict__ d, int n8each) {
    const int i = blockIdx.x * 256 + threadIdx.x;
    const int sel = i / n8each;
    const int off = i - sel * n8each;
    const float* s = sel == 0 ? s0 : (sel == 1 ? s1 : (sel == 2 ? s2 : s3));
    const float4 a = ((const float4*)s)[2 * off];
    const float4 b = ((const float4*)s)[2 * off + 1];
    half8 h = {(_Float16)a.x, (_Float16)a.y, (_Float16)a.z, (_Float16)a.w,
               (_Float16)b.x, (_Float16)b.y, (_Float16)b.z, (_Float16)b.w};
    ((half8*)d)[i] = h;
}

__global__ __launch_bounds__(256) void f2h3(const float* __restrict__ s0,
                                            const float* __restrict__ s1,
                                            const float* __restrict__ s2,
                                            _Float16* __restrict__ d, int n8each) {
    const int i = blockIdx.x * 256 + threadIdx.x;
    const int sel = i / n8each;
    const int off = i - sel * n8each;
    const float* s = sel == 0 ? s0 : (sel == 1 ? s1 : s2);
    const float4 a = ((const float4*)s)[2 * off];
    const float4 b = ((const float4*)s)[2 * off + 1];
    half8 h = {(_Float16)a.x, (_Float16)a.y, (_Float16)a.z, (_Float16)a.w,
               (_Float16)b.x, (_Float16)b.y, (_Float16)b.z, (_Float16)b.w};
    ((half8*)d)[i] = h;
}

__global__ __launch_bounds__(256) void f2h(const float* __restrict__ in,
                                           _Float16* __restrict__ out, int n8) {
    const int i = blockIdx.x * 256 + threadIdx.x;
    if (i >= n8) return;
    const float4 a = ((const float4*)in)[2 * i];
    const float4 b = ((const float4*)in)[2 * i + 1];
    half8 h = {(_Float16)a.x, (_Float16)a.y, (_Float16)a.z, (_Float16)a.w,
               (_Float16)b.x, (_Float16)b.y, (_Float16)b.z, (_Float16)b.w};
    ((half8*)out)[i] = h;
}

// elementwise fp16 a *= b (swiglu combine)
__global__ __launch_bounds__(256) void hmul(_Float16* __restrict__ a,
                                            const _Float16* __restrict__ b, int n8) {
    const int i = blockIdx.x * 256 + threadIdx.x;
    if (i >= n8) return;
    half8 x = ((half8*)a)[i];
    const half8 y = ((const half8*)b)[i];
#pragma unroll
    for (int j = 0; j < 8; ++j) x[j] = (_Float16)((float)x[j] * (float)y[j]);
    ((half8*)a)[i] = x;
}

// ---------------------------------------------------------------------------
// Embedding gather (fp32)
// ---------------------------------------------------------------------------
__global__ __launch_bounds__(256) void embed_kernel(const int* __restrict__ ids,
                                                    const float* __restrict__ emb,
                                                    float* __restrict__ x) {
    const int row = blockIdx.x;
    const int id = ids[row];
    const float4* src = (const float4*)(emb + (size_t)id * D_SZ);
    float4* dst = (float4*)(x + (size_t)row * D_SZ);
    dst[threadIdx.x] = src[threadIdx.x];
}

// ---------------------------------------------------------------------------
// RMSNorm: fp32 in, fp16 out
// ---------------------------------------------------------------------------
__global__ __launch_bounds__(256) void rmsnorm_kernel(const float* __restrict__ x,
                                                      const float* __restrict__ w,
                                                      _Float16* __restrict__ out) {
    const int row = blockIdx.x;
    const int tid = threadIdx.x;
    const float4 v = ((const float4*)(x + (size_t)row * D_SZ))[tid];
    float ss = v.x * v.x + v.y * v.y + v.z * v.z + v.w * v.w;
#pragma unroll
    for (int off = 32; off > 0; off >>= 1) ss += __shfl_down(ss, off, 64);
    __shared__ float red[4];
    if ((tid & 63) == 0) red[tid >> 6] = ss;
    __syncthreads();
    const float tot = red[0] + red[1] + red[2] + red[3];
    const float inv = 1.0f / (sqrtf(tot * (1.0f / (float)D_SZ)) + 1e-5f);
    const float4 wv = ((const float4*)w)[tid];
    half4 o = {(_Float16)(v.x * inv * wv.x), (_Float16)(v.y * inv * wv.y),
               (_Float16)(v.z * inv * wv.z), (_Float16)(v.w * inv * wv.w)};
    ((half4*)(out + (size_t)row * D_SZ))[tid] = o;
}

// ---------------------------------------------------------------------------
// Deep-pipelined 256x256 MFMA fp16 GEMM (NT). BK=32, 8 waves (2Mx4N), 512 thr.
// 4-deep LDS ring (128 KiB): tile t+3 staged while computing t -> counted
// vmcnt(8) at each tile boundary (t+1,t+2 stay in flight; never drain to 0
// except the tail). One raw s_barrier per tile, 32 MFMA between syncs.
// LDS XOR swizzle: logical 16B chunk c stored at position c ^ ((row>>1)&3);
// applied both-sides (inverse-swizzled global source + swizzled ds_read).
// EPI8: 0 = Cf fp32 store (lm_head); 1 = w1||w3 split: col<4096 ->
//       Ch1=swish(v) [stride 4096], else Ch3=v [stride 4096].
// Requires M%256==0, N%256==0, K%32==0, K>=96.
// ---------------------------------------------------------------------------
template <int EPI8, bool MFAST>
__global__ __launch_bounds__(512, 2) void hgemm8(const _Float16* __restrict__ A,
                                                 const _Float16* __restrict__ B,
                                                 float* __restrict__ Cf,
                                                 _Float16* __restrict__ Ch1,
                                                 _Float16* __restrict__ Ch3,
                                                 int M, int N, int K) {
    __shared__ __align__(16) _Float16 As[4][256 * 32];
    __shared__ __align__(16) _Float16 Bs[4][256 * 32];
    const int tid = threadIdx.x;
    const int lane = tid & 63, wave = tid >> 6;
    const int wm = wave >> 2, wn = wave & 3;
    const int l15 = lane & 15, g = lane >> 4;

    // bijective XCD chunk swizzle (m204)
    const int gm = M >> 8, gn = N >> 8, nwg = gm * gn;
    const int orig = blockIdx.x;
    const int q8 = nwg >> 3, r8 = nwg & 7, xcd = orig & 7, j8 = orig >> 3;
    const int wgid = (xcd < r8 ? xcd * (q8 + 1) : r8 * (q8 + 1) + (xcd - r8) * q8) + j8;
    const int bm = MFAST ? (wgid % gm) : (wgid / gn);
    const int bn = MFAST ? (wgid / gm) : (wgid % gn);
    const int m0 = bm << 8, n0 = bn << 8;

    // staging geometry: round r (0/1): lds row = r*128 + tid/4, chunk pos = tid&3
    // position p holds logical chunk c = p ^ ((row>>1)&3)
    const int row0 = tid >> 2, row1 = 128 + (tid >> 2);
    const int p = tid & 3;
    const int c0 = p ^ ((row0 >> 1) & 3);
    const int c1 = p ^ ((row1 >> 1) & 3);
    const char* gA0 = (const char*)A + (size_t)(m0 + row0) * 2 * K + c0 * 16;
    const char* gA1 = (const char*)A + (size_t)(m0 + row1) * 2 * K + c1 * 16;
    const char* gB0 = (const char*)B + (size_t)(n0 + row0) * 2 * K + c0 * 16;
    const char* gB1 = (const char*)B + (size_t)(n0 + row1) * 2 * K + c1 * 16;
    const int loff0 = tid * 16, loff1 = 8192 + tid * 16;

#define STAGE8(t)                                          \
    do {                                                   \
        const int _b = (t) & 3;                            \
        const size_t _o = (size_t)(t) * 64;                \
        gload16(gA0 + _o, (char*)As[_b] + loff0);          \
        gload16(gA1 + _o, (char*)As[_b] + loff1);          \
        gload16(gB0 + _o, (char*)Bs[_b] + loff0);          \
        gload16(gB1 + _o, (char*)Bs[_b] + loff1);          \
    } while (0)

    floatx4 acc[8][4];
#pragma unroll
    for (int i = 0; i < 8; i++)
#pragma unroll
        for (int j = 0; j < 4; j++) acc[i][j] = 0;

    const int nt = K >> 5;
    STAGE8(0);
    STAGE8(1);
    STAGE8(2);
    for (int t = 0; t < nt; ++t) {
        const int rem = nt - 1 - t;
        if (rem >= 2)      asm volatile("s_waitcnt vmcnt(8)" ::: "memory");
        else if (rem == 1) asm volatile("s_waitcnt vmcnt(4)" ::: "memory");
        else               asm volatile("s_waitcnt vmcnt(0)" ::: "memory");
        __builtin_amdgcn_s_barrier();          // all waves done reading t-1
        __builtin_amdgcn_sched_barrier(0);     // pin: no motion across barrier
        if (t + 3 < nt) STAGE8(t + 3);         // into buf (t+3)&3 == (t-1)&3
        const int buf = t & 3;
        half8 bF[4], aF[8];
#pragma unroll
        for (int j = 0; j < 4; j++) {
            const int R = wn * 64 + j * 16 + l15;
            bF[j] = *(const half8*)&Bs[buf][R * 32 + (g ^ ((R >> 1) & 3)) * 8];
        }
#pragma unroll
        for (int i = 0; i < 8; i++) {
            const int R = wm * 128 + i * 16 + l15;
            aF[i] = *(const half8*)&As[buf][R * 32 + (g ^ ((R >> 1) & 3)) * 8];
        }
#pragma unroll
        for (int i = 0; i < 8; i++)
#pragma unroll
            for (int j = 0; j < 4; j++)
                acc[i][j] = __builtin_amdgcn_mfma_f32_16x16x32_f16(aF[i], bF[j], acc[i][j], 0, 0, 0);
    }
#undef STAGE8

    // epilogue: D frag mapping col = lane&15, row = (lane>>4)*4 + e
#pragma unroll
    for (int i = 0; i < 8; i++) {
#pragma unroll
        for (int e = 0; e < 4; e++) {
            const int row = m0 + wm * 128 + i * 16 + g * 4 + e;
#pragma unroll
            for (int j = 0; j < 4; j++) {
                const int col = n0 + wn * 64 + j * 16 + l15;
                const float v = acc[i][j][e];
                if (EPI8 == 0) {
                    Cf[(size_t)row * N + col] = v;
                } else {
                    if (col < 4096)
                        Ch1[(size_t)row * 4096 + col] =
                            (_Float16)(v / (1.0f + __expf(-v)));
                    else
                        Ch3[(size_t)row * 4096 + col - 4096] = (_Float16)v;
                }
            }
        }
    }
}

// ---------------------------------------------------------------------------
// MFMA fp16 GEMM (NT): C[M,N] = A[M,K] * B[N,K]^T, fp32 accumulate.
// Tile TM x 128, BK=32, 4 waves. 2-phase prefetch, double-buffered LDS.
// EPI: 0 = Cf store; 1 = Cf += ; 2 = Ch = swish(v); 3 = Ch = AUXh * v;
//      4 = qkv split store (fp16) with fused RoPE on q,k
// ---------------------------------------------------------------------------
template <int EPI, bool MFAST, int TM>
__global__ __launch_bounds__(256) void hgemm(const _Float16* __restrict__ A,
                                             const _Float16* __restrict__ B,
                                             float* __restrict__ Cf,
                                             _Float16* Ch,
                                             const _Float16* AUXh,
                                             _Float16* Cq,
                                             _Float16* Ck,
                                             _Float16* Cv,
                                             int M, int N, int K) {
    constexpr int WN = (TM == 128) ? 2 : 4;
    constexpr int CW = 128 / WN;
    constexpr int FN = CW / 16;
    __shared__ __align__(16) _Float16 As[2][TM * 32];
    __shared__ __align__(16) _Float16 Bs[2][128 * 32];
    const int tid = threadIdx.x;
    const int lane = tid & 63;
    const int wave = tid >> 6;
    const int wr = (TM == 128) ? (wave >> 1) : 0;
    const int wc = (TM == 128) ? (wave & 1) : wave;
    const int l15 = lane & 15, g = lane >> 4;

    const int gm = M / TM, gn = N >> 7, nwg = gm * gn;
    const int orig = blockIdx.x;
    const int q8 = nwg >> 3, r8 = nwg & 7, xcd = orig & 7, j8 = orig >> 3;
    const int wgid = (xcd < r8 ? xcd * (q8 + 1) : r8 * (q8 + 1) + (xcd - r8) * q8) + j8;
    const int bm = MFAST ? (wgid % gm) : (wgid / gn);
    const int bn = MFAST ? (wgid / gm) : (wgid % gn);
    const int m0 = bm * TM, n0 = bn * 128;

    const int offA0 = wave * (TM * 16) + lane * 16;
    const int offA1 = offA0 + 1024;
    const int rA0 = offA0 >> 6, kA0 = offA0 & 63;
    const int rA1 = offA1 >> 6, kA1 = offA1 & 63;
    const int offB0 = wave * 2048 + lane * 16;
    const int offB1 = offB0 + 1024;
    const int rB0 = offB0 >> 6, kB0 = offB0 & 63;
    const int rB1 = offB1 >> 6, kB1 = offB1 & 63;
    const char* gA0 = (const char*)(A + (size_t)(m0 + rA0) * K) + kA0;
    const char* gA1 = (const char*)(A + (size_t)(m0 + rA1) * K) + kA1;
    const char* gB0 = (const char*)(B + (size_t)(n0 + rB0) * K) + kB0;
    const char* gB1 = (const char*)(B + (size_t)(n0 + rB1) * K) + kB1;

#define STAGE(buf)                                                     \
    do {                                                               \
        gload16(gA0, (char*)As[buf] + offA0);                          \
        if constexpr (TM == 128) gload16(gA1, (char*)As[buf] + offA1); \
        gload16(gB0, (char*)Bs[buf] + offB0);                          \
        gload16(gB1, (char*)Bs[buf] + offB1);                          \
        gA0 += 64; gA1 += 64; gB0 += 64; gB1 += 64;                    \
    } while (0)

    floatx4 acc[4][FN];
#pragma unroll
    for (int i = 0; i < 4; i++)
#pragma unroll
        for (int j = 0; j < FN; j++) acc[i][j] = 0;

    STAGE(0);
    __syncthreads();
    int cur = 0;
    for (int kk = 0; kk < K; kk += 32) {
        if (kk + 32 < K) STAGE(cur ^ 1);
        half8 aF[4], bF[FN];
#pragma unroll
        for (int i = 0; i < 4; i++)
            aF[i] = *(const half8*)&As[cur][(wr * 64 + i * 16 + l15) * 32 + g * 8];
#pragma unroll
        for (int j = 0; j < FN; j++)
            bF[j] = *(const half8*)&Bs[cur][(wc * CW + j * 16 + l15) * 32 + g * 8];
#pragma unroll
        for (int i = 0; i < 4; i++)
#pragma unroll
            for (int j = 0; j < FN; j++)
                acc[i][j] = __builtin_amdgcn_mfma_f32_16x16x32_f16(aF[i], bF[j], acc[i][j], 0, 0, 0);
        __syncthreads();
        cur ^= 1;
    }
#undef STAGE

    const int rb = m0 + wr * 64 + g * 4;
    const int cb = n0 + wc * CW + l15;
    if (EPI == 4) {
        const int sel = n0 >> 10;
        _Float16* Cx = sel == 0 ? Cq : (sel == 1 ? Ck : Cv);
        const int cb0 = cb - sel * 1024;
#pragma unroll
        for (int i = 0; i < 4; i++) {
#pragma unroll
            for (int e = 0; e < 4; e++) {
                const int row = rb + i * 16 + e;
                const int pos = row & (S_SZ - 1);
#pragma unroll
                for (int j = 0; j < FN; j++) {
                    float v = acc[i][j][e];
                    const int col = cb0 + j * 16;
                    if (sel < 2) {
                        const float pp = __shfl_xor(v, 1, 64);
                        const int pi = (col & 63) >> 1;
                        const float invf = exp2f((float)pi * -0.41524101186f);
                        float sn, cs;
                        sincosf((float)pos * invf, &sn, &cs);
                        v = (col & 1) ? (pp * sn + v * cs) : (v * cs - pp * sn);
                    }
                    Cx[(size_t)row * 1024 + col] = (_Float16)v;
                }
            }
        }
        return;
    }
#pragma unroll
    for (int i = 0; i < 4; i++) {
#pragma unroll
        for (int e = 0; e < 4; e++) {
            const int row = rb + i * 16 + e;
#pragma unroll
            for (int j = 0; j < FN; j++) {
                const float v = acc[i][j][e];
                if (EPI == 0) {
                    Cf[(size_t)row * N + cb + j * 16] = v;
                } else if (EPI == 1) {
                    Cf[(size_t)row * N + cb + j * 16] += v;
                } else if (EPI == 2) {
                    Ch[(size_t)row * N + cb + j * 16] =
                        (_Float16)(v / (1.0f + __expf(-v)));
                } else if (EPI == 3) {
                    const size_t idx = (size_t)row * N + cb + j * 16;
                    Ch[idx] = (_Float16)((float)AUXh[idx] * v);
                }
            }
        }
    }
}

// ---------------------------------------------------------------------------
// Per-head V transpose: vh[b,s,h*64+d] -> vt[(b*16+h)*64+d][s]
// ---------------------------------------------------------------------------
__global__ __launch_bounds__(256) void vtrans(const _Float16* __restrict__ vh,
                                              _Float16* __restrict__ vt) {
    __shared__ __align__(16) _Float16 Ls[64][80];
    const int t = threadIdx.x;
    const int s0 = blockIdx.x * 64;
    const int bh = blockIdx.y;
    const int b = bh >> 4, h = bh & 15;
#pragma unroll
    for (int p = 0; p < 2; ++p) {
        const int sl = p * 32 + (t >> 3);
        const int d = (t & 7) * 8;
        *(half8*)&Ls[sl][d] =
            *(const half8*)&vh[((size_t)b * S_SZ + s0 + sl) * D_SZ + h * 64 + d];
    }
    __syncthreads();
#pragma unroll
    for (int p = 0; p < 2; ++p) {
        const int d = p * 32 + (t >> 3);
        const int sc = (t & 7) * 8;
        half8 v;
#pragma unroll
        for (int j = 0; j < 8; ++j) v[j] = Ls[sc + j][d];
        *(half8*)&vt[((size_t)bh * 64 + d) * S_SZ + s0 + sc] = v;
    }
}

// ---------------------------------------------------------------------------
// MFMA flash attention (causal), fp16 in/out, fp32 softmax state.
// Paired q-tiles (bx, 15-bx), K/V LDS-staged w/ 2-phase prefetch + XOR swizzle.
// ---------------------------------------------------------------------------
__global__ __launch_bounds__(256) void attn_mfma(const _Float16* __restrict__ qh,
                                                 const _Float16* __restrict__ kh,
                                                 const _Float16* __restrict__ vt,
                                                 _Float16* __restrict__ o) {
    __shared__ __align__(16) _Float16 Ks[2][64 * 64];
    __shared__ __align__(16) _Float16 Vs[2][64 * 64];
    __shared__ __align__(16) _Float16 Ps[4][16][88];
    const int tid = threadIdx.x;
    const int lane = tid & 63, wave = tid >> 6;
    const int l15 = lane & 15, g = lane >> 4;
    const int bx = blockIdx.x;
    const int bh = blockIdx.y;
    const int h = bh & 15;
    const size_t tokb = (size_t)(bh >> 4) * S_SZ;

    const int qt0 = bx, qt1 = 15 - bx;
    const int qb0 = qt0 * 64, qb1 = qt1 * 64;
    const int ktmax = qt1;

    const int qrow = l15 * 4 + wave;
    half8 qA0[2], qA1[2];
#pragma unroll
    for (int kk = 0; kk < 2; ++kk) {
        qA0[kk] = *(const half8*)&qh[(tokb + qb0 + qrow) * D_SZ + h * 64 + kk * 32 + g * 8];
        qA1[kk] = *(const half8*)&qh[(tokb + qb1 + qrow) * D_SZ + h * 64 + kk * 32 + g * 8];
    }

    floatx4 accO0[4], accO1[4];
#pragma unroll
    for (int s = 0; s < 4; s++) { accO0[s] = 0; accO1[s] = 0; }
    float m0_[4] = {NEG_INF, NEG_INF, NEG_INF, NEG_INF};
    float l0_[4] = {0.0f, 0.0f, 0.0f, 0.0f};
    float m1_[4] = {NEG_INF, NEG_INF, NEG_INF, NEG_INF};
    float l1_[4] = {0.0f, 0.0f, 0.0f, 0.0f};

    const char* KbB = (const char*)(kh + tokb * D_SZ + h * 64);
    const char* VbB = (const char*)(vt + (size_t)bh * 64 * S_SZ);
    const int so0 = wave * 2048 + lane * 16;
    const int so1 = so0 + 1024;
    const int r0 = so0 >> 7, c0 = (so0 >> 4) & 7;
    const int r1 = so1 >> 7, c1 = (so1 >> 4) & 7;
    const int gc0 = ((c0 ^ (r0 & 7)) << 4);
    const int gc1 = ((c1 ^ (r1 & 7)) << 4);

#define STAGEKV(buf, kt)                                                   \
    do {                                                                   \
        const size_t kvr = (size_t)(kt) * 64;                              \
        gload16(KbB + (kvr + r0) * 2048 + gc0, (char*)Ks[buf] + so0);      \
        gload16(KbB + (kvr + r1) * 2048 + gc1, (char*)Ks[buf] + so1);      \
        gload16(VbB + r0 * 2048 + kvr * 2 + gc0, (char*)Vs[buf] + so0);    \
        gload16(VbB + r1 * 2048 + kvr * 2 + gc1, (char*)Vs[buf] + so1);    \
    } while (0)

#define LDSW(arr, rr, cc) \
    (*(const half8*)&(arr)[(rr) * 64 + ((((cc) ^ ((rr) & 7))) << 3)])

    auto computeTile = [&](const half8* qA, floatx4* accO, float* m_, float* l_,
                           int qbase, int kt, bool diag, int buf) {
        const int kv0 = kt * 64;
        floatx4 accS[4];
#pragma unroll
        for (int sub = 0; sub < 4; ++sub) {
            accS[sub] = 0;
#pragma unroll
            for (int kk = 0; kk < 2; ++kk) {
                half8 kB = LDSW(Ks[buf], sub * 16 + l15, kk * 4 + g);
                accS[sub] = __builtin_amdgcn_mfma_f32_16x16x32_f16(qA[kk], kB, accS[sub], 0, 0, 0);
            }
        }
        float sv[4][4];
        float mx[4] = {NEG_INF, NEG_INF, NEG_INF, NEG_INF};
#pragma unroll
        for (int sub = 0; sub < 4; ++sub)
#pragma unroll
            for (int e = 0; e < 4; ++e) {
                float s = accS[sub][e] * 0.125f;
                if (diag && (kv0 + sub * 16 + l15 > qbase + (g * 4 + e) * 4 + wave))
                    s = NEG_INF;
                sv[sub][e] = s;
                mx[e] = fmaxf(mx[e], s);
            }
#pragma unroll
        for (int msk = 1; msk <= 8; msk <<= 1)
#pragma unroll
            for (int e = 0; e < 4; ++e)
                mx[e] = fmaxf(mx[e], __shfl_xor(mx[e], msk, 64));
        float sf[4];
#pragma unroll
        for (int e = 0; e < 4; ++e) {
            const float mn = fmaxf(m_[e], mx[e]);
            sf[e] = __expf(m_[e] - mn);
            m_[e] = mn;
        }
        float rs[4] = {0.0f, 0.0f, 0.0f, 0.0f};
#pragma unroll
        for (int sub = 0; sub < 4; ++sub)
#pragma unroll
            for (int e = 0; e < 4; ++e) {
                const float p = __expf(sv[sub][e] - m_[e]);
                sv[sub][e] = p;
                rs[e] += p;
            }
#pragma unroll
        for (int msk = 1; msk <= 8; msk <<= 1)
#pragma unroll
            for (int e = 0; e < 4; ++e)
                rs[e] += __shfl_xor(rs[e], msk, 64);
#pragma unroll
        for (int e = 0; e < 4; ++e) l_[e] = l_[e] * sf[e] + rs[e];
#pragma unroll
        for (int sub = 0; sub < 4; ++sub)
#pragma unroll
            for (int e = 0; e < 4; ++e) accO[sub][e] *= sf[e];
#pragma unroll
        for (int sub = 0; sub < 4; ++sub)
#pragma unroll
            for (int e = 0; e < 4; ++e)
                Ps[wave][g * 4 + e][sub * 16 + l15] = (_Float16)sv[sub][e];
        half8 aP[2];
        aP[0] = *(const half8*)&Ps[wave][l15][g * 8];
        aP[1] = *(const half8*)&Ps[wave][l15][32 + g * 8];
#pragma unroll
        for (int sub = 0; sub < 4; ++sub)
#pragma unroll
            for (int kk = 0; kk < 2; ++kk) {
                half8 vB = LDSW(Vs[buf], sub * 16 + l15, kk * 4 + g);
                accO[sub] = __builtin_amdgcn_mfma_f32_16x16x32_f16(aP[kk], vB, accO[sub], 0, 0, 0);
            }
    };

    STAGEKV(0, 0);
    __syncthreads();
    int cur = 0;
    for (int kt = 0; kt <= ktmax; ++kt) {
        if (kt < ktmax) STAGEKV(cur ^ 1, kt + 1);
        computeTile(qA1, accO1, m1_, l1_, qb1, kt, kt == qt1, cur);
        if (kt <= qt0)
            computeTile(qA0, accO0, m0_, l0_, qb0, kt, kt == qt0, cur);
        __syncthreads();
        cur ^= 1;
    }
#undef STAGEKV
#undef LDSW

#pragma unroll
    for (int sub = 0; sub < 4; ++sub)
#pragma unroll
        for (int e = 0; e < 4; ++e) {
            const int rr = (g * 4 + e) * 4 + wave;
            o[(tokb + qb1 + rr) * D_SZ + h * 64 + sub * 16 + l15] =
                (_Float16)(accO1[sub][e] / l1_[e]);
            o[(tokb + qb0 + rr) * D_SZ + h * 64 + sub * 16 + l15] =
                (_Float16)(accO0[sub][e] / l0_[e]);
        }
}

// ---------------------------------------------------------------------------
// Host-side launch
// ---------------------------------------------------------------------------
extern "C" void kernel_launch(void* const* d_in, const int* in_sizes, int n_in,
                              void* d_out, int out_size, void* d_ws, size_t ws_size,
                              hipStream_t stream) {
    const int*   token_ids  = (const int*)d_in[0];
    const float* tok_emb    = (const float*)d_in[1];
    const float* lm_head_w  = (const float*)d_in[2];
    const float* ln_final_w = (const float*)d_in[3];
    const float* q_w        = (const float*)d_in[4];
    const float* k_w        = (const float*)d_in[5];
    const float* v_w        = (const float*)d_in[6];
    const float* o_w        = (const float*)d_in[7];
    const float* ln1_w      = (const float*)d_in[8];
    const float* ln2_w      = (const float*)d_in[9];
    const float* w1         = (const float*)d_in[10];
    const float* w2         = (const float*)d_in[11];
    const float* w3         = (const float*)d_in[12];
    float* out = (float*)d_out;

    char* W = (char*)d_ws;
    const size_t MB = 1u << 20;
    float*    x    = (float*)(W + 0);           // 8 MB
    _Float16* h    = (_Float16*)(W + 8 * MB);   // 4 MB
    _Float16* ao   = (_Float16*)(W + 12 * MB);  // 4 MB
    _Float16* wq   = (_Float16*)(W + 16 * MB);  // 8 MB: q/k/v/o contiguous
    _Float16* wo   = wq + 3 * (1u << 20);
    _Float16* ww1  = (_Float16*)(W + 24 * MB);  // 24 MB: w1/w3/w2 contiguous
    _Float16* ww2  = ww1 + 2 * (F_SZ * D_SZ);
    _Float16* qh   = (_Float16*)(W + 48 * MB);  // 4 MB  (dead during FFN)
    _Float16* kh   = (_Float16*)(W + 52 * MB);  // 4 MB
    _Float16* vh   = (_Float16*)(W + 56 * MB);  // 4 MB
    _Float16* vt   = (_Float16*)(W + 60 * MB);  // 4 MB
    _Float16* ff3h = (_Float16*)(W + 48 * MB);  // 16 MB, overlaps qh..vt (dead)
    _Float16* ff1h = (_Float16*)(W + 64 * MB);  // 16 MB -> 80 MB
    _Float16* whead = (_Float16*)(W + 24 * MB); // 62.5 MB, overlaps dead ww*

    embed_kernel<<<NTOK, 256, 0, stream>>>(token_ids, tok_emb, x);

    const int nDD8 = D_SZ * D_SZ / 8;     // 131072
    const int nFD8 = F_SZ * D_SZ / 8;     // 524288
    const dim3 gQKV(3 * D_SZ / 128 * (NTOK / 128));   // 384
    const dim3 gD64(D_SZ / 128 * (NTOK / 64));        // 256 (TM=64)
    const dim3 gW13(2 * F_SZ / 256 * (NTOK / 256));   // 256 (256^2 tile)
    const dim3 gATT(S_SZ / 128, B_SZ * H_SZ);         // (8,32), paired tiles
    const dim3 gVT(S_SZ / 64, B_SZ * H_SZ);

    for (int l = 0; l < L_SZ; l++) {
        const size_t oDD = (size_t)l * D_SZ * D_SZ;
        const size_t oFD = (size_t)l * F_SZ * D_SZ;
        rmsnorm_kernel<<<NTOK, 256, 0, stream>>>(x, ln1_w + (size_t)l * D_SZ, h);
        f2h4<<<4 * nDD8 / 256, 256, 0, stream>>>(q_w + oDD, k_w + oDD, v_w + oDD,
                                                 o_w + oDD, wq, nDD8);
        f2h3<<<3 * nFD8 / 256, 256, 0, stream>>>(w1 + oFD, w3 + oFD, w2 + oFD,
                                                 ww1, nFD8);
        hgemm<4, true, 128><<<gQKV, 256, 0, stream>>>(h, wq, nullptr, nullptr, nullptr,
                                                      qh, kh, vh, NTOK, 3 * D_SZ, D_SZ);
        vtrans<<<gVT, 256, 0, stream>>>(vh, vt);
        attn_mfma<<<gATT, 256, 0, stream>>>(qh, kh, vt, ao);
        hgemm<1, false, 64><<<gD64, 256, 0, stream>>>(ao, wo, x, nullptr, nullptr,
                                                      nullptr, nullptr, nullptr, NTOK, D_SZ, D_SZ);
        rmsnorm_kernel<<<NTOK, 256, 0, stream>>>(x, ln2_w + (size_t)l * D_SZ, h);
        // fused w1 || w3 (N = 8192), then elementwise combine
        hgemm8<1, true><<<gW13, 512, 0, stream>>>(h, ww1, nullptr, ff1h, ff3h,
                                                  NTOK, 2 * F_SZ, D_SZ);
        hmul<<<NTOK * F_SZ / 8 / 256, 256, 0, stream>>>(ff1h, ff3h, NTOK * F_SZ / 8);
        hgemm<1, false, 64><<<gD64, 256, 0, stream>>>(ff1h, ww2, x, nullptr, nullptr,
                                                      nullptr, nullptr, nullptr, NTOK, D_SZ, F_SZ);
    }
    rmsnorm_kernel<<<NTOK, 256, 0, stream>>>(x, ln_final_w, h);
    const int nVD8 = V_SZ * D_SZ / 8;
    f2h<<<(nVD8 + 255) / 256, 256, 0, stream>>>(lm_head_w, whead, nVD8);
    const dim3 gOUT(V_SZ / 256 * (NTOK / 256));       // 1000 (256^2 tile)
    hgemm8<0, true><<<gOUT, 512, 0, stream>>>(h, whead, out, nullptr, nullptr,
                                              NTOK, V_SZ, D_SZ);
}

// Round 7
// 1244.087 us; speedup vs baseline: 8.3986x; 1.0133x over previous
//
#include <hip/hip_runtime.h>
#include <math.h>

// Problem constants (from reference)
#define V_SZ 32000
#define D_SZ 1024
#define H_SZ 16
#define L_SZ 4
#define F_SZ 4096
#define S_SZ 1024
#define B_SZ 2
#define DK 64              // D/H
#define NTOK (B_SZ * S_SZ) // 2048
#define NEG_INF -3.0e38f

typedef _Float16 half8 __attribute__((ext_vector_type(8)));
typedef _Float16 half4 __attribute__((ext_vector_type(4)));
typedef float floatx4 __attribute__((ext_vector_type(4)));

// async global->LDS, 16B per lane; lds dest is wave-uniform base + lane*16.
__device__ __forceinline__ void gload16(const void* g, void* l) {
    __builtin_amdgcn_global_load_lds(
        (const __attribute__((address_space(1))) unsigned int*)g,
        (__attribute__((address_space(3))) unsigned int*)l, 16, 0, 0);
}

// ---------------------------------------------------------------------------
// fp32 -> fp16 conversion: all 7 per-layer weight mats in one launch.
// Sources: q,k,v,o (nDD8 each) then w1,w3,w2 (nFD8 each); dest contiguous.
// ---------------------------------------------------------------------------
__global__ __launch_bounds__(256) void f2h7(const float* __restrict__ sq,
                                            const float* __restrict__ sk,
                                            const float* __restrict__ sv,
                                            const float* __restrict__ so,
                                            const float* __restrict__ s1,
                                            const float* __restrict__ s3,
                                            const float* __restrict__ s2,
                                            _Float16* __restrict__ d,
                                            int nDD8, int nFD8) {
    const int i = blockIdx.x * 256 + threadIdx.x;
    const float* s;
    int off;
    if (i < 4 * nDD8) {
        const int sel = i / nDD8;
        off = i - sel * nDD8;
        s = sel == 0 ? sq : (sel == 1 ? sk : (sel == 2 ? sv : so));
    } else {
        const int j = i - 4 * nDD8;
        const int sel = j / nFD8;
        off = j - sel * nFD8;
        s = sel == 0 ? s1 : (sel == 1 ? s3 : s2);
    }
    const float4 a = ((const float4*)s)[2 * off];
    const float4 b = ((const float4*)s)[2 * off + 1];
    half8 h = {(_Float16)a.x, (_Float16)a.y, (_Float16)a.z, (_Float16)a.w,
               (_Float16)b.x, (_Float16)b.y, (_Float16)b.z, (_Float16)b.w};
    ((half8*)d)[i] = h;
}

__global__ __launch_bounds__(256) void f2h(const float* __restrict__ in,
                                           _Float16* __restrict__ out, int n8) {
    const int i = blockIdx.x * 256 + threadIdx.x;
    if (i >= n8) return;
    const float4 a = ((const float4*)in)[2 * i];
    const float4 b = ((const float4*)in)[2 * i + 1];
    half8 h = {(_Float16)a.x, (_Float16)a.y, (_Float16)a.z, (_Float16)a.w,
               (_Float16)b.x, (_Float16)b.y, (_Float16)b.z, (_Float16)b.w};
    ((half8*)out)[i] = h;
}

// elementwise fp16 a *= b (swiglu combine)
__global__ __launch_bounds__(256) void hmul(_Float16* __restrict__ a,
                                            const _Float16* __restrict__ b, int n8) {
    const int i = blockIdx.x * 256 + threadIdx.x;
    if (i >= n8) return;
    half8 x = ((half8*)a)[i];
    const half8 y = ((const half8*)b)[i];
#pragma unroll
    for (int j = 0; j < 8; ++j) x[j] = (_Float16)((float)x[j] * (float)y[j]);
    ((half8*)a)[i] = x;
}

// ---------------------------------------------------------------------------
// Embedding gather (fp32)
// ---------------------------------------------------------------------------
__global__ __launch_bounds__(256) void embed_kernel(const int* __restrict__ ids,
                                                    const float* __restrict__ emb,
                                                    float* __restrict__ x) {
    const int row = blockIdx.x;
    const int id = ids[row];
    const float4* src = (const float4*)(emb + (size_t)id * D_SZ);
    float4* dst = (float4*)(x + (size_t)row * D_SZ);
    dst[threadIdx.x] = src[threadIdx.x];
}

// ---------------------------------------------------------------------------
// RMSNorm: fp32 in, fp16 out
// ---------------------------------------------------------------------------
__global__ __launch_bounds__(256) void rmsnorm_kernel(const float* __restrict__ x,
                                                      const float* __restrict__ w,
                                                      _Float16* __restrict__ out) {
    const int row = blockIdx.x;
    const int tid = threadIdx.x;
    const float4 v = ((const float4*)(x + (size_t)row * D_SZ))[tid];
    float ss = v.x * v.x + v.y * v.y + v.z * v.z + v.w * v.w;
#pragma unroll
    for (int off = 32; off > 0; off >>= 1) ss += __shfl_down(ss, off, 64);
    __shared__ float red[4];
    if ((tid & 63) == 0) red[tid >> 6] = ss;
    __syncthreads();
    const float tot = red[0] + red[1] + red[2] + red[3];
    const float inv = 1.0f / (sqrtf(tot * (1.0f / (float)D_SZ)) + 1e-5f);
    const float4 wv = ((const float4*)w)[tid];
    half4 o = {(_Float16)(v.x * inv * wv.x), (_Float16)(v.y * inv * wv.y),
               (_Float16)(v.z * inv * wv.z), (_Float16)(v.w * inv * wv.w)};
    ((half4*)(out + (size_t)row * D_SZ))[tid] = o;
}

// ---------------------------------------------------------------------------
// MFMA fp16 GEMM (NT): C[M,N] = A[M,K] * B[N,K]^T, fp32 accumulate.
// Tile TM x 128, BK=32, 4 waves. 2-phase prefetch, double-buffered LDS
// (proven structure: next tile's global_load_lds issued BEFORE current
// tile's ds_read+MFMA, one __syncthreads per K-step).
// EPI: 0 = Cf store; 1 = Cf += ; 2 = Ch = swish(v); 3 = Ch = AUXh * v;
//      4 = qkv split store (fp16) with fused RoPE on q,k
//      5 = w1||w3 split (N=8192): col<4096 -> Ch=swish(v), else Cq=v (raw),
//          both stride 4096
// ---------------------------------------------------------------------------
template <int EPI, bool MFAST, int TM>
__global__ __launch_bounds__(256, 5) void hgemm(const _Float16* __restrict__ A,
                                                const _Float16* __restrict__ B,
                                                float* __restrict__ Cf,
                                                _Float16* Ch,
                                                const _Float16* AUXh,
                                                _Float16* Cq,
                                                _Float16* Ck,
                                                _Float16* Cv,
                                                int M, int N, int K) {
    constexpr int WN = (TM == 128) ? 2 : 4;
    constexpr int CW = 128 / WN;
    constexpr int FN = CW / 16;
    __shared__ __align__(16) _Float16 As[2][TM * 32];
    __shared__ __align__(16) _Float16 Bs[2][128 * 32];
    const int tid = threadIdx.x;
    const int lane = tid & 63;
    const int wave = tid >> 6;
    const int wr = (TM == 128) ? (wave >> 1) : 0;
    const int wc = (TM == 128) ? (wave & 1) : wave;
    const int l15 = lane & 15, g = lane >> 4;

    // bijective XCD chunk swizzle (m204)
    const int gm = M / TM, gn = N >> 7, nwg = gm * gn;
    const int orig = blockIdx.x;
    const int q8 = nwg >> 3, r8 = nwg & 7, xcd = orig & 7, j8 = orig >> 3;
    const int wgid = (xcd < r8 ? xcd * (q8 + 1) : r8 * (q8 + 1) + (xcd - r8) * q8) + j8;
    const int bm = MFAST ? (wgid % gm) : (wgid / gn);
    const int bn = MFAST ? (wgid / gm) : (wgid % gn);
    const int m0 = bm * TM, n0 = bn * 128;

    const int offA0 = wave * (TM * 16) + lane * 16;
    const int offA1 = offA0 + 1024;
    const int rA0 = offA0 >> 6, kA0 = offA0 & 63;
    const int rA1 = offA1 >> 6, kA1 = offA1 & 63;
    const int offB0 = wave * 2048 + lane * 16;
    const int offB1 = offB0 + 1024;
    const int rB0 = offB0 >> 6, kB0 = offB0 & 63;
    const int rB1 = offB1 >> 6, kB1 = offB1 & 63;
    const char* gA0 = (const char*)(A + (size_t)(m0 + rA0) * K) + kA0;
    const char* gA1 = (const char*)(A + (size_t)(m0 + rA1) * K) + kA1;
    const char* gB0 = (const char*)(B + (size_t)(n0 + rB0) * K) + kB0;
    const char* gB1 = (const char*)(B + (size_t)(n0 + rB1) * K) + kB1;

#define STAGE(buf)                                                     \
    do {                                                               \
        gload16(gA0, (char*)As[buf] + offA0);                          \
        if constexpr (TM == 128) gload16(gA1, (char*)As[buf] + offA1); \
        gload16(gB0, (char*)Bs[buf] + offB0);                          \
        gload16(gB1, (char*)Bs[buf] + offB1);                          \
        gA0 += 64; gA1 += 64; gB0 += 64; gB1 += 64;                    \
    } while (0)

    floatx4 acc[4][FN];
#pragma unroll
    for (int i = 0; i < 4; i++)
#pragma unroll
        for (int j = 0; j < FN; j++) acc[i][j] = 0;

    STAGE(0);
    __syncthreads();
    int cur = 0;
    for (int kk = 0; kk < K; kk += 32) {
        if (kk + 32 < K) STAGE(cur ^ 1);
        half8 aF[4], bF[FN];
#pragma unroll
        for (int i = 0; i < 4; i++)
            aF[i] = *(const half8*)&As[cur][(wr * 64 + i * 16 + l15) * 32 + g * 8];
#pragma unroll
        for (int j = 0; j < FN; j++)
            bF[j] = *(const half8*)&Bs[cur][(wc * CW + j * 16 + l15) * 32 + g * 8];
#pragma unroll
        for (int i = 0; i < 4; i++)
#pragma unroll
            for (int j = 0; j < FN; j++)
                acc[i][j] = __builtin_amdgcn_mfma_f32_16x16x32_f16(aF[i], bF[j], acc[i][j], 0, 0, 0);
        __syncthreads();
        cur ^= 1;
    }
#undef STAGE

    // epilogue: D frag mapping col = lane&15, row = (lane>>4)*4 + e
    const int rb = m0 + wr * 64 + g * 4;
    const int cb = n0 + wc * CW + l15;
    if (EPI == 4) {
        const int sel = n0 >> 10;
        _Float16* Cx = sel == 0 ? Cq : (sel == 1 ? Ck : Cv);
        const int cb0 = cb - sel * 1024;
#pragma unroll
        for (int i = 0; i < 4; i++) {
#pragma unroll
            for (int e = 0; e < 4; e++) {
                const int row = rb + i * 16 + e;
                const int pos = row & (S_SZ - 1);
#pragma unroll
                for (int j = 0; j < FN; j++) {
                    float v = acc[i][j][e];
                    const int col = cb0 + j * 16;
                    if (sel < 2) {
                        const float pp = __shfl_xor(v, 1, 64);
                        const int pi = (col & 63) >> 1;
                        const float invf = exp2f((float)pi * -0.41524101186f);
                        float sn, cs;
                        sincosf((float)pos * invf, &sn, &cs);
                        v = (col & 1) ? (pp * sn + v * cs) : (v * cs - pp * sn);
                    }
                    Cx[(size_t)row * 1024 + col] = (_Float16)v;
                }
            }
        }
        return;
    }
#pragma unroll
    for (int i = 0; i < 4; i++) {
#pragma unroll
        for (int e = 0; e < 4; e++) {
            const int row = rb + i * 16 + e;
#pragma unroll
            for (int j = 0; j < FN; j++) {
                const float v = acc[i][j][e];
                const int col = cb + j * 16;
                if (EPI == 0) {
                    Cf[(size_t)row * N + col] = v;
                } else if (EPI == 1) {
                    Cf[(size_t)row * N + col] += v;
                } else if (EPI == 2) {
                    Ch[(size_t)row * N + col] =
                        (_Float16)(v / (1.0f + __expf(-v)));
                } else if (EPI == 3) {
                    const size_t idx = (size_t)row * N + col;
                    Ch[idx] = (_Float16)((float)AUXh[idx] * v);
                } else if (EPI == 5) {
                    if (col < 4096)
                        Ch[(size_t)row * 4096 + col] =
                            (_Float16)(v / (1.0f + __expf(-v)));
                    else
                        Cq[(size_t)row * 4096 + col - 4096] = (_Float16)v;
                }
            }
        }
    }
}

// ---------------------------------------------------------------------------
// Per-head V transpose: vh[b,s,h*64+d] -> vt[(b*16+h)*64+d][s]
// ---------------------------------------------------------------------------
__global__ __launch_bounds__(256) void vtrans(const _Float16* __restrict__ vh,
                                              _Float16* __restrict__ vt) {
    __shared__ __align__(16) _Float16 Ls[64][80];
    const int t = threadIdx.x;
    const int s0 = blockIdx.x * 64;
    const int bh = blockIdx.y;
    const int b = bh >> 4, h = bh & 15;
#pragma unroll
    for (int p = 0; p < 2; ++p) {
        const int sl = p * 32 + (t >> 3);
        const int d = (t & 7) * 8;
        *(half8*)&Ls[sl][d] =
            *(const half8*)&vh[((size_t)b * S_SZ + s0 + sl) * D_SZ + h * 64 + d];
    }
    __syncthreads();
#pragma unroll
    for (int p = 0; p < 2; ++p) {
        const int d = p * 32 + (t >> 3);
        const int sc = (t & 7) * 8;
        half8 v;
#pragma unroll
        for (int j = 0; j < 8; ++j) v[j] = Ls[sc + j][d];
        *(half8*)&vt[((size_t)bh * 64 + d) * S_SZ + s0 + sc] = v;
    }
}

// ---------------------------------------------------------------------------
// MFMA flash attention (causal), fp16 in/out, fp32 softmax state.
// Paired q-tiles (bx, 15-bx), K/V LDS-staged w/ 2-phase prefetch + XOR swizzle.
// s_setprio(1) around MFMA bursts (T5; blocks independent -> role diversity).
// ---------------------------------------------------------------------------
__global__ __launch_bounds__(256) void attn_mfma(const _Float16* __restrict__ qh,
                                                 const _Float16* __restrict__ kh,
                                                 const _Float16* __restrict__ vt,
                                                 _Float16* __restrict__ o) {
    __shared__ __align__(16) _Float16 Ks[2][64 * 64];
    __shared__ __align__(16) _Float16 Vs[2][64 * 64];
    __shared__ __align__(16) _Float16 Ps[4][16][88];
    const int tid = threadIdx.x;
    const int lane = tid & 63, wave = tid >> 6;
    const int l15 = lane & 15, g = lane >> 4;
    const int bx = blockIdx.x;
    const int bh = blockIdx.y;
    const int h = bh & 15;
    const size_t tokb = (size_t)(bh >> 4) * S_SZ;

    const int qt0 = bx, qt1 = 15 - bx;
    const int qb0 = qt0 * 64, qb1 = qt1 * 64;
    const int ktmax = qt1;

    const int qrow = l15 * 4 + wave;
    half8 qA0[2], qA1[2];
#pragma unroll
    for (int kk = 0; kk < 2; ++kk) {
        qA0[kk] = *(const half8*)&qh[(tokb + qb0 + qrow) * D_SZ + h * 64 + kk * 32 + g * 8];
        qA1[kk] = *(const half8*)&qh[(tokb + qb1 + qrow) * D_SZ + h * 64 + kk * 32 + g * 8];
    }

    floatx4 accO0[4], accO1[4];
#pragma unroll
    for (int s = 0; s < 4; s++) { accO0[s] = 0; accO1[s] = 0; }
    float m0_[4] = {NEG_INF, NEG_INF, NEG_INF, NEG_INF};
    float l0_[4] = {0.0f, 0.0f, 0.0f, 0.0f};
    float m1_[4] = {NEG_INF, NEG_INF, NEG_INF, NEG_INF};
    float l1_[4] = {0.0f, 0.0f, 0.0f, 0.0f};

    const char* KbB = (const char*)(kh + tokb * D_SZ + h * 64);
    const char* VbB = (const char*)(vt + (size_t)bh * 64 * S_SZ);
    const int so0 = wave * 2048 + lane * 16;
    const int so1 = so0 + 1024;
    const int r0 = so0 >> 7, c0 = (so0 >> 4) & 7;
    const int r1 = so1 >> 7, c1 = (so1 >> 4) & 7;
    const int gc0 = ((c0 ^ (r0 & 7)) << 4);
    const int gc1 = ((c1 ^ (r1 & 7)) << 4);

#define STAGEKV(buf, kt)                                                   \
    do {                                                                   \
        const size_t kvr = (size_t)(kt) * 64;                              \
        gload16(KbB + (kvr + r0) * 2048 + gc0, (char*)Ks[buf] + so0);      \
        gload16(KbB + (kvr + r1) * 2048 + gc1, (char*)Ks[buf] + so1);      \
        gload16(VbB + r0 * 2048 + kvr * 2 + gc0, (char*)Vs[buf] + so0);    \
        gload16(VbB + r1 * 2048 + kvr * 2 + gc1, (char*)Vs[buf] + so1);    \
    } while (0)

#define LDSW(arr, rr, cc) \
    (*(const half8*)&(arr)[(rr) * 64 + ((((cc) ^ ((rr) & 7))) << 3)])

    auto computeTile = [&](const half8* qA, floatx4* accO, float* m_, float* l_,
                           int qbase, int kt, bool diag, int buf) {
        const int kv0 = kt * 64;
        floatx4 accS[4];
        __builtin_amdgcn_s_setprio(1);
#pragma unroll
        for (int sub = 0; sub < 4; ++sub) {
            accS[sub] = 0;
#pragma unroll
            for (int kk = 0; kk < 2; ++kk) {
                half8 kB = LDSW(Ks[buf], sub * 16 + l15, kk * 4 + g);
                accS[sub] = __builtin_amdgcn_mfma_f32_16x16x32_f16(qA[kk], kB, accS[sub], 0, 0, 0);
            }
        }
        __builtin_amdgcn_s_setprio(0);
        float sv[4][4];
        float mx[4] = {NEG_INF, NEG_INF, NEG_INF, NEG_INF};
#pragma unroll
        for (int sub = 0; sub < 4; ++sub)
#pragma unroll
            for (int e = 0; e < 4; ++e) {
                float s = accS[sub][e] * 0.125f;
                if (diag && (kv0 + sub * 16 + l15 > qbase + (g * 4 + e) * 4 + wave))
                    s = NEG_INF;
                sv[sub][e] = s;
                mx[e] = fmaxf(mx[e], s);
            }
#pragma unroll
        for (int msk = 1; msk <= 8; msk <<= 1)
#pragma unroll
            for (int e = 0; e < 4; ++e)
                mx[e] = fmaxf(mx[e], __shfl_xor(mx[e], msk, 64));
        float sf[4];
#pragma unroll
        for (int e = 0; e < 4; ++e) {
            const float mn = fmaxf(m_[e], mx[e]);
            sf[e] = __expf(m_[e] - mn);
            m_[e] = mn;
        }
        float rs[4] = {0.0f, 0.0f, 0.0f, 0.0f};
#pragma unroll
        for (int sub = 0; sub < 4; ++sub)
#pragma unroll
            for (int e = 0; e < 4; ++e) {
                const float p = __expf(sv[sub][e] - m_[e]);
                sv[sub][e] = p;
                rs[e] += p;
            }
#pragma unroll
        for (int msk = 1; msk <= 8; msk <<= 1)
#pragma unroll
            for (int e = 0; e < 4; ++e)
                rs[e] += __shfl_xor(rs[e], msk, 64);
#pragma unroll
        for (int e = 0; e < 4; ++e) l_[e] = l_[e] * sf[e] + rs[e];
#pragma unroll
        for (int sub = 0; sub < 4; ++sub)
#pragma unroll
            for (int e = 0; e < 4; ++e) accO[sub][e] *= sf[e];
#pragma unroll
        for (int sub = 0; sub < 4; ++sub)
#pragma unroll
            for (int e = 0; e < 4; ++e)
                Ps[wave][g * 4 + e][sub * 16 + l15] = (_Float16)sv[sub][e];
        half8 aP[2];
        aP[0] = *(const half8*)&Ps[wave][l15][g * 8];
        aP[1] = *(const half8*)&Ps[wave][l15][32 + g * 8];
        __builtin_amdgcn_s_setprio(1);
#pragma unroll
        for (int sub = 0; sub < 4; ++sub)
#pragma unroll
            for (int kk = 0; kk < 2; ++kk) {
                half8 vB = LDSW(Vs[buf], sub * 16 + l15, kk * 4 + g);
                accO[sub] = __builtin_amdgcn_mfma_f32_16x16x32_f16(aP[kk], vB, accO[sub], 0, 0, 0);
            }
        __builtin_amdgcn_s_setprio(0);
    };

    STAGEKV(0, 0);
    __syncthreads();
    int cur = 0;
    for (int kt = 0; kt <= ktmax; ++kt) {
        if (kt < ktmax) STAGEKV(cur ^ 1, kt + 1);
        computeTile(qA1, accO1, m1_, l1_, qb1, kt, kt == qt1, cur);
        if (kt <= qt0)
            computeTile(qA0, accO0, m0_, l0_, qb0, kt, kt == qt0, cur);
        __syncthreads();
        cur ^= 1;
    }
#undef STAGEKV
#undef LDSW

#pragma unroll
    for (int sub = 0; sub < 4; ++sub)
#pragma unroll
        for (int e = 0; e < 4; ++e) {
            const int rr = (g * 4 + e) * 4 + wave;
            o[(tokb + qb1 + rr) * D_SZ + h * 64 + sub * 16 + l15] =
                (_Float16)(accO1[sub][e] / l1_[e]);
            o[(tokb + qb0 + rr) * D_SZ + h * 64 + sub * 16 + l15] =
                (_Float16)(accO0[sub][e] / l0_[e]);
        }
}

// ---------------------------------------------------------------------------
// Host-side launch
// ---------------------------------------------------------------------------
extern "C" void kernel_launch(void* const* d_in, const int* in_sizes, int n_in,
                              void* d_out, int out_size, void* d_ws, size_t ws_size,
                              hipStream_t stream) {
    const int*   token_ids  = (const int*)d_in[0];
    const float* tok_emb    = (const float*)d_in[1];
    const float* lm_head_w  = (const float*)d_in[2];
    const float* ln_final_w = (const float*)d_in[3];
    const float* q_w        = (const float*)d_in[4];
    const float* k_w        = (const float*)d_in[5];
    const float* v_w        = (const float*)d_in[6];
    const float* o_w        = (const float*)d_in[7];
    const float* ln1_w      = (const float*)d_in[8];
    const float* ln2_w      = (const float*)d_in[9];
    const float* w1         = (const float*)d_in[10];
    const float* w2         = (const float*)d_in[11];
    const float* w3         = (const float*)d_in[12];
    float* out = (float*)d_out;

    char* W = (char*)d_ws;
    const size_t MB = 1u << 20;
    float*    x    = (float*)(W + 0);           // 8 MB
    _Float16* h    = (_Float16*)(W + 8 * MB);   // 4 MB
    _Float16* ao   = (_Float16*)(W + 12 * MB);  // 4 MB
    _Float16* wq   = (_Float16*)(W + 16 * MB);  // 8 MB: q/k/v/o contiguous
    _Float16* wo   = wq + 3 * (1u << 20);
    _Float16* ww1  = (_Float16*)(W + 24 * MB);  // 24 MB: w1/w3/w2 contiguous
    _Float16* ww2  = ww1 + 2 * (F_SZ * D_SZ);
    _Float16* qh   = (_Float16*)(W + 48 * MB);  // 4 MB  (dead during FFN)
    _Float16* kh   = (_Float16*)(W + 52 * MB);  // 4 MB
    _Float16* vh   = (_Float16*)(W + 56 * MB);  // 4 MB
    _Float16* vt   = (_Float16*)(W + 60 * MB);  // 4 MB
    _Float16* ff3h = (_Float16*)(W + 48 * MB);  // 16 MB, overlaps qh..vt (dead)
    _Float16* ff1h = (_Float16*)(W + 64 * MB);  // 16 MB -> 80 MB
    _Float16* whead = (_Float16*)(W + 24 * MB); // 62.5 MB, overlaps dead ww*/ff*

    embed_kernel<<<NTOK, 256, 0, stream>>>(token_ids, tok_emb, x);

    const int nDD8 = D_SZ * D_SZ / 8;     // 131072
    const int nFD8 = F_SZ * D_SZ / 8;     // 524288
    const int nCNV = 4 * nDD8 + 3 * nFD8; // 2097152
    const dim3 gQKV(3 * D_SZ / 128 * (NTOK / 128));   // 384
    const dim3 gD64(D_SZ / 128 * (NTOK / 64));        // 256 (TM=64)
    const dim3 gW13(2 * F_SZ / 128 * (NTOK / 128));   // 1024
    const dim3 gATT(S_SZ / 128, B_SZ * H_SZ);         // (8,32), paired tiles
    const dim3 gVT(S_SZ / 64, B_SZ * H_SZ);

    for (int l = 0; l < L_SZ; l++) {
        const size_t oDD = (size_t)l * D_SZ * D_SZ;
        const size_t oFD = (size_t)l * F_SZ * D_SZ;
        rmsnorm_kernel<<<NTOK, 256, 0, stream>>>(x, ln1_w + (size_t)l * D_SZ, h);
        f2h7<<<nCNV / 256, 256, 0, stream>>>(q_w + oDD, k_w + oDD, v_w + oDD,
                                             o_w + oDD, w1 + oFD, w3 + oFD,
                                             w2 + oFD, wq, nDD8, nFD8);
        hgemm<4, true, 128><<<gQKV, 256, 0, stream>>>(h, wq, nullptr, nullptr, nullptr,
                                                      qh, kh, vh, NTOK, 3 * D_SZ, D_SZ);
        vtrans<<<gVT, 256, 0, stream>>>(vh, vt);
        attn_mfma<<<gATT, 256, 0, stream>>>(qh, kh, vt, ao);
        hgemm<1, false, 64><<<gD64, 256, 0, stream>>>(ao, wo, x, nullptr, nullptr,
                                                      nullptr, nullptr, nullptr, NTOK, D_SZ, D_SZ);
        rmsnorm_kernel<<<NTOK, 256, 0, stream>>>(x, ln2_w + (size_t)l * D_SZ, h);
        // fused w1 || w3 (N = 8192) at 128^2, split epilogue; then combine
        hgemm<5, true, 128><<<gW13, 256, 0, stream>>>(h, ww1, nullptr, ff1h, nullptr,
                                                      ff3h, nullptr, nullptr, NTOK, 2 * F_SZ, D_SZ);
        hmul<<<NTOK * F_SZ / 8 / 256, 256, 0, stream>>>(ff1h, ff3h, NTOK * F_SZ / 8);
        hgemm<1, false, 64><<<gD64, 256, 0, stream>>>(ff1h, ww2, x, nullptr, nullptr,
                                                      nullptr, nullptr, nullptr, NTOK, D_SZ, F_SZ);
    }
    rmsnorm_kernel<<<NTOK, 256, 0, stream>>>(x, ln_final_w, h);
    const int nVD8 = V_SZ * D_SZ / 8;
    f2h<<<(nVD8 + 255) / 256, 256, 0, stream>>>(lm_head_w, whead, nVD8);
    const dim3 gOUT(V_SZ / 128 * (NTOK / 128));       // 4000
    hgemm<0, true, 128><<<gOUT, 256, 0, stream>>>(h, whead, out, nullptr, nullptr,
                                                  nullptr, nullptr, nullptr, NTOK, V_SZ, D_SZ);
}

// Round 8
// 1242.188 us; speedup vs baseline: 8.4114x; 1.0015x over previous
//
#include <hip/hip_runtime.h>
#include <math.h>

// Problem constants (from reference)
#define V_SZ 32000
#define D_SZ 1024
#define H_SZ 16
#define L_SZ 4
#define F_SZ 4096
#define S_SZ 1024
#define B_SZ 2
#define DK 64              // D/H
#define NTOK (B_SZ * S_SZ) // 2048
#define NEG_INF -3.0e38f

typedef _Float16 half8 __attribute__((ext_vector_type(8)));
typedef _Float16 half4 __attribute__((ext_vector_type(4)));
typedef float floatx4 __attribute__((ext_vector_type(4)));

// async global->LDS, 16B per lane; lds dest is wave-uniform base + lane*16.
__device__ __forceinline__ void gload16(const void* g, void* l) {
    __builtin_amdgcn_global_load_lds(
        (const __attribute__((address_space(1))) unsigned int*)g,
        (__attribute__((address_space(3))) unsigned int*)l, 16, 0, 0);
}

// ---------------------------------------------------------------------------
// fp32 -> fp16 conversion: all 7 per-layer weight mats in one launch.
// ---------------------------------------------------------------------------
__global__ __launch_bounds__(256) void f2h7(const float* __restrict__ sq,
                                            const float* __restrict__ sk,
                                            const float* __restrict__ sv,
                                            const float* __restrict__ so,
                                            const float* __restrict__ s1,
                                            const float* __restrict__ s3,
                                            const float* __restrict__ s2,
                                            _Float16* __restrict__ d,
                                            int nDD8, int nFD8) {
    const int i = blockIdx.x * 256 + threadIdx.x;
    const float* s;
    int off;
    if (i < 4 * nDD8) {
        const int sel = i / nDD8;
        off = i - sel * nDD8;
        s = sel == 0 ? sq : (sel == 1 ? sk : (sel == 2 ? sv : so));
    } else {
        const int j = i - 4 * nDD8;
        const int sel = j / nFD8;
        off = j - sel * nFD8;
        s = sel == 0 ? s1 : (sel == 1 ? s3 : s2);
    }
    const float4 a = ((const float4*)s)[2 * off];
    const float4 b = ((const float4*)s)[2 * off + 1];
    half8 h = {(_Float16)a.x, (_Float16)a.y, (_Float16)a.z, (_Float16)a.w,
               (_Float16)b.x, (_Float16)b.y, (_Float16)b.z, (_Float16)b.w};
    ((half8*)d)[i] = h;
}

__global__ __launch_bounds__(256) void f2h(const float* __restrict__ in,
                                           _Float16* __restrict__ out, int n8) {
    const int i = blockIdx.x * 256 + threadIdx.x;
    if (i >= n8) return;
    const float4 a = ((const float4*)in)[2 * i];
    const float4 b = ((const float4*)in)[2 * i + 1];
    half8 h = {(_Float16)a.x, (_Float16)a.y, (_Float16)a.z, (_Float16)a.w,
               (_Float16)b.x, (_Float16)b.y, (_Float16)b.z, (_Float16)b.w};
    ((half8*)out)[i] = h;
}

// ---------------------------------------------------------------------------
// Embedding gather (fp32)
// ---------------------------------------------------------------------------
__global__ __launch_bounds__(256) void embed_kernel(const int* __restrict__ ids,
                                                    const float* __restrict__ emb,
                                                    float* __restrict__ x) {
    const int row = blockIdx.x;
    const int id = ids[row];
    const float4* src = (const float4*)(emb + (size_t)id * D_SZ);
    float4* dst = (float4*)(x + (size_t)row * D_SZ);
    dst[threadIdx.x] = src[threadIdx.x];
}

// ---------------------------------------------------------------------------
// RMSNorm: fp32 in, fp16 out
// ---------------------------------------------------------------------------
__global__ __launch_bounds__(256) void rmsnorm_kernel(const float* __restrict__ x,
                                                      const float* __restrict__ w,
                                                      _Float16* __restrict__ out) {
    const int row = blockIdx.x;
    const int tid = threadIdx.x;
    const float4 v = ((const float4*)(x + (size_t)row * D_SZ))[tid];
    float ss = v.x * v.x + v.y * v.y + v.z * v.z + v.w * v.w;
#pragma unroll
    for (int off = 32; off > 0; off >>= 1) ss += __shfl_down(ss, off, 64);
    __shared__ float red[4];
    if ((tid & 63) == 0) red[tid >> 6] = ss;
    __syncthreads();
    const float tot = red[0] + red[1] + red[2] + red[3];
    const float inv = 1.0f / (sqrtf(tot * (1.0f / (float)D_SZ)) + 1e-5f);
    const float4 wv = ((const float4*)w)[tid];
    half4 o = {(_Float16)(v.x * inv * wv.x), (_Float16)(v.y * inv * wv.y),
               (_Float16)(v.z * inv * wv.z), (_Float16)(v.w * inv * wv.w)};
    ((half4*)(out + (size_t)row * D_SZ))[tid] = o;
}

// ---------------------------------------------------------------------------
// MFMA fp16 GEMM (NT): C[M,N] = A[M,K] * B[N,K]^T, fp32 accumulate.
// Tile TM x 128, BK=32, 4 waves. 2-phase prefetch, double-buffered LDS.
// EPI: 0 = Cf store; 1 = Cf += ; 2 = Ch = swish(v); 3 = Ch = AUXh * v;
//      4 = qkv split store (fp16) with fused RoPE on q,k
// ---------------------------------------------------------------------------
template <int EPI, bool MFAST, int TM>
__global__ __launch_bounds__(256) void hgemm(const _Float16* __restrict__ A,
                                             const _Float16* __restrict__ B,
                                             float* __restrict__ Cf,
                                             _Float16* Ch,
                                             const _Float16* AUXh,
                                             _Float16* Cq,
                                             _Float16* Ck,
                                             _Float16* Cv,
                                             int M, int N, int K) {
    constexpr int WN = (TM == 128) ? 2 : 4;
    constexpr int CW = 128 / WN;
    constexpr int FN = CW / 16;
    __shared__ __align__(16) _Float16 As[2][TM * 32];
    __shared__ __align__(16) _Float16 Bs[2][128 * 32];
    const int tid = threadIdx.x;
    const int lane = tid & 63;
    const int wave = tid >> 6;
    const int wr = (TM == 128) ? (wave >> 1) : 0;
    const int wc = (TM == 128) ? (wave & 1) : wave;
    const int l15 = lane & 15, g = lane >> 4;

    // bijective XCD chunk swizzle (m204)
    const int gm = M / TM, gn = N >> 7, nwg = gm * gn;
    const int orig = blockIdx.x;
    const int q8 = nwg >> 3, r8 = nwg & 7, xcd = orig & 7, j8 = orig >> 3;
    const int wgid = (xcd < r8 ? xcd * (q8 + 1) : r8 * (q8 + 1) + (xcd - r8) * q8) + j8;
    const int bm = MFAST ? (wgid % gm) : (wgid / gn);
    const int bn = MFAST ? (wgid / gm) : (wgid % gn);
    const int m0 = bm * TM, n0 = bn * 128;

    const int offA0 = wave * (TM * 16) + lane * 16;
    const int offA1 = offA0 + 1024;
    const int rA0 = offA0 >> 6, kA0 = offA0 & 63;
    const int rA1 = offA1 >> 6, kA1 = offA1 & 63;
    const int offB0 = wave * 2048 + lane * 16;
    const int offB1 = offB0 + 1024;
    const int rB0 = offB0 >> 6, kB0 = offB0 & 63;
    const int rB1 = offB1 >> 6, kB1 = offB1 & 63;
    const char* gA0 = (const char*)(A + (size_t)(m0 + rA0) * K) + kA0;
    const char* gA1 = (const char*)(A + (size_t)(m0 + rA1) * K) + kA1;
    const char* gB0 = (const char*)(B + (size_t)(n0 + rB0) * K) + kB0;
    const char* gB1 = (const char*)(B + (size_t)(n0 + rB1) * K) + kB1;

#define STAGE(buf)                                                     \
    do {                                                               \
        gload16(gA0, (char*)As[buf] + offA0);                          \
        if constexpr (TM == 128) gload16(gA1, (char*)As[buf] + offA1); \
        gload16(gB0, (char*)Bs[buf] + offB0);                          \
        gload16(gB1, (char*)Bs[buf] + offB1);                          \
        gA0 += 64; gA1 += 64; gB0 += 64; gB1 += 64;                    \
    } while (0)

    floatx4 acc[4][FN];
#pragma unroll
    for (int i = 0; i < 4; i++)
#pragma unroll
        for (int j = 0; j < FN; j++) acc[i][j] = 0;

    STAGE(0);
    __syncthreads();
    int cur = 0;
    for (int kk = 0; kk < K; kk += 32) {
        if (kk + 32 < K) STAGE(cur ^ 1);
        half8 aF[4], bF[FN];
#pragma unroll
        for (int i = 0; i < 4; i++)
            aF[i] = *(const half8*)&As[cur][(wr * 64 + i * 16 + l15) * 32 + g * 8];
#pragma unroll
        for (int j = 0; j < FN; j++)
            bF[j] = *(const half8*)&Bs[cur][(wc * CW + j * 16 + l15) * 32 + g * 8];
#pragma unroll
        for (int i = 0; i < 4; i++)
#pragma unroll
            for (int j = 0; j < FN; j++)
                acc[i][j] = __builtin_amdgcn_mfma_f32_16x16x32_f16(aF[i], bF[j], acc[i][j], 0, 0, 0);
        __syncthreads();
        cur ^= 1;
    }
#undef STAGE

    // epilogue: D frag mapping col = lane&15, row = (lane>>4)*4 + e
    const int rb = m0 + wr * 64 + g * 4;
    const int cb = n0 + wc * CW + l15;
    if (EPI == 4) {
        const int sel = n0 >> 10;
        _Float16* Cx = sel == 0 ? Cq : (sel == 1 ? Ck : Cv);
        const int cb0 = cb - sel * 1024;
#pragma unroll
        for (int i = 0; i < 4; i++) {
#pragma unroll
            for (int e = 0; e < 4; e++) {
                const int row = rb + i * 16 + e;
                const int pos = row & (S_SZ - 1);
#pragma unroll
                for (int j = 0; j < FN; j++) {
                    float v = acc[i][j][e];
                    const int col = cb0 + j * 16;
                    if (sel < 2) {
                        const float pp = __shfl_xor(v, 1, 64);
                        const int pi = (col & 63) >> 1;
                        const float invf = exp2f((float)pi * -0.41524101186f);
                        float sn, cs;
                        sincosf((float)pos * invf, &sn, &cs);
                        v = (col & 1) ? (pp * sn + v * cs) : (v * cs - pp * sn);
                    }
                    Cx[(size_t)row * 1024 + col] = (_Float16)v;
                }
            }
        }
        return;
    }
#pragma unroll
    for (int i = 0; i < 4; i++) {
#pragma unroll
        for (int e = 0; e < 4; e++) {
            const int row = rb + i * 16 + e;
#pragma unroll
            for (int j = 0; j < FN; j++) {
                const float v = acc[i][j][e];
                const int col = cb + j * 16;
                if (EPI == 0) {
                    Cf[(size_t)row * N + col] = v;
                } else if (EPI == 1) {
                    Cf[(size_t)row * N + col] += v;
                } else if (EPI == 2) {
                    Ch[(size_t)row * N + col] =
                        (_Float16)(v / (1.0f + __expf(-v)));
                } else if (EPI == 3) {
                    const size_t idx = (size_t)row * N + col;
                    Ch[idx] = (_Float16)((float)AUXh[idx] * v);
                }
            }
        }
    }
}

// ---------------------------------------------------------------------------
// Fused SwiGLU GEMM: out[M,F] = swish(A@B1^T) * (A@B3^T), fp16 out.
// TM=64 x 128-col tile, BK=32, 4 waves along N (each 64x32). Both B tiles
// staged; A staged once (halves A traffic vs two GEMMs); no hmul pass.
// ---------------------------------------------------------------------------
__global__ __launch_bounds__(256) void hgemm_ff(const _Float16* __restrict__ A,
                                                const _Float16* __restrict__ B1,
                                                const _Float16* __restrict__ B3,
                                                _Float16* __restrict__ Ch,
                                                int M, int N, int K) {
    __shared__ __align__(16) _Float16 As[2][64 * 32];
    __shared__ __align__(16) _Float16 Bs1[2][128 * 32];
    __shared__ __align__(16) _Float16 Bs3[2][128 * 32];
    const int tid = threadIdx.x;
    const int lane = tid & 63;
    const int wave = tid >> 6;
    const int l15 = lane & 15, g = lane >> 4;

    const int gm = M >> 6, gn = N >> 7, nwg = gm * gn;
    const int orig = blockIdx.x;
    const int q8 = nwg >> 3, r8 = nwg & 7, xcd = orig & 7, j8 = orig >> 3;
    const int wgid = (xcd < r8 ? xcd * (q8 + 1) : r8 * (q8 + 1) + (xcd - r8) * q8) + j8;
    const int bm = wgid % gm, bn = wgid / gm;   // m-fastest (share B panels)
    const int m0 = bm * 64, n0 = bn * 128;

    // A tile: 64 rows x 64 B = 4 KB -> 1 KB (1 gload) per wave
    const int offA = wave * 1024 + lane * 16;
    const int rA = offA >> 6, kA = offA & 63;
    // B tiles: 128 rows x 64 B = 8 KB -> 2 KB (2 gloads) per wave
    const int offB0 = wave * 2048 + lane * 16;
    const int offB1 = offB0 + 1024;
    const int rB0 = offB0 >> 6, kB0 = offB0 & 63;
    const int rB1 = offB1 >> 6, kB1 = offB1 & 63;
    const char* gA  = (const char*)(A  + (size_t)(m0 + rA) * K) + kA;
    const char* gB10 = (const char*)(B1 + (size_t)(n0 + rB0) * K) + kB0;
    const char* gB11 = (const char*)(B1 + (size_t)(n0 + rB1) * K) + kB1;
    const char* gB30 = (const char*)(B3 + (size_t)(n0 + rB0) * K) + kB0;
    const char* gB31 = (const char*)(B3 + (size_t)(n0 + rB1) * K) + kB1;

#define STAGEF(buf)                                   \
    do {                                              \
        gload16(gA,   (char*)As[buf]  + offA);        \
        gload16(gB10, (char*)Bs1[buf] + offB0);       \
        gload16(gB11, (char*)Bs1[buf] + offB1);       \
        gload16(gB30, (char*)Bs3[buf] + offB0);       \
        gload16(gB31, (char*)Bs3[buf] + offB1);       \
        gA += 64; gB10 += 64; gB11 += 64;             \
        gB30 += 64; gB31 += 64;                       \
    } while (0)

    floatx4 acc1[4][2], acc3[4][2];
#pragma unroll
    for (int i = 0; i < 4; i++)
#pragma unroll
        for (int j = 0; j < 2; j++) { acc1[i][j] = 0; acc3[i][j] = 0; }

    STAGEF(0);
    __syncthreads();
    int cur = 0;
    for (int kk = 0; kk < K; kk += 32) {
        if (kk + 32 < K) STAGEF(cur ^ 1);
        half8 aF[4], b1F[2], b3F[2];
#pragma unroll
        for (int i = 0; i < 4; i++)
            aF[i] = *(const half8*)&As[cur][(i * 16 + l15) * 32 + g * 8];
#pragma unroll
        for (int j = 0; j < 2; j++) {
            b1F[j] = *(const half8*)&Bs1[cur][(wave * 32 + j * 16 + l15) * 32 + g * 8];
            b3F[j] = *(const half8*)&Bs3[cur][(wave * 32 + j * 16 + l15) * 32 + g * 8];
        }
#pragma unroll
        for (int i = 0; i < 4; i++)
#pragma unroll
            for (int j = 0; j < 2; j++) {
                acc1[i][j] = __builtin_amdgcn_mfma_f32_16x16x32_f16(aF[i], b1F[j], acc1[i][j], 0, 0, 0);
                acc3[i][j] = __builtin_amdgcn_mfma_f32_16x16x32_f16(aF[i], b3F[j], acc3[i][j], 0, 0, 0);
            }
        __syncthreads();
        cur ^= 1;
    }
#undef STAGEF

    const int cb = n0 + wave * 32 + l15;
#pragma unroll
    for (int i = 0; i < 4; i++) {
#pragma unroll
        for (int e = 0; e < 4; e++) {
            const int row = m0 + i * 16 + g * 4 + e;
#pragma unroll
            for (int j = 0; j < 2; j++) {
                const float v1 = acc1[i][j][e];
                const float v3 = acc3[i][j][e];
                const float sw = v1 / (1.0f + __expf(-v1));
                Ch[(size_t)row * N + cb + j * 16] = (_Float16)(sw * v3);
            }
        }
    }
}

// ---------------------------------------------------------------------------
// Per-head V transpose: vh[b,s,h*64+d] -> vt[(b*16+h)*64+d][s]
// ---------------------------------------------------------------------------
__global__ __launch_bounds__(256) void vtrans(const _Float16* __restrict__ vh,
                                              _Float16* __restrict__ vt) {
    __shared__ __align__(16) _Float16 Ls[64][80];
    const int t = threadIdx.x;
    const int s0 = blockIdx.x * 64;
    const int bh = blockIdx.y;
    const int b = bh >> 4, h = bh & 15;
#pragma unroll
    for (int p = 0; p < 2; ++p) {
        const int sl = p * 32 + (t >> 3);
        const int d = (t & 7) * 8;
        *(half8*)&Ls[sl][d] =
            *(const half8*)&vh[((size_t)b * S_SZ + s0 + sl) * D_SZ + h * 64 + d];
    }
    __syncthreads();
#pragma unroll
    for (int p = 0; p < 2; ++p) {
        const int d = p * 32 + (t >> 3);
        const int sc = (t & 7) * 8;
        half8 v;
#pragma unroll
        for (int j = 0; j < 8; ++j) v[j] = Ls[sc + j][d];
        *(half8*)&vt[((size_t)bh * 64 + d) * S_SZ + s0 + sc] = v;
    }
}

// ---------------------------------------------------------------------------
// MFMA flash attention (causal), fp16 in/out, fp32 softmax state.
// Paired q-tiles (bx, 15-bx), K/V LDS-staged w/ 2-phase prefetch + XOR swizzle.
// ---------------------------------------------------------------------------
__global__ __launch_bounds__(256) void attn_mfma(const _Float16* __restrict__ qh,
                                                 const _Float16* __restrict__ kh,
                                                 const _Float16* __restrict__ vt,
                                                 _Float16* __restrict__ o) {
    __shared__ __align__(16) _Float16 Ks[2][64 * 64];
    __shared__ __align__(16) _Float16 Vs[2][64 * 64];
    __shared__ __align__(16) _Float16 Ps[4][16][88];
    const int tid = threadIdx.x;
    const int lane = tid & 63, wave = tid >> 6;
    const int l15 = lane & 15, g = lane >> 4;
    const int bx = blockIdx.x;
    const int bh = blockIdx.y;
    const int h = bh & 15;
    const size_t tokb = (size_t)(bh >> 4) * S_SZ;

    const int qt0 = bx, qt1 = 15 - bx;
    const int qb0 = qt0 * 64, qb1 = qt1 * 64;
    const int ktmax = qt1;

    const int qrow = l15 * 4 + wave;
    half8 qA0[2], qA1[2];
#pragma unroll
    for (int kk = 0; kk < 2; ++kk) {
        qA0[kk] = *(const half8*)&qh[(tokb + qb0 + qrow) * D_SZ + h * 64 + kk * 32 + g * 8];
        qA1[kk] = *(const half8*)&qh[(tokb + qb1 + qrow) * D_SZ + h * 64 + kk * 32 + g * 8];
    }

    floatx4 accO0[4], accO1[4];
#pragma unroll
    for (int s = 0; s < 4; s++) { accO0[s] = 0; accO1[s] = 0; }
    float m0_[4] = {NEG_INF, NEG_INF, NEG_INF, NEG_INF};
    float l0_[4] = {0.0f, 0.0f, 0.0f, 0.0f};
    float m1_[4] = {NEG_INF, NEG_INF, NEG_INF, NEG_INF};
    float l1_[4] = {0.0f, 0.0f, 0.0f, 0.0f};

    const char* KbB = (const char*)(kh + tokb * D_SZ + h * 64);
    const char* VbB = (const char*)(vt + (size_t)bh * 64 * S_SZ);
    const int so0 = wave * 2048 + lane * 16;
    const int so1 = so0 + 1024;
    const int r0 = so0 >> 7, c0 = (so0 >> 4) & 7;
    const int r1 = so1 >> 7, c1 = (so1 >> 4) & 7;
    const int gc0 = ((c0 ^ (r0 & 7)) << 4);
    const int gc1 = ((c1 ^ (r1 & 7)) << 4);

#define STAGEKV(buf, kt)                                                   \
    do {                                                                   \
        const size_t kvr = (size_t)(kt) * 64;                              \
        gload16(KbB + (kvr + r0) * 2048 + gc0, (char*)Ks[buf] + so0);      \
        gload16(KbB + (kvr + r1) * 2048 + gc1, (char*)Ks[buf] + so1);      \
        gload16(VbB + r0 * 2048 + kvr * 2 + gc0, (char*)Vs[buf] + so0);    \
        gload16(VbB + r1 * 2048 + kvr * 2 + gc1, (char*)Vs[buf] + so1);    \
    } while (0)

#define LDSW(arr, rr, cc) \
    (*(const half8*)&(arr)[(rr) * 64 + ((((cc) ^ ((rr) & 7))) << 3)])

    auto computeTile = [&](const half8* qA, floatx4* accO, float* m_, float* l_,
                           int qbase, int kt, bool diag, int buf) {
        const int kv0 = kt * 64;
        floatx4 accS[4];
        __builtin_amdgcn_s_setprio(1);
#pragma unroll
        for (int sub = 0; sub < 4; ++sub) {
            accS[sub] = 0;
#pragma unroll
            for (int kk = 0; kk < 2; ++kk) {
                half8 kB = LDSW(Ks[buf], sub * 16 + l15, kk * 4 + g);
                accS[sub] = __builtin_amdgcn_mfma_f32_16x16x32_f16(qA[kk], kB, accS[sub], 0, 0, 0);
            }
        }
        __builtin_amdgcn_s_setprio(0);
        float sv[4][4];
        float mx[4] = {NEG_INF, NEG_INF, NEG_INF, NEG_INF};
#pragma unroll
        for (int sub = 0; sub < 4; ++sub)
#pragma unroll
            for (int e = 0; e < 4; ++e) {
                float s = accS[sub][e] * 0.125f;
                if (diag && (kv0 + sub * 16 + l15 > qbase + (g * 4 + e) * 4 + wave))
                    s = NEG_INF;
                sv[sub][e] = s;
                mx[e] = fmaxf(mx[e], s);
            }
#pragma unroll
        for (int msk = 1; msk <= 8; msk <<= 1)
#pragma unroll
            for (int e = 0; e < 4; ++e)
                mx[e] = fmaxf(mx[e], __shfl_xor(mx[e], msk, 64));
        float sf[4];
#pragma unroll
        for (int e = 0; e < 4; ++e) {
            const float mn = fmaxf(m_[e], mx[e]);
            sf[e] = __expf(m_[e] - mn);
            m_[e] = mn;
        }
        float rs[4] = {0.0f, 0.0f, 0.0f, 0.0f};
#pragma unroll
        for (int sub = 0; sub < 4; ++sub)
#pragma unroll
            for (int e = 0; e < 4; ++e) {
                const float p = __expf(sv[sub][e] - m_[e]);
                sv[sub][e] = p;
                rs[e] += p;
            }
#pragma unroll
        for (int msk = 1; msk <= 8; msk <<= 1)
#pragma unroll
            for (int e = 0; e < 4; ++e)
                rs[e] += __shfl_xor(rs[e], msk, 64);
#pragma unroll
        for (int e = 0; e < 4; ++e) l_[e] = l_[e] * sf[e] + rs[e];
#pragma unroll
        for (int sub = 0; sub < 4; ++sub)
#pragma unroll
            for (int e = 0; e < 4; ++e) accO[sub][e] *= sf[e];
#pragma unroll
        for (int sub = 0; sub < 4; ++sub)
#pragma unroll
            for (int e = 0; e < 4; ++e)
                Ps[wave][g * 4 + e][sub * 16 + l15] = (_Float16)sv[sub][e];
        half8 aP[2];
        aP[0] = *(const half8*)&Ps[wave][l15][g * 8];
        aP[1] = *(const half8*)&Ps[wave][l15][32 + g * 8];
        __builtin_amdgcn_s_setprio(1);
#pragma unroll
        for (int sub = 0; sub < 4; ++sub)
#pragma unroll
            for (int kk = 0; kk < 2; ++kk) {
                half8 vB = LDSW(Vs[buf], sub * 16 + l15, kk * 4 + g);
                accO[sub] = __builtin_amdgcn_mfma_f32_16x16x32_f16(aP[kk], vB, accO[sub], 0, 0, 0);
            }
        __builtin_amdgcn_s_setprio(0);
    };

    STAGEKV(0, 0);
    __syncthreads();
    int cur = 0;
    for (int kt = 0; kt <= ktmax; ++kt) {
        if (kt < ktmax) STAGEKV(cur ^ 1, kt + 1);
        computeTile(qA1, accO1, m1_, l1_, qb1, kt, kt == qt1, cur);
        if (kt <= qt0)
            computeTile(qA0, accO0, m0_, l0_, qb0, kt, kt == qt0, cur);
        __syncthreads();
        cur ^= 1;
    }
#undef STAGEKV
#undef LDSW

#pragma unroll
    for (int sub = 0; sub < 4; ++sub)
#pragma unroll
        for (int e = 0; e < 4; ++e) {
            const int rr = (g * 4 + e) * 4 + wave;
            o[(tokb + qb1 + rr) * D_SZ + h * 64 + sub * 16 + l15] =
                (_Float16)(accO1[sub][e] / l1_[e]);
            o[(tokb + qb0 + rr) * D_SZ + h * 64 + sub * 16 + l15] =
                (_Float16)(accO0[sub][e] / l0_[e]);
        }
}

// ---------------------------------------------------------------------------
// Host-side launch
// ---------------------------------------------------------------------------
extern "C" void kernel_launch(void* const* d_in, const int* in_sizes, int n_in,
                              void* d_out, int out_size, void* d_ws, size_t ws_size,
                              hipStream_t stream) {
    const int*   token_ids  = (const int*)d_in[0];
    const float* tok_emb    = (const float*)d_in[1];
    const float* lm_head_w  = (const float*)d_in[2];
    const float* ln_final_w = (const float*)d_in[3];
    const float* q_w        = (const float*)d_in[4];
    const float* k_w        = (const float*)d_in[5];
    const float* v_w        = (const float*)d_in[6];
    const float* o_w        = (const float*)d_in[7];
    const float* ln1_w      = (const float*)d_in[8];
    const float* ln2_w      = (const float*)d_in[9];
    const float* w1         = (const float*)d_in[10];
    const float* w2         = (const float*)d_in[11];
    const float* w3         = (const float*)d_in[12];
    float* out = (float*)d_out;

    char* W = (char*)d_ws;
    const size_t MB = 1u << 20;
    float*    x    = (float*)(W + 0);           // 8 MB
    _Float16* h    = (_Float16*)(W + 8 * MB);   // 4 MB
    _Float16* ao   = (_Float16*)(W + 12 * MB);  // 4 MB
    _Float16* wq   = (_Float16*)(W + 16 * MB);  // 8 MB: q/k/v/o contiguous
    _Float16* wo   = wq + 3 * (1u << 20);
    _Float16* ww1  = (_Float16*)(W + 24 * MB);  // 24 MB: w1/w3/w2 contiguous
    _Float16* ww3  = ww1 + (size_t)F_SZ * D_SZ;
    _Float16* ww2  = ww1 + 2 * (size_t)F_SZ * D_SZ;
    _Float16* qh   = (_Float16*)(W + 48 * MB);  // 4 MB
    _Float16* kh   = (_Float16*)(W + 52 * MB);  // 4 MB
    _Float16* vh   = (_Float16*)(W + 56 * MB);  // 4 MB
    _Float16* vt   = (_Float16*)(W + 60 * MB);  // 4 MB
    _Float16* ff1h = (_Float16*)(W + 64 * MB);  // 16 MB -> 80 MB
    _Float16* whead = (_Float16*)(W + 24 * MB); // 62.5 MB, overlaps dead ww*

    embed_kernel<<<NTOK, 256, 0, stream>>>(token_ids, tok_emb, x);

    const int nDD8 = D_SZ * D_SZ / 8;     // 131072
    const int nFD8 = F_SZ * D_SZ / 8;     // 524288
    const int nCNV = 4 * nDD8 + 3 * nFD8; // 2097152
    const dim3 gQKV(3 * D_SZ / 128 * (NTOK / 128));   // 384
    const dim3 gD64(D_SZ / 128 * (NTOK / 64));        // 256 (TM=64)
    const dim3 gFF(F_SZ / 128 * (NTOK / 64));         // 1024 (fused swiglu)
    const dim3 gATT(S_SZ / 128, B_SZ * H_SZ);         // (8,32), paired tiles
    const dim3 gVT(S_SZ / 64, B_SZ * H_SZ);

    for (int l = 0; l < L_SZ; l++) {
        const size_t oDD = (size_t)l * D_SZ * D_SZ;
        const size_t oFD = (size_t)l * F_SZ * D_SZ;
        rmsnorm_kernel<<<NTOK, 256, 0, stream>>>(x, ln1_w + (size_t)l * D_SZ, h);
        f2h7<<<nCNV / 256, 256, 0, stream>>>(q_w + oDD, k_w + oDD, v_w + oDD,
                                             o_w + oDD, w1 + oFD, w3 + oFD,
                                             w2 + oFD, wq, nDD8, nFD8);
        hgemm<4, true, 128><<<gQKV, 256, 0, stream>>>(h, wq, nullptr, nullptr, nullptr,
                                                      qh, kh, vh, NTOK, 3 * D_SZ, D_SZ);
        vtrans<<<gVT, 256, 0, stream>>>(vh, vt);
        attn_mfma<<<gATT, 256, 0, stream>>>(qh, kh, vt, ao);
        hgemm<1, false, 64><<<gD64, 256, 0, stream>>>(ao, wo, x, nullptr, nullptr,
                                                      nullptr, nullptr, nullptr, NTOK, D_SZ, D_SZ);
        rmsnorm_kernel<<<NTOK, 256, 0, stream>>>(x, ln2_w + (size_t)l * D_SZ, h);
        // fused swiglu: ff1h = swish(h@w1^T) * (h@w3^T)
        hgemm_ff<<<gFF, 256, 0, stream>>>(h, ww1, ww3, ff1h, NTOK, F_SZ, D_SZ);
        hgemm<1, false, 64><<<gD64, 256, 0, stream>>>(ff1h, ww2, x, nullptr, nullptr,
                                                      nullptr, nullptr, nullptr, NTOK, D_SZ, F_SZ);
    }
    rmsnorm_kernel<<<NTOK, 256, 0, stream>>>(x, ln_final_w, h);
    const int nVD8 = V_SZ * D_SZ / 8;
    f2h<<<(nVD8 + 255) / 256, 256, 0, stream>>>(lm_head_w, whead, nVD8);
    const dim3 gOUT(V_SZ / 128 * (NTOK / 128));       // 4000
    hgemm<0, true, 128><<<gOUT, 256, 0, stream>>>(h, whead, out, nullptr, nullptr,
                                                  nullptr, nullptr, nullptr, NTOK, V_SZ, D_SZ);
}

// Round 9
// 1212.284 us; speedup vs baseline: 8.6189x; 1.0247x over previous
//
#include <hip/hip_runtime.h>
#include <math.h>

// Problem constants (from reference)
#define V_SZ 32000
#define D_SZ 1024
#define H_SZ 16
#define L_SZ 4
#define F_SZ 4096
#define S_SZ 1024
#define B_SZ 2
#define DK 64              // D/H
#define NTOK (B_SZ * S_SZ) // 2048
#define NEG_INF -3.0e38f

typedef _Float16 half8 __attribute__((ext_vector_type(8)));
typedef _Float16 half4 __attribute__((ext_vector_type(4)));
typedef float floatx4 __attribute__((ext_vector_type(4)));

// async global->LDS, 16B per lane; lds dest is wave-uniform base + lane*16.
__device__ __forceinline__ void gload16(const void* g, void* l) {
    __builtin_amdgcn_global_load_lds(
        (const __attribute__((address_space(1))) unsigned int*)g,
        (__attribute__((address_space(3))) unsigned int*)l, 16, 0, 0);
}

// ---------------------------------------------------------------------------
// fp32 -> fp16 conversion: all 7 per-layer weight mats in one launch.
// ---------------------------------------------------------------------------
__global__ __launch_bounds__(256) void f2h7(const float* __restrict__ sq,
                                            const float* __restrict__ sk,
                                            const float* __restrict__ sv,
                                            const float* __restrict__ so,
                                            const float* __restrict__ s1,
                                            const float* __restrict__ s3,
                                            const float* __restrict__ s2,
                                            _Float16* __restrict__ d,
                                            int nDD8, int nFD8) {
    const int i = blockIdx.x * 256 + threadIdx.x;
    const float* s;
    int off;
    if (i < 4 * nDD8) {
        const int sel = i / nDD8;
        off = i - sel * nDD8;
        s = sel == 0 ? sq : (sel == 1 ? sk : (sel == 2 ? sv : so));
    } else {
        const int j = i - 4 * nDD8;
        const int sel = j / nFD8;
        off = j - sel * nFD8;
        s = sel == 0 ? s1 : (sel == 1 ? s3 : s2);
    }
    const float4 a = ((const float4*)s)[2 * off];
    const float4 b = ((const float4*)s)[2 * off + 1];
    half8 h = {(_Float16)a.x, (_Float16)a.y, (_Float16)a.z, (_Float16)a.w,
               (_Float16)b.x, (_Float16)b.y, (_Float16)b.z, (_Float16)b.w};
    ((half8*)d)[i] = h;
}

__global__ __launch_bounds__(256) void f2h(const float* __restrict__ in,
                                           _Float16* __restrict__ out, int n8) {
    const int i = blockIdx.x * 256 + threadIdx.x;
    if (i >= n8) return;
    const float4 a = ((const float4*)in)[2 * i];
    const float4 b = ((const float4*)in)[2 * i + 1];
    half8 h = {(_Float16)a.x, (_Float16)a.y, (_Float16)a.z, (_Float16)a.w,
               (_Float16)b.x, (_Float16)b.y, (_Float16)b.z, (_Float16)b.w};
    ((half8*)out)[i] = h;
}

// ---------------------------------------------------------------------------
// Embedding gather (fp32)
// ---------------------------------------------------------------------------
__global__ __launch_bounds__(256) void embed_kernel(const int* __restrict__ ids,
                                                    const float* __restrict__ emb,
                                                    float* __restrict__ x) {
    const int row = blockIdx.x;
    const int id = ids[row];
    const float4* src = (const float4*)(emb + (size_t)id * D_SZ);
    float4* dst = (float4*)(x + (size_t)row * D_SZ);
    dst[threadIdx.x] = src[threadIdx.x];
}

// ---------------------------------------------------------------------------
// RMSNorm: fp32 in, fp16 out
// ---------------------------------------------------------------------------
__global__ __launch_bounds__(256) void rmsnorm_kernel(const float* __restrict__ x,
                                                      const float* __restrict__ w,
                                                      _Float16* __restrict__ out) {
    const int row = blockIdx.x;
    const int tid = threadIdx.x;
    const float4 v = ((const float4*)(x + (size_t)row * D_SZ))[tid];
    float ss = v.x * v.x + v.y * v.y + v.z * v.z + v.w * v.w;
#pragma unroll
    for (int off = 32; off > 0; off >>= 1) ss += __shfl_down(ss, off, 64);
    __shared__ float red[4];
    if ((tid & 63) == 0) red[tid >> 6] = ss;
    __syncthreads();
    const float tot = red[0] + red[1] + red[2] + red[3];
    const float inv = 1.0f / (sqrtf(tot * (1.0f / (float)D_SZ)) + 1e-5f);
    const float4 wv = ((const float4*)w)[tid];
    half4 o = {(_Float16)(v.x * inv * wv.x), (_Float16)(v.y * inv * wv.y),
               (_Float16)(v.z * inv * wv.z), (_Float16)(v.w * inv * wv.w)};
    ((half4*)(out + (size_t)row * D_SZ))[tid] = o;
}

// ---------------------------------------------------------------------------
// 8-phase deep-pipelined 256x256 MFMA fp16 GEMM (NT), faithful T3+T4 port.
// BK=64 split into K-halves; halves {A.k0,B.k0,A.k1,B.k1} are contiguous
// 16 KB LDS sub-arrays (linear global_load_lds). Per K-tile 4 phases:
//   {ds_read quadrant | stage 1 half | barrier | lgkmcnt(0)+sched_barrier |
//    setprio(1) 16 MFMA setprio(0) | barrier}
// Stage plan: q0->(t+1).A.k1, q1->(t+1).B.k1, q2->(t+2).A.k0, q3->(t+2).B.k0
// (each target region's last LDS read finished >=1 phase earlier).
// Counted vmcnt(4) once per tile boundary (0 only at the final tile).
// LDS XOR swizzle chunk^=(row&3) on 64B rows, applied both-sides.
// Requires M%256==0, N%256==0, K%64==0, K>=128.
// ---------------------------------------------------------------------------
template <bool MFAST>
__global__ __launch_bounds__(512) void hgemm8p(const _Float16* __restrict__ A,
                                               const _Float16* __restrict__ B,
                                               float* __restrict__ Cf,
                                               int M, int N, int K) {
    __shared__ __align__(16) _Float16 As[2][2][256 * 32];
    __shared__ __align__(16) _Float16 Bs[2][2][256 * 32];
    const int tid = threadIdx.x;
    const int lane = tid & 63, wave = tid >> 6;
    const int wm = wave >> 2, wn = wave & 3;
    const int l15 = lane & 15, g = lane >> 4;

    // bijective XCD chunk swizzle (m204)
    const int gm = M >> 8, gn = N >> 8, nwg = gm * gn;
    const int orig = blockIdx.x;
    const int q8 = nwg >> 3, r8 = nwg & 7, xcd = orig & 7, j8 = orig >> 3;
    const int wgid = (xcd < r8 ? xcd * (q8 + 1) : r8 * (q8 + 1) + (xcd - r8) * q8) + j8;
    const int bm = MFAST ? (wgid % gm) : (wgid / gn);
    const int bn = MFAST ? (wgid / gm) : (wgid % gn);
    const int m0 = bm << 8, n0 = bn << 8;

    // staging geometry: half = 256 rows x 32 K (64 B) = 16 KB = 2 gloads.
    // gload r: row = r*128 + tid/4, phys chunk p = tid&3 holds logical
    // chunk c = p ^ (row&3) -> source byte col = c*16 within the half.
    const int rowS = tid >> 2;                       // 0..127
    const int srcC = ((tid & 3) ^ (rowS & 3)) << 4;  // inverse-swizzled src
    const size_t Kb = (size_t)K * 2;
    const char* gA = (const char*)A + (size_t)(m0 + rowS) * Kb + srcC;
    const char* gB = (const char*)B + (size_t)(n0 + rowS) * Kb + srcC;
    const size_t g128 = 128 * Kb;                    // +128 rows

#define STA(ks, t, buf) do {                                              \
        const char* _s = gA + (size_t)(t) * 128 + (ks) * 64;              \
        char* _d = (char*)&As[buf][ks][0];                                \
        gload16(_s, _d + tid * 16);                                       \
        gload16(_s + g128, _d + 8192 + tid * 16);                         \
    } while (0)
#define STB(ks, t, buf) do {                                              \
        const char* _s = gB + (size_t)(t) * 128 + (ks) * 64;              \
        char* _d = (char*)&Bs[buf][ks][0];                                \
        gload16(_s, _d + tid * 16);                                       \
        gload16(_s + g128, _d + 8192 + tid * 16);                         \
    } while (0)

    half8 aF[8], bF[2];
#define READA(buf, ks) do {                                               \
        _Pragma("unroll")                                                 \
        for (int i = 0; i < 8; i++) {                                     \
            const int R = wm * 128 + i * 16 + l15;                        \
            aF[i] = *(const half8*)((const char*)&As[buf][ks][0] +        \
                                    R * 64 + ((g ^ (R & 3)) << 4));       \
        }                                                                 \
    } while (0)
#define READB(buf, ks, nh) do {                                           \
        _Pragma("unroll")                                                 \
        for (int jj = 0; jj < 2; jj++) {                                  \
            const int R = wn * 64 + ((nh) * 2 + jj) * 16 + l15;           \
            bF[jj] = *(const half8*)((const char*)&Bs[buf][ks][0] +       \
                                     R * 64 + ((g ^ (R & 3)) << 4));      \
        }                                                                 \
    } while (0)
#define MFMA16(nh) do {                                                   \
        __builtin_amdgcn_s_setprio(1);                                    \
        _Pragma("unroll")                                                 \
        for (int i = 0; i < 8; i++) {                                     \
            acc[i][(nh) * 2 + 0] = __builtin_amdgcn_mfma_f32_16x16x32_f16(\
                aF[i], bF[0], acc[i][(nh) * 2 + 0], 0, 0, 0);             \
            acc[i][(nh) * 2 + 1] = __builtin_amdgcn_mfma_f32_16x16x32_f16(\
                aF[i], bF[1], acc[i][(nh) * 2 + 1], 0, 0, 0);             \
        }                                                                 \
        __builtin_amdgcn_s_setprio(0);                                    \
    } while (0)
#define FENCE_MID() do {                                                  \
        __builtin_amdgcn_s_barrier();                                     \
        asm volatile("s_waitcnt lgkmcnt(0)" ::: "memory");                \
        __builtin_amdgcn_sched_barrier(0);                                \
    } while (0)

    floatx4 acc[8][4];
#pragma unroll
    for (int i = 0; i < 8; i++)
#pragma unroll
        for (int j = 0; j < 4; j++) acc[i][j] = 0;

    const int nt = K >> 6;
    // prologue: tile0 all 4 halves + tile1 first 2 halves (12 gloads)
    STA(0, 0, 0); STB(0, 0, 0); STA(1, 0, 0); STB(1, 0, 0);
    STA(0, 1, 1); STB(0, 1, 1);

    for (int t = 0; t < nt; ++t) {
        const int buf = t & 1, nbuf = buf ^ 1;
        // tile boundary: counted drain -> tile t fully resident
        if (t == nt - 1) asm volatile("s_waitcnt vmcnt(0)" ::: "memory");
        else             asm volatile("s_waitcnt vmcnt(4)" ::: "memory");
        __builtin_amdgcn_s_barrier();
        // phase 0: quadrant (ks=0, nh=0); stage (t+1).A.k1
        READA(buf, 0); READB(buf, 0, 0);
        if (t + 1 < nt) STA(1, t + 1, nbuf);
        FENCE_MID();
        MFMA16(0);
        __builtin_amdgcn_s_barrier();
        // phase 1: quadrant (ks=0, nh=1); stage (t+1).B.k1
        READB(buf, 0, 1);
        if (t + 1 < nt) STB(1, t + 1, nbuf);
        FENCE_MID();
        MFMA16(1);
        __builtin_amdgcn_s_barrier();
        // phase 2: quadrant (ks=1, nh=0); stage (t+2).A.k0 (recycles buf)
        READA(buf, 1); READB(buf, 1, 0);
        if (t + 2 < nt) STA(0, t + 2, buf);
        FENCE_MID();
        MFMA16(0);
        __builtin_amdgcn_s_barrier();
        // phase 3: quadrant (ks=1, nh=1); stage (t+2).B.k0
        READB(buf, 1, 1);
        if (t + 2 < nt) STB(0, t + 2, buf);
        FENCE_MID();
        MFMA16(1);
        __builtin_amdgcn_s_barrier();
    }
#undef STA
#undef STB
#undef READA
#undef READB
#undef MFMA16
#undef FENCE_MID

    // epilogue: D frag mapping col = lane&15, row = (lane>>4)*4 + e
#pragma unroll
    for (int i = 0; i < 8; i++) {
#pragma unroll
        for (int e = 0; e < 4; e++) {
            const int row = m0 + wm * 128 + i * 16 + g * 4 + e;
#pragma unroll
            for (int j = 0; j < 4; j++) {
                const int col = n0 + wn * 64 + j * 16 + l15;
                Cf[(size_t)row * N + col] = acc[i][j][e];
            }
        }
    }
}

// ---------------------------------------------------------------------------
// MFMA fp16 GEMM (NT): C[M,N] = A[M,K] * B[N,K]^T, fp32 accumulate.
// Tile TM x 128, BK=32, 4 waves. 2-phase prefetch, double-buffered LDS.
// EPI: 0 = Cf store; 1 = Cf += ; 2 = Ch = swish(v); 3 = Ch = AUXh * v;
//      4 = qkv split store (fp16) with fused RoPE on q,k
// ---------------------------------------------------------------------------
template <int EPI, bool MFAST, int TM>
__global__ __launch_bounds__(256) void hgemm(const _Float16* __restrict__ A,
                                             const _Float16* __restrict__ B,
                                             float* __restrict__ Cf,
                                             _Float16* Ch,
                                             const _Float16* AUXh,
                                             _Float16* Cq,
                                             _Float16* Ck,
                                             _Float16* Cv,
                                             int M, int N, int K) {
    constexpr int WN = (TM == 128) ? 2 : 4;
    constexpr int CW = 128 / WN;
    constexpr int FN = CW / 16;
    __shared__ __align__(16) _Float16 As[2][TM * 32];
    __shared__ __align__(16) _Float16 Bs[2][128 * 32];
    const int tid = threadIdx.x;
    const int lane = tid & 63;
    const int wave = tid >> 6;
    const int wr = (TM == 128) ? (wave >> 1) : 0;
    const int wc = (TM == 128) ? (wave & 1) : wave;
    const int l15 = lane & 15, g = lane >> 4;

    const int gm = M / TM, gn = N >> 7, nwg = gm * gn;
    const int orig = blockIdx.x;
    const int q8 = nwg >> 3, r8 = nwg & 7, xcd = orig & 7, j8 = orig >> 3;
    const int wgid = (xcd < r8 ? xcd * (q8 + 1) : r8 * (q8 + 1) + (xcd - r8) * q8) + j8;
    const int bm = MFAST ? (wgid % gm) : (wgid / gn);
    const int bn = MFAST ? (wgid / gm) : (wgid % gn);
    const int m0 = bm * TM, n0 = bn * 128;

    const int offA0 = wave * (TM * 16) + lane * 16;
    const int offA1 = offA0 + 1024;
    const int rA0 = offA0 >> 6, kA0 = offA0 & 63;
    const int rA1 = offA1 >> 6, kA1 = offA1 & 63;
    const int offB0 = wave * 2048 + lane * 16;
    const int offB1 = offB0 + 1024;
    const int rB0 = offB0 >> 6, kB0 = offB0 & 63;
    const int rB1 = offB1 >> 6, kB1 = offB1 & 63;
    const char* gA0 = (const char*)(A + (size_t)(m0 + rA0) * K) + kA0;
    const char* gA1 = (const char*)(A + (size_t)(m0 + rA1) * K) + kA1;
    const char* gB0 = (const char*)(B + (size_t)(n0 + rB0) * K) + kB0;
    const char* gB1 = (const char*)(B + (size_t)(n0 + rB1) * K) + kB1;

#define STAGE(buf)                                                     \
    do {                                                               \
        gload16(gA0, (char*)As[buf] + offA0);                          \
        if constexpr (TM == 128) gload16(gA1, (char*)As[buf] + offA1); \
        gload16(gB0, (char*)Bs[buf] + offB0);                          \
        gload16(gB1, (char*)Bs[buf] + offB1);                          \
        gA0 += 64; gA1 += 64; gB0 += 64; gB1 += 64;                    \
    } while (0)

    floatx4 acc[4][FN];
#pragma unroll
    for (int i = 0; i < 4; i++)
#pragma unroll
        for (int j = 0; j < FN; j++) acc[i][j] = 0;

    STAGE(0);
    __syncthreads();
    int cur = 0;
    for (int kk = 0; kk < K; kk += 32) {
        if (kk + 32 < K) STAGE(cur ^ 1);
        half8 aF[4], bF[FN];
#pragma unroll
        for (int i = 0; i < 4; i++)
            aF[i] = *(const half8*)&As[cur][(wr * 64 + i * 16 + l15) * 32 + g * 8];
#pragma unroll
        for (int j = 0; j < FN; j++)
            bF[j] = *(const half8*)&Bs[cur][(wc * CW + j * 16 + l15) * 32 + g * 8];
#pragma unroll
        for (int i = 0; i < 4; i++)
#pragma unroll
            for (int j = 0; j < FN; j++)
                acc[i][j] = __builtin_amdgcn_mfma_f32_16x16x32_f16(aF[i], bF[j], acc[i][j], 0, 0, 0);
        __syncthreads();
        cur ^= 1;
    }
#undef STAGE

    const int rb = m0 + wr * 64 + g * 4;
    const int cb = n0 + wc * CW + l15;
    if (EPI == 4) {
        const int sel = n0 >> 10;
        _Float16* Cx = sel == 0 ? Cq : (sel == 1 ? Ck : Cv);
        const int cb0 = cb - sel * 1024;
#pragma unroll
        for (int i = 0; i < 4; i++) {
#pragma unroll
            for (int e = 0; e < 4; e++) {
                const int row = rb + i * 16 + e;
                const int pos = row & (S_SZ - 1);
#pragma unroll
                for (int j = 0; j < FN; j++) {
                    float v = acc[i][j][e];
                    const int col = cb0 + j * 16;
                    if (sel < 2) {
                        const float pp = __shfl_xor(v, 1, 64);
                        const int pi = (col & 63) >> 1;
                        const float invf = exp2f((float)pi * -0.41524101186f);
                        float sn, cs;
                        sincosf((float)pos * invf, &sn, &cs);
                        v = (col & 1) ? (pp * sn + v * cs) : (v * cs - pp * sn);
                    }
                    Cx[(size_t)row * 1024 + col] = (_Float16)v;
                }
            }
        }
        return;
    }
#pragma unroll
    for (int i = 0; i < 4; i++) {
#pragma unroll
        for (int e = 0; e < 4; e++) {
            const int row = rb + i * 16 + e;
#pragma unroll
            for (int j = 0; j < FN; j++) {
                const float v = acc[i][j][e];
                const int col = cb + j * 16;
                if (EPI == 0) {
                    Cf[(size_t)row * N + col] = v;
                } else if (EPI == 1) {
                    Cf[(size_t)row * N + col] += v;
                } else if (EPI == 2) {
                    Ch[(size_t)row * N + col] =
                        (_Float16)(v / (1.0f + __expf(-v)));
                } else if (EPI == 3) {
                    const size_t idx = (size_t)row * N + col;
                    Ch[idx] = (_Float16)((float)AUXh[idx] * v);
                }
            }
        }
    }
}

// ---------------------------------------------------------------------------
// Fused SwiGLU GEMM: out[M,F] = swish(A@B1^T) * (A@B3^T), fp16 out.
// ---------------------------------------------------------------------------
__global__ __launch_bounds__(256) void hgemm_ff(const _Float16* __restrict__ A,
                                                const _Float16* __restrict__ B1,
                                                const _Float16* __restrict__ B3,
                                                _Float16* __restrict__ Ch,
                                                int M, int N, int K) {
    __shared__ __align__(16) _Float16 As[2][64 * 32];
    __shared__ __align__(16) _Float16 Bs1[2][128 * 32];
    __shared__ __align__(16) _Float16 Bs3[2][128 * 32];
    const int tid = threadIdx.x;
    const int lane = tid & 63;
    const int wave = tid >> 6;
    const int l15 = lane & 15, g = lane >> 4;

    const int gm = M >> 6, gn = N >> 7, nwg = gm * gn;
    const int orig = blockIdx.x;
    const int q8 = nwg >> 3, r8 = nwg & 7, xcd = orig & 7, j8 = orig >> 3;
    const int wgid = (xcd < r8 ? xcd * (q8 + 1) : r8 * (q8 + 1) + (xcd - r8) * q8) + j8;
    const int bm = wgid % gm, bn = wgid / gm;
    const int m0 = bm * 64, n0 = bn * 128;

    const int offA = wave * 1024 + lane * 16;
    const int rA = offA >> 6, kA = offA & 63;
    const int offB0 = wave * 2048 + lane * 16;
    const int offB1 = offB0 + 1024;
    const int rB0 = offB0 >> 6, kB0 = offB0 & 63;
    const int rB1 = offB1 >> 6, kB1 = offB1 & 63;
    const char* gA  = (const char*)(A  + (size_t)(m0 + rA) * K) + kA;
    const char* gB10 = (const char*)(B1 + (size_t)(n0 + rB0) * K) + kB0;
    const char* gB11 = (const char*)(B1 + (size_t)(n0 + rB1) * K) + kB1;
    const char* gB30 = (const char*)(B3 + (size_t)(n0 + rB0) * K) + kB0;
    const char* gB31 = (const char*)(B3 + (size_t)(n0 + rB1) * K) + kB1;

#define STAGEF(buf)                                   \
    do {                                              \
        gload16(gA,   (char*)As[buf]  + offA);        \
        gload16(gB10, (char*)Bs1[buf] + offB0);       \
        gload16(gB11, (char*)Bs1[buf] + offB1);       \
        gload16(gB30, (char*)Bs3[buf] + offB0);       \
        gload16(gB31, (char*)Bs3[buf] + offB1);       \
        gA += 64; gB10 += 64; gB11 += 64;             \
        gB30 += 64; gB31 += 64;                       \
    } while (0)

    floatx4 acc1[4][2], acc3[4][2];
#pragma unroll
    for (int i = 0; i < 4; i++)
#pragma unroll
        for (int j = 0; j < 2; j++) { acc1[i][j] = 0; acc3[i][j] = 0; }

    STAGEF(0);
    __syncthreads();
    int cur = 0;
    for (int kk = 0; kk < K; kk += 32) {
        if (kk + 32 < K) STAGEF(cur ^ 1);
        half8 aF[4], b1F[2], b3F[2];
#pragma unroll
        for (int i = 0; i < 4; i++)
            aF[i] = *(const half8*)&As[cur][(i * 16 + l15) * 32 + g * 8];
#pragma unroll
        for (int j = 0; j < 2; j++) {
            b1F[j] = *(const half8*)&Bs1[cur][(wave * 32 + j * 16 + l15) * 32 + g * 8];
            b3F[j] = *(const half8*)&Bs3[cur][(wave * 32 + j * 16 + l15) * 32 + g * 8];
        }
#pragma unroll
        for (int i = 0; i < 4; i++)
#pragma unroll
            for (int j = 0; j < 2; j++) {
                acc1[i][j] = __builtin_amdgcn_mfma_f32_16x16x32_f16(aF[i], b1F[j], acc1[i][j], 0, 0, 0);
                acc3[i][j] = __builtin_amdgcn_mfma_f32_16x16x32_f16(aF[i], b3F[j], acc3[i][j], 0, 0, 0);
            }
        __syncthreads();
        cur ^= 1;
    }
#undef STAGEF

    const int cb = n0 + wave * 32 + l15;
#pragma unroll
    for (int i = 0; i < 4; i++) {
#pragma unroll
        for (int e = 0; e < 4; e++) {
            const int row = m0 + i * 16 + g * 4 + e;
#pragma unroll
            for (int j = 0; j < 2; j++) {
                const float v1 = acc1[i][j][e];
                const float v3 = acc3[i][j][e];
                const float sw = v1 / (1.0f + __expf(-v1));
                Ch[(size_t)row * N + cb + j * 16] = (_Float16)(sw * v3);
            }
        }
    }
}

// ---------------------------------------------------------------------------
// Per-head V transpose: vh[b,s,h*64+d] -> vt[(b*16+h)*64+d][s]
// ---------------------------------------------------------------------------
__global__ __launch_bounds__(256) void vtrans(const _Float16* __restrict__ vh,
                                              _Float16* __restrict__ vt) {
    __shared__ __align__(16) _Float16 Ls[64][80];
    const int t = threadIdx.x;
    const int s0 = blockIdx.x * 64;
    const int bh = blockIdx.y;
    const int b = bh >> 4, h = bh & 15;
#pragma unroll
    for (int p = 0; p < 2; ++p) {
        const int sl = p * 32 + (t >> 3);
        const int d = (t & 7) * 8;
        *(half8*)&Ls[sl][d] =
            *(const half8*)&vh[((size_t)b * S_SZ + s0 + sl) * D_SZ + h * 64 + d];
    }
    __syncthreads();
#pragma unroll
    for (int p = 0; p < 2; ++p) {
        const int d = p * 32 + (t >> 3);
        const int sc = (t & 7) * 8;
        half8 v;
#pragma unroll
        for (int j = 0; j < 8; ++j) v[j] = Ls[sc + j][d];
        *(half8*)&vt[((size_t)bh * 64 + d) * S_SZ + s0 + sc] = v;
    }
}

// ---------------------------------------------------------------------------
// MFMA flash attention (causal), fp16 in/out, fp32 softmax state.
// ---------------------------------------------------------------------------
__global__ __launch_bounds__(256) void attn_mfma(const _Float16* __restrict__ qh,
                                                 const _Float16* __restrict__ kh,
                                                 const _Float16* __restrict__ vt,
                                                 _Float16* __restrict__ o) {
    __shared__ __align__(16) _Float16 Ks[2][64 * 64];
    __shared__ __align__(16) _Float16 Vs[2][64 * 64];
    __shared__ __align__(16) _Float16 Ps[4][16][88];
    const int tid = threadIdx.x;
    const int lane = tid & 63, wave = tid >> 6;
    const int l15 = lane & 15, g = lane >> 4;
    const int bx = blockIdx.x;
    const int bh = blockIdx.y;
    const int h = bh & 15;
    const size_t tokb = (size_t)(bh >> 4) * S_SZ;

    const int qt0 = bx, qt1 = 15 - bx;
    const int qb0 = qt0 * 64, qb1 = qt1 * 64;
    const int ktmax = qt1;

    const int qrow = l15 * 4 + wave;
    half8 qA0[2], qA1[2];
#pragma unroll
    for (int kk = 0; kk < 2; ++kk) {
        qA0[kk] = *(const half8*)&qh[(tokb + qb0 + qrow) * D_SZ + h * 64 + kk * 32 + g * 8];
        qA1[kk] = *(const half8*)&qh[(tokb + qb1 + qrow) * D_SZ + h * 64 + kk * 32 + g * 8];
    }

    floatx4 accO0[4], accO1[4];
#pragma unroll
    for (int s = 0; s < 4; s++) { accO0[s] = 0; accO1[s] = 0; }
    float m0_[4] = {NEG_INF, NEG_INF, NEG_INF, NEG_INF};
    float l0_[4] = {0.0f, 0.0f, 0.0f, 0.0f};
    float m1_[4] = {NEG_INF, NEG_INF, NEG_INF, NEG_INF};
    float l1_[4] = {0.0f, 0.0f, 0.0f, 0.0f};

    const char* KbB = (const char*)(kh + tokb * D_SZ + h * 64);
    const char* VbB = (const char*)(vt + (size_t)bh * 64 * S_SZ);
    const int so0 = wave * 2048 + lane * 16;
    const int so1 = so0 + 1024;
    const int r0 = so0 >> 7, c0 = (so0 >> 4) & 7;
    const int r1 = so1 >> 7, c1 = (so1 >> 4) & 7;
    const int gc0 = ((c0 ^ (r0 & 7)) << 4);
    const int gc1 = ((c1 ^ (r1 & 7)) << 4);

#define STAGEKV(buf, kt)                                                   \
    do {                                                                   \
        const size_t kvr = (size_t)(kt) * 64;                              \
        gload16(KbB + (kvr + r0) * 2048 + gc0, (char*)Ks[buf] + so0);      \
        gload16(KbB + (kvr + r1) * 2048 + gc1, (char*)Ks[buf] + so1);      \
        gload16(VbB + r0 * 2048 + kvr * 2 + gc0, (char*)Vs[buf] + so0);    \
        gload16(VbB + r1 * 2048 + kvr * 2 + gc1, (char*)Vs[buf] + so1);    \
    } while (0)

#define LDSW(arr, rr, cc) \
    (*(const half8*)&(arr)[(rr) * 64 + ((((cc) ^ ((rr) & 7))) << 3)])

    auto computeTile = [&](const half8* qA, floatx4* accO, float* m_, float* l_,
                           int qbase, int kt, bool diag, int buf) {
        const int kv0 = kt * 64;
        floatx4 accS[4];
        __builtin_amdgcn_s_setprio(1);
#pragma unroll
        for (int sub = 0; sub < 4; ++sub) {
            accS[sub] = 0;
#pragma unroll
            for (int kk = 0; kk < 2; ++kk) {
                half8 kB = LDSW(Ks[buf], sub * 16 + l15, kk * 4 + g);
                accS[sub] = __builtin_amdgcn_mfma_f32_16x16x32_f16(qA[kk], kB, accS[sub], 0, 0, 0);
            }
        }
        __builtin_amdgcn_s_setprio(0);
        float sv[4][4];
        float mx[4] = {NEG_INF, NEG_INF, NEG_INF, NEG_INF};
#pragma unroll
        for (int sub = 0; sub < 4; ++sub)
#pragma unroll
            for (int e = 0; e < 4; ++e) {
                float s = accS[sub][e] * 0.125f;
                if (diag && (kv0 + sub * 16 + l15 > qbase + (g * 4 + e) * 4 + wave))
                    s = NEG_INF;
                sv[sub][e] = s;
                mx[e] = fmaxf(mx[e], s);
            }
#pragma unroll
        for (int msk = 1; msk <= 8; msk <<= 1)
#pragma unroll
            for (int e = 0; e < 4; ++e)
                mx[e] = fmaxf(mx[e], __shfl_xor(mx[e], msk, 64));
        float sf[4];
#pragma unroll
        for (int e = 0; e < 4; ++e) {
            const float mn = fmaxf(m_[e], mx[e]);
            sf[e] = __expf(m_[e] - mn);
            m_[e] = mn;
        }
        float rs[4] = {0.0f, 0.0f, 0.0f, 0.0f};
#pragma unroll
        for (int sub = 0; sub < 4; ++sub)
#pragma unroll
            for (int e = 0; e < 4; ++e) {
                const float p = __expf(sv[sub][e] - m_[e]);
                sv[sub][e] = p;
                rs[e] += p;
            }
#pragma unroll
        for (int msk = 1; msk <= 8; msk <<= 1)
#pragma unroll
            for (int e = 0; e < 4; ++e)
                rs[e] += __shfl_xor(rs[e], msk, 64);
#pragma unroll
        for (int e = 0; e < 4; ++e) l_[e] = l_[e] * sf[e] + rs[e];
#pragma unroll
        for (int sub = 0; sub < 4; ++sub)
#pragma unroll
            for (int e = 0; e < 4; ++e) accO[sub][e] *= sf[e];
#pragma unroll
        for (int sub = 0; sub < 4; ++sub)
#pragma unroll
            for (int e = 0; e < 4; ++e)
                Ps[wave][g * 4 + e][sub * 16 + l15] = (_Float16)sv[sub][e];
        half8 aP[2];
        aP[0] = *(const half8*)&Ps[wave][l15][g * 8];
        aP[1] = *(const half8*)&Ps[wave][l15][32 + g * 8];
        __builtin_amdgcn_s_setprio(1);
#pragma unroll
        for (int sub = 0; sub < 4; ++sub)
#pragma unroll
            for (int kk = 0; kk < 2; ++kk) {
                half8 vB = LDSW(Vs[buf], sub * 16 + l15, kk * 4 + g);
                accO[sub] = __builtin_amdgcn_mfma_f32_16x16x32_f16(aP[kk], vB, accO[sub], 0, 0, 0);
            }
        __builtin_amdgcn_s_setprio(0);
    };

    STAGEKV(0, 0);
    __syncthreads();
    int cur = 0;
    for (int kt = 0; kt <= ktmax; ++kt) {
        if (kt < ktmax) STAGEKV(cur ^ 1, kt + 1);
        computeTile(qA1, accO1, m1_, l1_, qb1, kt, kt == qt1, cur);
        if (kt <= qt0)
            computeTile(qA0, accO0, m0_, l0_, qb0, kt, kt == qt0, cur);
        __syncthreads();
        cur ^= 1;
    }
#undef STAGEKV
#undef LDSW

#pragma unroll
    for (int sub = 0; sub < 4; ++sub)
#pragma unroll
        for (int e = 0; e < 4; ++e) {
            const int rr = (g * 4 + e) * 4 + wave;
            o[(tokb + qb1 + rr) * D_SZ + h * 64 + sub * 16 + l15] =
                (_Float16)(accO1[sub][e] / l1_[e]);
            o[(tokb + qb0 + rr) * D_SZ + h * 64 + sub * 16 + l15] =
                (_Float16)(accO0[sub][e] / l0_[e]);
        }
}

// ---------------------------------------------------------------------------
// Host-side launch
// ---------------------------------------------------------------------------
extern "C" void kernel_launch(void* const* d_in, const int* in_sizes, int n_in,
                              void* d_out, int out_size, void* d_ws, size_t ws_size,
                              hipStream_t stream) {
    const int*   token_ids  = (const int*)d_in[0];
    const float* tok_emb    = (const float*)d_in[1];
    const float* lm_head_w  = (const float*)d_in[2];
    const float* ln_final_w = (const float*)d_in[3];
    const float* q_w        = (const float*)d_in[4];
    const float* k_w        = (const float*)d_in[5];
    const float* v_w        = (const float*)d_in[6];
    const float* o_w        = (const float*)d_in[7];
    const float* ln1_w      = (const float*)d_in[8];
    const float* ln2_w      = (const float*)d_in[9];
    const float* w1         = (const float*)d_in[10];
    const float* w2         = (const float*)d_in[11];
    const float* w3         = (const float*)d_in[12];
    float* out = (float*)d_out;

    char* W = (char*)d_ws;
    const size_t MB = 1u << 20;
    float*    x    = (float*)(W + 0);           // 8 MB
    _Float16* h    = (_Float16*)(W + 8 * MB);   // 4 MB
    _Float16* ao   = (_Float16*)(W + 12 * MB);  // 4 MB
    _Float16* wq   = (_Float16*)(W + 16 * MB);  // 8 MB: q/k/v/o contiguous
    _Float16* wo   = wq + 3 * (1u << 20);
    _Float16* ww1  = (_Float16*)(W + 24 * MB);  // 24 MB: w1/w3/w2 contiguous
    _Float16* ww3  = ww1 + (size_t)F_SZ * D_SZ;
    _Float16* ww2  = ww1 + 2 * (size_t)F_SZ * D_SZ;
    _Float16* qh   = (_Float16*)(W + 48 * MB);  // 4 MB
    _Float16* kh   = (_Float16*)(W + 52 * MB);  // 4 MB
    _Float16* vh   = (_Float16*)(W + 56 * MB);  // 4 MB
    _Float16* vt   = (_Float16*)(W + 60 * MB);  // 4 MB
    _Float16* ff1h = (_Float16*)(W + 64 * MB);  // 16 MB -> 80 MB
    _Float16* whead = (_Float16*)(W + 24 * MB); // 62.5 MB, overlaps dead ww*

    embed_kernel<<<NTOK, 256, 0, stream>>>(token_ids, tok_emb, x);

    const int nDD8 = D_SZ * D_SZ / 8;     // 131072
    const int nFD8 = F_SZ * D_SZ / 8;     // 524288
    const int nCNV = 4 * nDD8 + 3 * nFD8; // 2097152
    const dim3 gQKV(3 * D_SZ / 128 * (NTOK / 128));   // 384
    const dim3 gD64(D_SZ / 128 * (NTOK / 64));        // 256 (TM=64)
    const dim3 gFF(F_SZ / 128 * (NTOK / 64));         // 1024 (fused swiglu)
    const dim3 gATT(S_SZ / 128, B_SZ * H_SZ);         // (8,32), paired tiles
    const dim3 gVT(S_SZ / 64, B_SZ * H_SZ);

    for (int l = 0; l < L_SZ; l++) {
        const size_t oDD = (size_t)l * D_SZ * D_SZ;
        const size_t oFD = (size_t)l * F_SZ * D_SZ;
        rmsnorm_kernel<<<NTOK, 256, 0, stream>>>(x, ln1_w + (size_t)l * D_SZ, h);
        f2h7<<<nCNV / 256, 256, 0, stream>>>(q_w + oDD, k_w + oDD, v_w + oDD,
                                             o_w + oDD, w1 + oFD, w3 + oFD,
                                             w2 + oFD, wq, nDD8, nFD8);
        hgemm<4, true, 128><<<gQKV, 256, 0, stream>>>(h, wq, nullptr, nullptr, nullptr,
                                                      qh, kh, vh, NTOK, 3 * D_SZ, D_SZ);
        vtrans<<<gVT, 256, 0, stream>>>(vh, vt);
        attn_mfma<<<gATT, 256, 0, stream>>>(qh, kh, vt, ao);
        hgemm<1, false, 64><<<gD64, 256, 0, stream>>>(ao, wo, x, nullptr, nullptr,
                                                      nullptr, nullptr, nullptr, NTOK, D_SZ, D_SZ);
        rmsnorm_kernel<<<NTOK, 256, 0, stream>>>(x, ln2_w + (size_t)l * D_SZ, h);
        hgemm_ff<<<gFF, 256, 0, stream>>>(h, ww1, ww3, ff1h, NTOK, F_SZ, D_SZ);
        hgemm<1, false, 64><<<gD64, 256, 0, stream>>>(ff1h, ww2, x, nullptr, nullptr,
                                                      nullptr, nullptr, nullptr, NTOK, D_SZ, F_SZ);
    }
    rmsnorm_kernel<<<NTOK, 256, 0, stream>>>(x, ln_final_w, h);
    const int nVD8 = V_SZ * D_SZ / 8;
    f2h<<<(nVD8 + 255) / 256, 256, 0, stream>>>(lm_head_w, whead, nVD8);
    const dim3 gOUT(V_SZ / 256 * (NTOK / 256));       // 1000 (256^2, 8-phase)
    hgemm8p<true><<<gOUT, 512, 0, stream>>>(h, whead, out, NTOK, V_SZ, D_SZ);
}